// Round 2
// baseline (998.306 us; speedup 1.0000x reference)
//
#include <hip/hip_runtime.h>
#include <hip/hip_bf16.h>

typedef __attribute__((ext_vector_type(8))) short short8;
typedef __attribute__((ext_vector_type(4))) float f32x4;

#define NTOK 576
#define DIM  1024
#define NB   4
#define NH   8
#define HD   128
#define KDIR 8
#define KN   4608

__device__ __forceinline__ float us2f(unsigned short u) {
    unsigned int x = ((unsigned int)u) << 16;
    return __uint_as_float(x);
}
__device__ __forceinline__ unsigned short f2us(float f) {
    unsigned int x = __float_as_uint(f);
    unsigned int r = x + 0x7fffu + ((x >> 16) & 1u);
    return (unsigned short)(r >> 16);
}

// meta[0] = dtype flag (1 = buffers are bf16, 0 = buffers are f32)
// meta[1] = NaN stage flags (bit i set -> stage i produced non-finite values)
__global__ void detect_kernel(const unsigned int* __restrict__ src, int* meta)
{
    if (threadIdx.x == 0) {
        int cnt = 0;
        for (int i = 0; i < 256; ++i) {
            unsigned u = src[(long)i * 16384] & 0xFFFFu;   // low ushort of dword
            unsigned e = (u >> 7) & 0xFFu;                 // bf16 exponent field
            cnt += (e >= 90 && e <= 150) ? 1 : 0;
        }
        // bf16 data: low ushort is a real bf16 value (~N(0,1/32)) -> cnt ~ 256.
        // f32 data: low ushort is mantissa bits -> exponent uniform -> cnt ~ 61.
        meta[0] = (cnt >= 192) ? 1 : 0;
        meta[1] = 0;
    }
}

__global__ __launch_bounds__(256)
void conv_kernel(const void* __restrict__ src, unsigned short* __restrict__ dst,
                 long n, const int* __restrict__ meta)
{
    long i = (long)blockIdx.x * 256 + threadIdx.x;
    const long st = (long)gridDim.x * 256;
    if (meta[0]) {
        const unsigned short* s = (const unsigned short*)src;
        for (; i < n; i += st) dst[i] = s[i];
    } else {
        const float* s = (const float*)src;
        for (; i < n; i += st) dst[i] = f2us(s[i]);
    }
}

__global__ __launch_bounds__(256)
void nan_check_bf16(const unsigned short* __restrict__ b, long n4,
                    int* meta, int bit)
{
    long i = (long)blockIdx.x * 256 + threadIdx.x;
    const long st = (long)gridDim.x * 256;
    const ushort4* p = (const ushort4*)b;
    int bad = 0;
    for (; i < n4; i += st) {
        ushort4 v = p[i];
        bad |= (((v.x >> 7) & 0xFF) == 0xFF);
        bad |= (((v.y >> 7) & 0xFF) == 0xFF);
        bad |= (((v.z >> 7) & 0xFF) == 0xFF);
        bad |= (((v.w >> 7) & 0xFF) == 0xFF);
    }
    if (bad) atomicOr(&meta[1], 1 << bit);
}

__global__ __launch_bounds__(256)
void nan_check_out(const void* __restrict__ o, long n, int* meta, int bit)
{
    long i = (long)blockIdx.x * 256 + threadIdx.x;
    const long st = (long)gridDim.x * 256;
    int bad = 0;
    if (meta[0]) {
        const unsigned short* p = (const unsigned short*)o;
        for (; i < n; i += st) bad |= (((p[i] >> 7) & 0xFF) == 0xFF);
    } else {
        const unsigned int* p = (const unsigned int*)o;
        for (; i < n; i += st) bad |= (((p[i] >> 23) & 0xFF) == 0xFF);
    }
    if (bad) atomicOr(&meta[1], 1 << bit);
}

__global__ __launch_bounds__(256)
void finalize_kernel(void* dout, const int* meta, long n)
{
    int f = meta[1];
    if (!f) return;
    int s = 0;
    while (!(f & (1 << s))) ++s;
    float code = 2048.0f * (s + 1);   // exact in bf16 for s=0..7
    long i = (long)blockIdx.x * 256 + threadIdx.x;
    const long st = (long)gridDim.x * 256;
    if (meta[0]) {
        unsigned short* p = (unsigned short*)dout;
        unsigned short c = f2us(code);
        for (; i < n; i += st) p[i] = c;
    } else {
        float* p = (float*)dout;
        for (; i < n; i += st) p[i] = code;
    }
}

// C[M x N] = A[M x K] @ op(B) + bias,  N = tiles_n*128 (always 1024 here).
template<bool BT>
__global__ __launch_bounds__(256)
void gemm_bias(const unsigned short* __restrict__ A, const unsigned short* __restrict__ Bm,
               const unsigned short* __restrict__ bias, unsigned short* __restrict__ C,
               int M, int K, int tiles_n,
               int a_div, long strideA, int b_mod, long strideB,
               long strideBias, long strideC)
{
    const int N = tiles_n * 128;
    const int z = blockIdx.y;
    const unsigned short* Ab = A + (long)(z / a_div) * strideA;
    const unsigned short* Bb = Bm + (long)(z % b_mod) * strideB;
    const unsigned short* Gb = bias + (long)(z % b_mod) * strideBias;
    unsigned short* Cb = C + (long)z * strideC;
    const int tm = blockIdx.x / tiles_n;
    const int tn = blockIdx.x % tiles_n;

    __shared__ __align__(16) unsigned short As[128][40];
    __shared__ __align__(16) unsigned short Bs[128][40];

    const int tid = threadIdx.x;
    const int lane = tid & 63;
    const int wid  = tid >> 6;
    const int wm = wid >> 1, wn = wid & 1;
    const int r0 = lane & 15;
    const int k8 = (lane >> 4) * 8;

    f32x4 zz = {0.f, 0.f, 0.f, 0.f};
    f32x4 acc[4][4];
    #pragma unroll
    for (int i = 0; i < 4; ++i)
        #pragma unroll
        for (int j = 0; j < 4; ++j) acc[i][j] = zz;

    for (int k0 = 0; k0 < K; k0 += 32) {
        short8 aR[2], bR[2];
        #pragma unroll
        for (int i = 0; i < 2; ++i) {
            int c = tid + i * 256;
            int row = c >> 2, kc = (c & 3) * 8;
            int rg = tm * 128 + row; rg = rg < M ? rg : M - 1;
            aR[i] = *reinterpret_cast<const short8*>(Ab + (long)rg * K + k0 + kc);
        }
        if (BT) {
            #pragma unroll
            for (int i = 0; i < 2; ++i) {
                int c = tid + i * 256;
                int row = c >> 2, kc = (c & 3) * 8;
                bR[i] = *reinterpret_cast<const short8*>(Bb + (long)(tn * 128 + row) * K + k0 + kc);
            }
        } else {
            #pragma unroll
            for (int i = 0; i < 2; ++i) {
                int c = tid + i * 256;
                int kr = c >> 4, nc = (c & 15) * 8;
                bR[i] = *reinterpret_cast<const short8*>(Bb + (long)(k0 + kr) * N + tn * 128 + nc);
            }
        }
        __syncthreads();
        #pragma unroll
        for (int i = 0; i < 2; ++i) {
            int c = tid + i * 256;
            int row = c >> 2, kc = (c & 3) * 8;
            *reinterpret_cast<short8*>(&As[row][kc]) = aR[i];
        }
        if (BT) {
            #pragma unroll
            for (int i = 0; i < 2; ++i) {
                int c = tid + i * 256;
                int row = c >> 2, kc = (c & 3) * 8;
                *reinterpret_cast<short8*>(&Bs[row][kc]) = bR[i];
            }
        } else {
            #pragma unroll
            for (int i = 0; i < 2; ++i) {
                int c = tid + i * 256;
                int kr = c >> 4, nc = (c & 15) * 8;
                #pragma unroll
                for (int j = 0; j < 8; ++j)
                    Bs[nc + j][kr] = (unsigned short)bR[i][j];
            }
        }
        __syncthreads();
        short8 af[4], bfr[4];
        #pragma unroll
        for (int mi = 0; mi < 4; ++mi)
            af[mi] = *reinterpret_cast<const short8*>(&As[wm * 64 + mi * 16 + r0][k8]);
        #pragma unroll
        for (int ni = 0; ni < 4; ++ni)
            bfr[ni] = *reinterpret_cast<const short8*>(&Bs[wn * 64 + ni * 16 + r0][k8]);
        #pragma unroll
        for (int mi = 0; mi < 4; ++mi)
            #pragma unroll
            for (int ni = 0; ni < 4; ++ni)
                acc[mi][ni] = __builtin_amdgcn_mfma_f32_16x16x32_bf16(af[mi], bfr[ni], acc[mi][ni], 0, 0, 0);
    }

    const int jr = (lane >> 4) * 4;
    #pragma unroll
    for (int ni = 0; ni < 4; ++ni) {
        int cg = tn * 128 + wn * 64 + ni * 16 + r0;
        float bv = us2f(Gb[cg]);
        #pragma unroll
        for (int mi = 0; mi < 4; ++mi) {
            #pragma unroll
            for (int j = 0; j < 4; ++j) {
                int rg = tm * 128 + wm * 64 + mi * 16 + jr + j;
                if (rg < M) Cb[(long)rg * N + cg] = f2us(acc[mi][ni][j] + bv);
            }
        }
    }
}

// Flash attention: grid (9 q-tiles, B*H). 4 waves x 16 q-rows. KV tile = 64.
__global__ __launch_bounds__(256)
void attn_kernel(const unsigned short* __restrict__ Qb, const unsigned short* __restrict__ Kb,
                 const unsigned short* __restrict__ Vb, unsigned short* __restrict__ Ob)
{
    const int qt = blockIdx.x;
    const int bh = blockIdx.y;
    const int b = bh >> 3, h = bh & 7;
    const int tid = threadIdx.x;
    const int lane = tid & 63, wid = tid >> 6;
    const int r0 = lane & 15;
    const int k8 = (lane >> 4) * 8;
    const int jr = (lane >> 4) * 4;

    __shared__ __align__(16) unsigned short Ks[64][136];
    __shared__ __align__(16) unsigned short VT[128][72];
    __shared__ __align__(16) unsigned short Pl[4][16][72];

    short8 qf[4];
    {
        const long qoff = ((long)(b * NTOK + qt * 64 + wid * 16 + r0)) * DIM + h * HD;
        #pragma unroll
        for (int kd = 0; kd < 4; ++kd)
            qf[kd] = *reinterpret_cast<const short8*>(Qb + qoff + kd * 32 + k8);
    }

    f32x4 zz = {0.f, 0.f, 0.f, 0.f};
    f32x4 oacc[8];
    #pragma unroll
    for (int i = 0; i < 8; ++i) oacc[i] = zz;
    float mrun[4], lrun[4];
    #pragma unroll
    for (int j = 0; j < 4; ++j) { mrun[j] = -1e30f; lrun[j] = 0.f; }

    const float sc = 0.08838834764831845f;  // 1/sqrt(128)

    for (int kt = 0; kt < 72; ++kt) {
        const long base = ((long)b * KN + kt * 64) * DIM + h * HD;
        #pragma unroll
        for (int i = 0; i < 4; ++i) {
            int c = tid + i * 256;
            int row = c >> 4, cc = (c & 15) * 8;
            short8 kk = *reinterpret_cast<const short8*>(Kb + base + (long)row * DIM + cc);
            *reinterpret_cast<short8*>(&Ks[row][cc]) = kk;
            short8 vv = *reinterpret_cast<const short8*>(Vb + base + (long)row * DIM + cc);
            #pragma unroll
            for (int j = 0; j < 8; ++j)
                VT[cc + j][row] = (unsigned short)vv[j];
        }
        __syncthreads();

        f32x4 s[4];
        #pragma unroll
        for (int nb = 0; nb < 4; ++nb) s[nb] = zz;
        #pragma unroll
        for (int nb = 0; nb < 4; ++nb)
            #pragma unroll
            for (int kd = 0; kd < 4; ++kd)
                s[nb] = __builtin_amdgcn_mfma_f32_16x16x32_bf16(qf[kd],
                        *reinterpret_cast<const short8*>(&Ks[nb * 16 + r0][kd * 32 + k8]), s[nb], 0, 0, 0);
        #pragma unroll
        for (int nb = 0; nb < 4; ++nb)
            #pragma unroll
            for (int j = 0; j < 4; ++j)
                s[nb][j] *= sc;

        float mt[4], rt[4], scl[4];
        #pragma unroll
        for (int j = 0; j < 4; ++j)
            mt[j] = fmaxf(fmaxf(s[0][j], s[1][j]), fmaxf(s[2][j], s[3][j]));
        #pragma unroll
        for (int off = 1; off < 16; off <<= 1)
            #pragma unroll
            for (int j = 0; j < 4; ++j)
                mt[j] = fmaxf(mt[j], __shfl_xor(mt[j], off));
        #pragma unroll
        for (int j = 0; j < 4; ++j) {
            float mn = fmaxf(mrun[j], mt[j]);
            scl[j] = __expf(mrun[j] - mn);
            mrun[j] = mn;
            rt[j] = 0.f;
        }
        #pragma unroll
        for (int nb = 0; nb < 4; ++nb)
            #pragma unroll
            for (int j = 0; j < 4; ++j) {
                float p = __expf(s[nb][j] - mrun[j]);
                rt[j] += p;
                Pl[wid][jr + j][nb * 16 + r0] = f2us(p);
            }
        #pragma unroll
        for (int off = 1; off < 16; off <<= 1)
            #pragma unroll
            for (int j = 0; j < 4; ++j)
                rt[j] += __shfl_xor(rt[j], off);
        #pragma unroll
        for (int j = 0; j < 4; ++j)
            lrun[j] = lrun[j] * scl[j] + rt[j];
        #pragma unroll
        for (int db = 0; db < 8; ++db)
            #pragma unroll
            for (int j = 0; j < 4; ++j)
                oacc[db][j] *= scl[j];

        #pragma unroll
        for (int kb = 0; kb < 2; ++kb) {
            short8 ap = *reinterpret_cast<const short8*>(&Pl[wid][r0][kb * 32 + k8]);
            #pragma unroll
            for (int db = 0; db < 8; ++db)
                oacc[db] = __builtin_amdgcn_mfma_f32_16x16x32_bf16(ap,
                        *reinterpret_cast<const short8*>(&VT[db * 16 + r0][kb * 32 + k8]), oacc[db], 0, 0, 0);
        }
        __syncthreads();
    }

    float inv[4];
    #pragma unroll
    for (int j = 0; j < 4; ++j) inv[j] = 1.f / lrun[j];
    const long orow0 = (long)(b * NTOK + qt * 64 + wid * 16);
    #pragma unroll
    for (int db = 0; db < 8; ++db)
        #pragma unroll
        for (int j = 0; j < 4; ++j) {
            long r = orow0 + jr + j;
            Ob[r * DIM + h * HD + db * 16 + r0] = f2us(oacc[db][j] * inv[j]);
        }
}

// LayerNorm(y)*g + b + vision, one row per block; output dtype per meta[0]
__global__ __launch_bounds__(256)
void ln2_kernel(const unsigned short* __restrict__ Y, const unsigned short* __restrict__ g,
                const unsigned short* __restrict__ be, const unsigned short* __restrict__ vis,
                void* __restrict__ dout, const int* __restrict__ meta)
{
    const int row = blockIdx.x;
    const int tid = threadIdx.x;
    const int lane = tid & 63, wid = tid >> 6;
    const unsigned short* yr = Y + (long)row * DIM;
    ushort4 raw = reinterpret_cast<const ushort4*>(yr)[tid];
    float v[4];
    v[0] = us2f(raw.x); v[1] = us2f(raw.y); v[2] = us2f(raw.z); v[3] = us2f(raw.w);
    float s1 = 0.f, s2 = 0.f;
    #pragma unroll
    for (int i = 0; i < 4; ++i) { s1 += v[i]; s2 += v[i] * v[i]; }
    #pragma unroll
    for (int off = 1; off < 64; off <<= 1) {
        s1 += __shfl_xor(s1, off);
        s2 += __shfl_xor(s2, off);
    }
    __shared__ float red[2][4];
    if (lane == 0) { red[0][wid] = s1; red[1][wid] = s2; }
    __syncthreads();
    s1 = red[0][0] + red[0][1] + red[0][2] + red[0][3];
    s2 = red[1][0] + red[1][1] + red[1][2] + red[1][3];
    const float mu = s1 * (1.f / DIM);
    const float var = s2 * (1.f / DIM) - mu * mu;
    const float inv = rsqrtf(var + 1e-5f);
    ushort4 gg = reinterpret_cast<const ushort4*>(g)[tid];
    ushort4 bb = reinterpret_cast<const ushort4*>(be)[tid];
    ushort4 vv = reinterpret_cast<const ushort4*>(vis + (long)row * DIM)[tid];
    float o0 = (v[0] - mu) * inv * us2f(gg.x) + us2f(bb.x) + us2f(vv.x);
    float o1 = (v[1] - mu) * inv * us2f(gg.y) + us2f(bb.y) + us2f(vv.y);
    float o2 = (v[2] - mu) * inv * us2f(gg.z) + us2f(bb.z) + us2f(vv.z);
    float o3 = (v[3] - mu) * inv * us2f(gg.w) + us2f(bb.w) + us2f(vv.w);
    if (meta[0]) {
        ushort4 o;
        o.x = f2us(o0); o.y = f2us(o1); o.z = f2us(o2); o.w = f2us(o3);
        reinterpret_cast<ushort4*>((unsigned short*)dout + (long)row * DIM)[tid] = o;
    } else {
        float4 o = make_float4(o0, o1, o2, o3);
        reinterpret_cast<float4*>((float*)dout + (long)row * DIM)[tid] = o;
    }
}

extern "C" void kernel_launch(void* const* d_in, const int* in_sizes, int n_in,
                              void* d_out, int out_size, void* d_ws, size_t ws_size,
                              hipStream_t stream)
{
    // scan_idx (d_in[11]) unused: all 8 scans are bijections on the 576 cells and
    // softmax over the full K*N key axis (K,V share row order) is permutation-
    // invariant per direction block -> gather elided.
    unsigned long long w = (unsigned long long)d_ws;
    int* meta = (int*)w; w += 256;

    const long nE[11] = {
        (long)NB * NTOK * DIM,      // vision
        (long)KDIR * DIM * DIM,     // dirW
        (long)KDIR * DIM,           // dirb
        3L * DIM * DIM,             // inW
        3L * DIM,                   // inB
        (long)DIM * DIM,            // outW
        DIM,                        // outB
        (long)DIM * DIM,            // finW
        DIM,                        // finB
        DIM, DIM                    // lng, lnb
    };
    unsigned short* cv[11];
    for (int i = 0; i < 11; ++i) {
        cv[i] = (unsigned short*)w;
        w += (nE[i] * 2 + 255) & ~255ULL;
    }
    const size_t big = (size_t)NB * KDIR * NTOK * DIM * 2;   // 37.75 MB
    const size_t sml = (size_t)NB * NTOK * DIM * 2;          // 4.72 MB
    unsigned short* dirs = (unsigned short*)w; w += big;
    unsigned short* Km   = (unsigned short*)w; w += big;
    unsigned short* Vm   = (unsigned short*)w; w += big;
    unsigned short* Qm   = (unsigned short*)w; w += sml;
    unsigned short* Ob   = (unsigned short*)w; w += sml;
    unsigned short* Fu   = (unsigned short*)w; w += sml;
    unsigned short* Y2   = (unsigned short*)w; w += sml;

    dim3 blk(256, 1, 1);

    // 0. dtype detect + zero nan-flags
    detect_kernel<<<dim3(1), dim3(64), 0, stream>>>((const unsigned int*)d_in[1], meta);

    // 1. convert (or copy) all float tensors to bf16
    for (int i = 0; i < 11; ++i)
        conv_kernel<<<dim3(512), blk, 0, stream>>>(d_in[i], cv[i], nE[i], meta);

    // 2. dirs[b,k] = vision[b] @ dirW[k] + dirb[k]   (batch z = b*8+k)
    gemm_bias<false><<<dim3(5 * 8, NB * KDIR), blk, 0, stream>>>(
        cv[0], cv[1], cv[2], dirs,
        NTOK, DIM, 8,
        KDIR, (long)NTOK * DIM, KDIR, (long)DIM * DIM, (long)DIM, (long)NTOK * DIM);

    // 3. Q = vision @ wq^T + bq
    gemm_bias<true><<<dim3(18 * 8, 1), blk, 0, stream>>>(
        cv[0], cv[3], cv[4], Qm,
        NB * NTOK, DIM, 8, 1, 0L, 1, 0L, 0L, 0L);

    // 4. K = dirs @ wk^T + bk
    gemm_bias<true><<<dim3(144 * 8, 1), blk, 0, stream>>>(
        dirs, cv[3] + DIM * DIM, cv[4] + DIM, Km,
        NB * KN, DIM, 8, 1, 0L, 1, 0L, 0L, 0L);

    // 5. V = dirs @ wv^T + bv
    gemm_bias<true><<<dim3(144 * 8, 1), blk, 0, stream>>>(
        dirs, cv[3] + 2 * DIM * DIM, cv[4] + 2 * DIM, Vm,
        NB * KN, DIM, 8, 1, 0L, 1, 0L, 0L, 0L);

    // 6. attention -> Ob
    attn_kernel<<<dim3(9, NB * NH), blk, 0, stream>>>(Qm, Km, Vm, Ob);

    // 7. fused = Ob @ out_proj^T + b
    gemm_bias<true><<<dim3(18 * 8, 1), blk, 0, stream>>>(
        Ob, cv[5], cv[6], Fu,
        NB * NTOK, DIM, 8, 1, 0L, 1, 0L, 0L, 0L);

    // 8. y = fused @ fin^T + b
    gemm_bias<true><<<dim3(18 * 8, 1), blk, 0, stream>>>(
        Fu, cv[7], cv[8], Y2,
        NB * NTOK, DIM, 8, 1, 0L, 1, 0L, 0L, 0L);

    // 9. LayerNorm + residual -> d_out (dtype per meta[0])
    ln2_kernel<<<dim3(NB * NTOK), blk, 0, stream>>>(Y2, cv[9], cv[10], cv[0], d_out, meta);

    // 10. stage diagnostics: flag non-finite values per stage
    const long n4v = nE[0] / 4, n4b = (long)NB * KDIR * NTOK * DIM / 4;
    nan_check_bf16<<<dim3(1024), blk, 0, stream>>>(cv[0], n4v, meta, 0);  // code 2048: conv/dtype
    nan_check_bf16<<<dim3(1024), blk, 0, stream>>>(dirs, n4b, meta, 1);   // 4096: dirs gemm
    nan_check_bf16<<<dim3(1024), blk, 0, stream>>>(Km,   n4b, meta, 2);   // 6144: K gemm
    nan_check_bf16<<<dim3(1024), blk, 0, stream>>>(Vm,   n4b, meta, 3);   // 8192: V gemm
    nan_check_bf16<<<dim3(1024), blk, 0, stream>>>(Qm,   n4v, meta, 4);   // 10240: Q gemm
    nan_check_bf16<<<dim3(1024), blk, 0, stream>>>(Ob,   n4v, meta, 5);   // 12288: attention
    nan_check_bf16<<<dim3(1024), blk, 0, stream>>>(Y2,   n4v, meta, 6);   // 14336: proj gemms
    nan_check_out <<<dim3(1024), blk, 0, stream>>>(d_out, (long)out_size, meta, 7); // 16384: LN

    // 11. if any stage flagged, overwrite output with the stage code
    finalize_kernel<<<dim3(1024), blk, 0, stream>>>(d_out, meta, (long)out_size);
}

// Round 3
// 490.538 us; speedup vs baseline: 2.0351x; 2.0351x over previous
//
#include <hip/hip_runtime.h>
#include <hip/hip_bf16.h>

typedef __attribute__((ext_vector_type(8))) short short8;
typedef __attribute__((ext_vector_type(4))) float f32x4;

#define NTOK 576
#define DIM  1024
#define NB   4
#define NH   8
#define HD   128
#define KDIR 8
#define KN   4608
#define NSPLIT 8

__device__ __forceinline__ float us2f(unsigned short u) {
    unsigned int x = ((unsigned int)u) << 16;
    return __uint_as_float(x);
}
__device__ __forceinline__ unsigned short f2us(float f) {
    unsigned int x = __float_as_uint(f);
    unsigned int r = x + 0x7fffu + ((x >> 16) & 1u);
    return (unsigned short)(r >> 16);
}

typedef __attribute__((address_space(3))) unsigned int lds_uint;
typedef const __attribute__((address_space(1))) unsigned int glb_uint;
__device__ __forceinline__ void async16(const unsigned short* g, unsigned short* l) {
    __builtin_amdgcn_global_load_lds((glb_uint*)g, (lds_uint*)l, 16, 0, 0);
}

// meta[0] = 1 if device buffers are bf16, 0 if f32
__global__ void detect_kernel(const unsigned int* __restrict__ src, int* meta)
{
    if (threadIdx.x == 0) {
        int cnt = 0;
        for (int i = 0; i < 256; ++i) {
            unsigned u = src[(long)i * 16384] & 0xFFFFu;
            unsigned e = (u >> 7) & 0xFFu;
            cnt += (e >= 90 && e <= 150) ? 1 : 0;
        }
        meta[0] = (cnt >= 192) ? 1 : 0;
    }
}

__global__ __launch_bounds__(256)
void conv_kernel(const void* __restrict__ src, unsigned short* __restrict__ dst,
                 long n, const int* __restrict__ meta)
{
    long i = (long)blockIdx.x * 256 + threadIdx.x;
    const long st = (long)gridDim.x * 256;
    if (meta[0]) {
        const unsigned short* s = (const unsigned short*)src;
        for (; i < n; i += st) dst[i] = s[i];
    } else {
        const float* s = (const float*)src;
        for (; i < n; i += st) dst[i] = f2us(s[i]);
    }
}

// dirW [8][1024 d][1024 e] -> dWT [8][1024 e][1024 d], with dtype conversion
__global__ __launch_bounds__(256)
void transpose_conv(const void* __restrict__ src, unsigned short* __restrict__ dst,
                    const int* __restrict__ meta)
{
    const int k = blockIdx.y;
    const int ty = blockIdx.x >> 5, tx = blockIdx.x & 31;
    const int d0 = ty * 32, e0 = tx * 32;
    __shared__ float tl[32][33];
    const int t = threadIdx.x;
    const int row = t >> 3, c4 = (t & 7) * 4;
    const long sbase = ((long)k * 1024 + d0 + row) * 1024 + e0 + c4;
    if (meta[0]) {
        const unsigned short* s = (const unsigned short*)src;
        ushort4 v = *(const ushort4*)(s + sbase);
        tl[row][c4+0] = us2f(v.x); tl[row][c4+1] = us2f(v.y);
        tl[row][c4+2] = us2f(v.z); tl[row][c4+3] = us2f(v.w);
    } else {
        const float* s = (const float*)src;
        float4 v = *(const float4*)(s + sbase);
        tl[row][c4+0] = v.x; tl[row][c4+1] = v.y;
        tl[row][c4+2] = v.z; tl[row][c4+3] = v.w;
    }
    __syncthreads();
    ushort4 o;
    o.x = f2us(tl[c4+0][row]); o.y = f2us(tl[c4+1][row]);
    o.z = f2us(tl[c4+2][row]); o.w = f2us(tl[c4+3][row]);
    *(ushort4*)(dst + ((long)k * 1024 + e0 + row) * 1024 + d0 + c4) = o;
}

// C = A[M x 1024] @ B^T + bias.  B row-major (N=1024, K=1024). BK=64, tile 128x128.
// global_load_lds staging with pre-swizzled source; XOR-swizzled ds_read_b128.
// MODE: 0 = row-major C[rg*1024+cg]
//       1 = Qh   [((b*8+h)*576 + n)*128 + d]
//       2 = Kh   [((b*8+h)*4608 + kv)*128 + d]
//       3 = VTh  [((b*8+h)*128 + d)*4608 + kv]
//       4 = dirs [(b*4608 + z*576 + n)*1024 + cg]
template<int MODE>
__global__ __launch_bounds__(256)
void gemm_glds(const unsigned short* __restrict__ A, const unsigned short* __restrict__ Bw,
               const unsigned short* __restrict__ bias, unsigned short* __restrict__ C,
               int M, long bStride, long biasStride)
{
    const int z = blockIdx.y;
    const unsigned short* Bb = Bw + (long)z * bStride;
    const unsigned short* Gb = bias + (long)z * biasStride;
    const int tm = blockIdx.x >> 3;
    const int tn = blockIdx.x & 7;

    __shared__ __align__(16) unsigned short As[128 * 64];
    __shared__ __align__(16) unsigned short Bs[128 * 64];

    const int tid = threadIdx.x, lane = tid & 63, wid = tid >> 6;
    const int wm = wid >> 1, wn = wid & 1;
    const int r0 = lane & 15, hi = lane >> 4;
    const int lr = lane >> 3;       // row-within-load (0..7)
    const int lg = lane & 7;        // 16B group within 128B row

    f32x4 zz = {0.f, 0.f, 0.f, 0.f};
    f32x4 acc[4][4];
    #pragma unroll
    for (int i = 0; i < 4; ++i)
        #pragma unroll
        for (int j = 0; j < 4; ++j) acc[i][j] = zz;

    const int sgc = ((lg ^ (lr & 7)) << 3);  // swizzled col (ushorts) for staging

    for (int k0 = 0; k0 < 1024; k0 += 64) {
        #pragma unroll
        for (int j = 0; j < 4; ++j) {
            int rb = wid * 32 + j * 8;          // 8 rows per wave-load
            int r = rb + lr;
            async16(A  + (long)(tm * 128 + r) * 1024 + k0 + sgc, &As[rb * 64]);
            async16(Bb + (long)(tn * 128 + r) * 1024 + k0 + sgc, &Bs[rb * 64]);
        }
        __syncthreads();
        #pragma unroll
        for (int kd = 0; kd < 2; ++kd) {
            const int pg = ((kd * 4 + hi) ^ (r0 & 7)) << 3;
            short8 af[4], bfr[4];
            #pragma unroll
            for (int mi = 0; mi < 4; ++mi)
                af[mi] = *reinterpret_cast<const short8*>(&As[(wm * 64 + mi * 16 + r0) * 64 + pg]);
            #pragma unroll
            for (int ni = 0; ni < 4; ++ni)
                bfr[ni] = *reinterpret_cast<const short8*>(&Bs[(wn * 64 + ni * 16 + r0) * 64 + pg]);
            #pragma unroll
            for (int mi = 0; mi < 4; ++mi)
                #pragma unroll
                for (int ni = 0; ni < 4; ++ni)
                    acc[mi][ni] = __builtin_amdgcn_mfma_f32_16x16x32_bf16(af[mi], bfr[ni], acc[mi][ni], 0, 0, 0);
        }
        __syncthreads();
    }

    const int jr = hi * 4;
    #pragma unroll
    for (int ni = 0; ni < 4; ++ni) {
        int cg = tn * 128 + wn * 64 + ni * 16 + r0;
        float bv = us2f(Gb[cg]);
        #pragma unroll
        for (int mi = 0; mi < 4; ++mi) {
            #pragma unroll
            for (int j = 0; j < 4; ++j) {
                int rg = tm * 128 + wm * 64 + mi * 16 + jr + j;
                float val = acc[mi][ni][j] + bv;
                long idx;
                if constexpr (MODE == 0) {
                    idx = (long)rg * 1024 + cg;
                } else if constexpr (MODE == 1) {
                    int b = rg / 576, n = rg - b * 576;
                    int h = cg >> 7, d = cg & 127;
                    idx = ((long)(b * 8 + h) * 576 + n) * 128 + d;
                } else if constexpr (MODE == 2) {
                    int b = rg / 4608, kv = rg - b * 4608;
                    int h = cg >> 7, d = cg & 127;
                    idx = ((long)(b * 8 + h) * 4608 + kv) * 128 + d;
                } else if constexpr (MODE == 3) {
                    int b = rg / 4608, kv = rg - b * 4608;
                    int h = cg >> 7, d = cg & 127;
                    idx = ((long)(b * 8 + h) * 128 + d) * 4608 + kv;
                } else {
                    int b = rg / 576, n = rg - b * 576;
                    idx = ((long)b * 4608 + (long)z * 576 + n) * 1024 + cg;
                }
                C[idx] = f2us(val);
            }
        }
    }
}

// KV-split flash attention. grid (9 q-tiles, 32 bh, 8 splits), 4 waves.
// Kh [bh][kv][128], VTh [bh][128][kv]. Writes normalized partial O (bf16) + (m,l).
__global__ __launch_bounds__(256)
void attn_kernel2(const unsigned short* __restrict__ Qh, const unsigned short* __restrict__ Kh,
                  const unsigned short* __restrict__ VTh, unsigned short* __restrict__ Opart,
                  float2* __restrict__ Ml)
{
    const int qt = blockIdx.x;
    const int bh = blockIdx.y;
    const int sp = blockIdx.z;
    const int tid = threadIdx.x;
    const int lane = tid & 63, wid = tid >> 6;
    const int r0 = lane & 15, hi = lane >> 4;
    const int k8 = hi * 8, jr = hi * 4;

    __shared__ __align__(16) unsigned short Ks[64 * 128];
    __shared__ __align__(16) unsigned short VT[128 * 64];
    __shared__ __align__(16) unsigned short Pl[4 * 16 * 64];
    unsigned short* Plw = &Pl[wid * 1024];

    short8 qf[4];
    {
        const long qoff = ((long)bh * NTOK + qt * 64 + wid * 16 + r0) * HD;
        #pragma unroll
        for (int kd = 0; kd < 4; ++kd)
            qf[kd] = *reinterpret_cast<const short8*>(Qh + qoff + kd * 32 + k8);
    }

    f32x4 zz = {0.f, 0.f, 0.f, 0.f};
    f32x4 oacc[8];
    #pragma unroll
    for (int i = 0; i < 8; ++i) oacc[i] = zz;
    float mrun[4], lrun[4];
    #pragma unroll
    for (int j = 0; j < 4; ++j) { mrun[j] = -1e30f; lrun[j] = 0.f; }

    const float sc = 0.08838834764831845f;  // 1/sqrt(128)
    const unsigned short* kbase0 = Kh + (long)bh * KN * HD;
    const unsigned short* vbase  = VTh + (long)bh * HD * KN;

    const int rK = (wid * 4) * 4 + hi;              // per-wave K staging rows (recomputed per j)
    for (int kt = 0; kt < KN / NSPLIT / 64; ++kt) {
        const int kv0 = sp * (KN / NSPLIT) + kt * 64;
        const unsigned short* kb = kbase0 + (long)kv0 * HD;
        #pragma unroll
        for (int j = 0; j < 4; ++j) {
            int li = wid * 4 + j;
            int r = li * 4 + hi;                                  // K tile row 0..63
            int scK = (((lane & 15) ^ (r & 7)) << 3);
            async16(kb + (long)r * HD + scK, &Ks[(li * 4) * 128]);
            int rv = li * 8 + (lane >> 3);                        // V tile row (=d) 0..127
            int scV = (((lane & 7) ^ (rv & 7)) << 3);
            async16(vbase + (long)rv * KN + kv0 + scV, &VT[(li * 8) * 64]);
        }
        __syncthreads();

        f32x4 s[4];
        #pragma unroll
        for (int nb = 0; nb < 4; ++nb) s[nb] = zz;
        #pragma unroll
        for (int nb = 0; nb < 4; ++nb) {
            const int krow = nb * 16 + r0;
            #pragma unroll
            for (int kd = 0; kd < 4; ++kd) {
                short8 kf = *reinterpret_cast<const short8*>(
                    &Ks[krow * 128 + (((kd * 4 + hi) ^ (r0 & 7)) << 3)]);
                s[nb] = __builtin_amdgcn_mfma_f32_16x16x32_bf16(qf[kd], kf, s[nb], 0, 0, 0);
            }
        }
        #pragma unroll
        for (int nb = 0; nb < 4; ++nb)
            #pragma unroll
            for (int j = 0; j < 4; ++j)
                s[nb][j] *= sc;

        float mt[4], rt[4], scl[4];
        #pragma unroll
        for (int j = 0; j < 4; ++j)
            mt[j] = fmaxf(fmaxf(s[0][j], s[1][j]), fmaxf(s[2][j], s[3][j]));
        #pragma unroll
        for (int off = 1; off < 16; off <<= 1)
            #pragma unroll
            for (int j = 0; j < 4; ++j)
                mt[j] = fmaxf(mt[j], __shfl_xor(mt[j], off));
        #pragma unroll
        for (int j = 0; j < 4; ++j) {
            float mn = fmaxf(mrun[j], mt[j]);
            scl[j] = __expf(mrun[j] - mn);
            mrun[j] = mn;
            rt[j] = 0.f;
        }
        #pragma unroll
        for (int nb = 0; nb < 4; ++nb)
            #pragma unroll
            for (int j = 0; j < 4; ++j) {
                float p = __expf(s[nb][j] - mrun[j]);
                rt[j] += p;
                int row = jr + j;
                int g = nb * 2 + (r0 >> 3);
                Plw[row * 64 + ((g ^ (row & 7)) << 3) + (r0 & 7)] = f2us(p);
            }
        #pragma unroll
        for (int off = 1; off < 16; off <<= 1)
            #pragma unroll
            for (int j = 0; j < 4; ++j)
                rt[j] += __shfl_xor(rt[j], off);
        #pragma unroll
        for (int j = 0; j < 4; ++j)
            lrun[j] = lrun[j] * scl[j] + rt[j];
        #pragma unroll
        for (int db = 0; db < 8; ++db)
            #pragma unroll
            for (int j = 0; j < 4; ++j)
                oacc[db][j] *= scl[j];

        #pragma unroll
        for (int kb2 = 0; kb2 < 2; ++kb2) {
            const int pg = ((kb2 * 4 + hi) ^ (r0 & 7)) << 3;
            short8 ap = *reinterpret_cast<const short8*>(&Plw[r0 * 64 + pg]);
            #pragma unroll
            for (int db = 0; db < 8; ++db) {
                short8 vf = *reinterpret_cast<const short8*>(&VT[(db * 16 + r0) * 64 + pg]);
                oacc[db] = __builtin_amdgcn_mfma_f32_16x16x32_bf16(ap, vf, oacc[db], 0, 0, 0);
            }
        }
        __syncthreads();
    }

    float inv[4];
    #pragma unroll
    for (int j = 0; j < 4; ++j) inv[j] = 1.f / lrun[j];
    const long po = ((long)(sp * 32 + bh) * NTOK + qt * 64 + wid * 16) * HD;
    #pragma unroll
    for (int db = 0; db < 8; ++db)
        #pragma unroll
        for (int j = 0; j < 4; ++j)
            Opart[po + (long)(jr + j) * HD + db * 16 + r0] = f2us(oacc[db][j] * inv[j]);
    if (r0 == 0) {
        const long mo = (long)(sp * 32 + bh) * NTOK + qt * 64 + wid * 16;
        #pragma unroll
        for (int j = 0; j < 4; ++j)
            Ml[mo + jr + j] = make_float2(mrun[j], lrun[j]);
    }
}

// Combine NSPLIT partials -> Ob[(b*576+n)*1024 + h*128 + d]
__global__ __launch_bounds__(256)
void attn_reduce(const unsigned short* __restrict__ Opart, const float2* __restrict__ Ml,
                 unsigned short* __restrict__ Ob)
{
    const int qt = blockIdx.x, bh = blockIdx.y;
    const int t = threadIdx.x;
    const int rl = t >> 2, dc = (t & 3) * 32;
    const int q = qt * 64 + rl;

    float m[NSPLIT], l[NSPLIT];
    float M = -1e30f;
    #pragma unroll
    for (int sp = 0; sp < NSPLIT; ++sp) {
        float2 v = Ml[(long)(sp * 32 + bh) * NTOK + q];
        m[sp] = v.x; l[sp] = v.y;
        M = fmaxf(M, v.x);
    }
    float w[NSPLIT], denom = 0.f;
    #pragma unroll
    for (int sp = 0; sp < NSPLIT; ++sp) {
        w[sp] = l[sp] * __expf(m[sp] - M);
        denom += w[sp];
    }
    const float inv = 1.f / denom;
    const int b = bh >> 3, h = bh & 7;
    #pragma unroll
    for (int dj = 0; dj < 4; ++dj) {
        float a[8];
        #pragma unroll
        for (int e = 0; e < 8; ++e) a[e] = 0.f;
        #pragma unroll
        for (int sp = 0; sp < NSPLIT; ++sp) {
            short8 v = *reinterpret_cast<const short8*>(
                &Opart[((long)(sp * 32 + bh) * NTOK + q) * HD + dc + dj * 8]);
            #pragma unroll
            for (int e = 0; e < 8; ++e)
                a[e] += w[sp] * us2f((unsigned short)v[e]);
        }
        short8 o;
        #pragma unroll
        for (int e = 0; e < 8; ++e) o[e] = (short)f2us(a[e] * inv);
        *reinterpret_cast<short8*>(&Ob[((long)b * NTOK + q) * 1024 + h * 128 + dc + dj * 8]) = o;
    }
}

// LayerNorm(y)*g + b + vision; output dtype per meta[0]
__global__ __launch_bounds__(256)
void ln2_kernel(const unsigned short* __restrict__ Y, const unsigned short* __restrict__ g,
                const unsigned short* __restrict__ be, const unsigned short* __restrict__ vis,
                void* __restrict__ dout, const int* __restrict__ meta)
{
    const int row = blockIdx.x;
    const int tid = threadIdx.x;
    const int lane = tid & 63, wid = tid >> 6;
    const unsigned short* yr = Y + (long)row * DIM;
    ushort4 raw = reinterpret_cast<const ushort4*>(yr)[tid];
    float v[4];
    v[0] = us2f(raw.x); v[1] = us2f(raw.y); v[2] = us2f(raw.z); v[3] = us2f(raw.w);
    float s1 = 0.f, s2 = 0.f;
    #pragma unroll
    for (int i = 0; i < 4; ++i) { s1 += v[i]; s2 += v[i] * v[i]; }
    #pragma unroll
    for (int off = 1; off < 64; off <<= 1) {
        s1 += __shfl_xor(s1, off);
        s2 += __shfl_xor(s2, off);
    }
    __shared__ float red[2][4];
    if (lane == 0) { red[0][wid] = s1; red[1][wid] = s2; }
    __syncthreads();
    s1 = red[0][0] + red[0][1] + red[0][2] + red[0][3];
    s2 = red[1][0] + red[1][1] + red[1][2] + red[1][3];
    const float mu = s1 * (1.f / DIM);
    const float var = s2 * (1.f / DIM) - mu * mu;
    const float inv = rsqrtf(var + 1e-5f);
    ushort4 gg = reinterpret_cast<const ushort4*>(g)[tid];
    ushort4 bb = reinterpret_cast<const ushort4*>(be)[tid];
    ushort4 vv = reinterpret_cast<const ushort4*>(vis + (long)row * DIM)[tid];
    float o0 = (v[0] - mu) * inv * us2f(gg.x) + us2f(bb.x) + us2f(vv.x);
    float o1 = (v[1] - mu) * inv * us2f(gg.y) + us2f(bb.y) + us2f(vv.y);
    float o2 = (v[2] - mu) * inv * us2f(gg.z) + us2f(bb.z) + us2f(vv.z);
    float o3 = (v[3] - mu) * inv * us2f(gg.w) + us2f(bb.w) + us2f(vv.w);
    if (meta[0]) {
        ushort4 o;
        o.x = f2us(o0); o.y = f2us(o1); o.z = f2us(o2); o.w = f2us(o3);
        reinterpret_cast<ushort4*>((unsigned short*)dout + (long)row * DIM)[tid] = o;
    } else {
        float4 o = make_float4(o0, o1, o2, o3);
        reinterpret_cast<float4*>((float*)dout + (long)row * DIM)[tid] = o;
    }
}

extern "C" void kernel_launch(void* const* d_in, const int* in_sizes, int n_in,
                              void* d_out, int out_size, void* d_ws, size_t ws_size,
                              hipStream_t stream)
{
    // scan_idx (d_in[11]) unused: all 8 scans are bijections on the 576 cells and
    // softmax over the full K*N key axis (K,V share row order) is permutation-
    // invariant per direction block -> gather elided.
    unsigned long long w = (unsigned long long)d_ws;
    int* meta = (int*)w; w += 256;

    // converted-input buffers (dirW handled separately via transpose_conv)
    const int cidx[10] = {0, 2, 3, 4, 5, 6, 7, 8, 9, 10};
    const long csz[10] = {
        (long)NB * NTOK * DIM,  // vision
        (long)KDIR * DIM,       // dirb
        3L * DIM * DIM,         // inW
        3L * DIM,               // inB
        (long)DIM * DIM,        // outW
        DIM,                    // outB
        (long)DIM * DIM,        // finW
        DIM, DIM, DIM           // finB, lng, lnb
    };
    unsigned short* cv[10];
    for (int i = 0; i < 10; ++i) {
        cv[i] = (unsigned short*)w;
        w += (csz[i] * 2 + 255) & ~255ULL;
    }
    unsigned short* dWT = (unsigned short*)w; w += (long)KDIR * DIM * DIM * 2;

    const size_t big = (size_t)NB * KDIR * NTOK * DIM * 2;   // 37.75 MB
    const size_t sml = (size_t)NB * NTOK * DIM * 2;          // 4.72 MB
    unsigned short* dirs = (unsigned short*)w; w += big;     // aliased as Opart later
    unsigned short* Kh   = (unsigned short*)w; w += big;
    unsigned short* VTh  = (unsigned short*)w; w += big;
    unsigned short* Qh   = (unsigned short*)w; w += sml;
    unsigned short* Ob   = (unsigned short*)w; w += sml;
    unsigned short* Fu   = (unsigned short*)w; w += sml;
    unsigned short* Y2   = (unsigned short*)w; w += sml;
    float2* Ml = (float2*)w; w += (long)NSPLIT * 32 * NTOK * sizeof(float2);
    unsigned short* Opart = dirs;   // dirs is dead once K/V GEMMs complete

    const unsigned short* vision = cv[0];
    const unsigned short* dirb = cv[1];
    const unsigned short* inW = cv[2];
    const unsigned short* inB = cv[3];
    const unsigned short* outW = cv[4];
    const unsigned short* outB = cv[5];
    const unsigned short* finW = cv[6];
    const unsigned short* finB = cv[7];
    const unsigned short* lng = cv[8];
    const unsigned short* lnbt = cv[9];

    dim3 blk(256, 1, 1);

    // 0. dtype detect
    detect_kernel<<<dim3(1), dim3(64), 0, stream>>>((const unsigned int*)d_in[1], meta);

    // 1. convert inputs to bf16 (+ transposed dirW)
    for (int i = 0; i < 10; ++i)
        conv_kernel<<<dim3(256), blk, 0, stream>>>(d_in[cidx[i]], cv[i], csz[i], meta);
    transpose_conv<<<dim3(1024, KDIR), blk, 0, stream>>>(d_in[1], dWT, meta);

    // 2. dirs[b,k] = vision[b] @ dirW[k] + dirb[k]; flat GEMM M=2304, batch z=k
    gemm_glds<4><<<dim3(18 * 8, KDIR), blk, 0, stream>>>(
        vision, dWT, dirb, dirs, NB * NTOK, (long)DIM * DIM, DIM);

    // 3. Q -> Qh [b,h,n,d]
    gemm_glds<1><<<dim3(18 * 8, 1), blk, 0, stream>>>(
        vision, inW, inB, Qh, NB * NTOK, 0L, 0L);

    // 4. K -> Kh [b,h,kv,d]
    gemm_glds<2><<<dim3(144 * 8, 1), blk, 0, stream>>>(
        dirs, inW + DIM * DIM, inB + DIM, Kh, NB * KN, 0L, 0L);

    // 5. V -> VTh [b,h,d,kv]  (pre-transposed for attention PV)
    gemm_glds<3><<<dim3(144 * 8, 1), blk, 0, stream>>>(
        dirs, inW + 2 * DIM * DIM, inB + 2 * DIM, VTh, NB * KN, 0L, 0L);

    // 6. KV-split flash attention -> Opart (aliases dirs) + Ml
    attn_kernel2<<<dim3(9, 32, NSPLIT), blk, 0, stream>>>(Qh, Kh, VTh, Opart, Ml);

    // 7. combine partials -> Ob [b,n,h*128+d]
    attn_reduce<<<dim3(9, 32), blk, 0, stream>>>(Opart, Ml, Ob);

    // 8. fused = Ob @ out_proj^T + b
    gemm_glds<0><<<dim3(18 * 8, 1), blk, 0, stream>>>(
        Ob, outW, outB, Fu, NB * NTOK, 0L, 0L);

    // 9. y = fused @ fin^T + b
    gemm_glds<0><<<dim3(18 * 8, 1), blk, 0, stream>>>(
        Fu, finW, finB, Y2, NB * NTOK, 0L, 0L);

    // 10. LayerNorm + residual -> d_out
    ln2_kernel<<<dim3(NB * NTOK), blk, 0, stream>>>(Y2, lng, lnbt, vision, d_out, meta);
}

// Round 4
// 440.663 us; speedup vs baseline: 2.2655x; 1.1132x over previous
//
#include <hip/hip_runtime.h>
#include <hip/hip_bf16.h>

typedef __attribute__((ext_vector_type(8))) short short8;
typedef __attribute__((ext_vector_type(4))) float f32x4;

#define NTOK 576
#define DIM  1024
#define NB   4
#define NH   8
#define HD   128
#define KDIR 8
#define KN   4608
#define NSPLIT 8

__device__ __forceinline__ float us2f(unsigned short u) {
    unsigned int x = ((unsigned int)u) << 16;
    return __uint_as_float(x);
}
__device__ __forceinline__ unsigned short f2us(float f) {
    unsigned int x = __float_as_uint(f);
    unsigned int r = x + 0x7fffu + ((x >> 16) & 1u);
    return (unsigned short)(r >> 16);
}
__device__ __forceinline__ unsigned short cvt_bf16(float f) {
    unsigned int pk;
    asm("v_cvt_pk_bf16_f32 %0, %1, %2" : "=v"(pk) : "v"(f), "v"(f));
    return (unsigned short)(pk & 0xffffu);
}

typedef __attribute__((address_space(3))) unsigned int lds_uint;
typedef const __attribute__((address_space(1))) unsigned int glb_uint;
__device__ __forceinline__ void async16(const unsigned short* g, unsigned short* l) {
    __builtin_amdgcn_global_load_lds((glb_uint*)g, (lds_uint*)l, 16, 0, 0);
}

// meta[0] = 1 if device buffers are bf16, 0 if f32
__global__ void detect_kernel(const unsigned int* __restrict__ src, int* meta)
{
    if (threadIdx.x == 0) {
        int cnt = 0;
        for (int i = 0; i < 256; ++i) {
            unsigned u = src[(long)i * 16384] & 0xFFFFu;
            unsigned e = (u >> 7) & 0xFFu;
            cnt += (e >= 90 && e <= 150) ? 1 : 0;
        }
        meta[0] = (cnt >= 192) ? 1 : 0;
    }
}

// vectorized f32->bf16 conversion (n multiple of 4)
__global__ __launch_bounds__(256)
void conv_kernel(const void* __restrict__ src, unsigned short* __restrict__ dst,
                 long n4, const int* __restrict__ meta)
{
    long i = (long)blockIdx.x * 256 + threadIdx.x;
    const long st = (long)gridDim.x * 256;
    if (meta[0]) {
        const ushort4* s = (const ushort4*)src;
        ushort4* d = (ushort4*)dst;
        for (; i < n4; i += st) d[i] = s[i];
    } else {
        const float4* s = (const float4*)src;
        ushort4* d = (ushort4*)dst;
        for (; i < n4; i += st) {
            float4 v = s[i];
            ushort4 o;
            o.x = f2us(v.x); o.y = f2us(v.y); o.z = f2us(v.z); o.w = f2us(v.w);
            d[i] = o;
        }
    }
}

// dirW [8][1024 d][1024 e] -> dWT [8][1024 e][1024 d], with dtype conversion
__global__ __launch_bounds__(256)
void transpose_conv(const void* __restrict__ src, unsigned short* __restrict__ dst,
                    const int* __restrict__ meta)
{
    const int k = blockIdx.y;
    const int ty = blockIdx.x >> 5, tx = blockIdx.x & 31;
    const int d0 = ty * 32, e0 = tx * 32;
    __shared__ float tl[32][33];
    const int t = threadIdx.x;
    const int row = t >> 3, c4 = (t & 7) * 4;
    const long sbase = ((long)k * 1024 + d0 + row) * 1024 + e0 + c4;
    if (meta[0]) {
        const unsigned short* s = (const unsigned short*)src;
        ushort4 v = *(const ushort4*)(s + sbase);
        tl[row][c4+0] = us2f(v.x); tl[row][c4+1] = us2f(v.y);
        tl[row][c4+2] = us2f(v.z); tl[row][c4+3] = us2f(v.w);
    } else {
        const float* s = (const float*)src;
        float4 v = *(const float4*)(s + sbase);
        tl[row][c4+0] = v.x; tl[row][c4+1] = v.y;
        tl[row][c4+2] = v.z; tl[row][c4+3] = v.w;
    }
    __syncthreads();
    ushort4 o;
    o.x = f2us(tl[c4+0][row]); o.y = f2us(tl[c4+1][row]);
    o.z = f2us(tl[c4+2][row]); o.w = f2us(tl[c4+3][row]);
    *(ushort4*)(dst + ((long)k * 1024 + e0 + row) * 1024 + d0 + c4) = o;
}

// C = A[M x 1024] @ B^T + bias.  B row-major (TN*128 rows, K=1024). BK=64, tile 128x128.
// MODE: 0 = row-major C[rg*1024+cg]
//       1 = Qh   [((b*8+h)*576 + n)*128 + d]
//       4 = dirs [(b*4608 + z*576 + n)*1024 + cg]
//       5 = fused KV: cg<1024 -> Kh [bh][kv][128]; cg>=1024 -> VTh [bh][128][kv]
template<int MODE, int TN>
__global__ __launch_bounds__(256)
void gemm_glds(const unsigned short* __restrict__ A, const unsigned short* __restrict__ Bw,
               const unsigned short* __restrict__ bias, unsigned short* __restrict__ C,
               unsigned short* __restrict__ C2,
               int M, long bStride, long biasStride)
{
    const int z = blockIdx.y;
    const unsigned short* Bb = Bw + (long)z * bStride;
    const unsigned short* Gb = bias + (long)z * biasStride;
    const int tm = blockIdx.x / TN;
    const int tn = blockIdx.x % TN;

    __shared__ __align__(16) unsigned short As[128 * 64];
    __shared__ __align__(16) unsigned short Bs[128 * 64];

    const int tid = threadIdx.x, lane = tid & 63, wid = tid >> 6;
    const int wm = wid >> 1, wn = wid & 1;
    const int r0 = lane & 15, hi = lane >> 4;
    const int lr = lane >> 3;       // row-within-load (0..7)
    const int lg = lane & 7;        // 16B group within 128B row

    f32x4 zz = {0.f, 0.f, 0.f, 0.f};
    f32x4 acc[4][4];
    #pragma unroll
    for (int i = 0; i < 4; ++i)
        #pragma unroll
        for (int j = 0; j < 4; ++j) acc[i][j] = zz;

    const int sgc = ((lg ^ (lr & 7)) << 3);  // swizzled col (ushorts) for staging

    for (int k0 = 0; k0 < 1024; k0 += 64) {
        #pragma unroll
        for (int j = 0; j < 4; ++j) {
            int rb = wid * 32 + j * 8;          // 8 rows per wave-load
            int r = rb + lr;
            async16(A  + (long)(tm * 128 + r) * 1024 + k0 + sgc, &As[rb * 64]);
            async16(Bb + (long)(tn * 128 + r) * 1024 + k0 + sgc, &Bs[rb * 64]);
        }
        __syncthreads();
        __builtin_amdgcn_s_setprio(1);
        #pragma unroll
        for (int kd = 0; kd < 2; ++kd) {
            const int pg = ((kd * 4 + hi) ^ (r0 & 7)) << 3;
            short8 af[4], bfr[4];
            #pragma unroll
            for (int mi = 0; mi < 4; ++mi)
                af[mi] = *reinterpret_cast<const short8*>(&As[(wm * 64 + mi * 16 + r0) * 64 + pg]);
            #pragma unroll
            for (int ni = 0; ni < 4; ++ni)
                bfr[ni] = *reinterpret_cast<const short8*>(&Bs[(wn * 64 + ni * 16 + r0) * 64 + pg]);
            #pragma unroll
            for (int mi = 0; mi < 4; ++mi)
                #pragma unroll
                for (int ni = 0; ni < 4; ++ni)
                    acc[mi][ni] = __builtin_amdgcn_mfma_f32_16x16x32_bf16(af[mi], bfr[ni], acc[mi][ni], 0, 0, 0);
        }
        __builtin_amdgcn_s_setprio(0);
        __syncthreads();
    }

    const int jr = hi * 4;
    #pragma unroll
    for (int ni = 0; ni < 4; ++ni) {
        int cg = tn * 128 + wn * 64 + ni * 16 + r0;
        float bv = us2f(Gb[cg]);
        if constexpr (MODE == 5) {
            if (cg >= 1024) {
                // V^T epilogue: pack 4 contiguous kv into one 8B store
                int cg2 = cg - 1024;
                int h = cg2 >> 7, d = cg2 & 127;
                #pragma unroll
                for (int mi = 0; mi < 4; ++mi) {
                    int rgb = tm * 128 + wm * 64 + mi * 16 + jr;
                    int b = rgb / 4608, kv = rgb - b * 4608;
                    ushort4 o;
                    o.x = f2us(acc[mi][ni][0] + bv);
                    o.y = f2us(acc[mi][ni][1] + bv);
                    o.z = f2us(acc[mi][ni][2] + bv);
                    o.w = f2us(acc[mi][ni][3] + bv);
                    *(ushort4*)&C2[((long)(b * 8 + h) * 128 + d) * 4608 + kv] = o;
                }
                continue;
            }
        }
        #pragma unroll
        for (int mi = 0; mi < 4; ++mi) {
            #pragma unroll
            for (int j = 0; j < 4; ++j) {
                int rg = tm * 128 + wm * 64 + mi * 16 + jr + j;
                float val = acc[mi][ni][j] + bv;
                long idx;
                if constexpr (MODE == 0) {
                    idx = (long)rg * 1024 + cg;
                } else if constexpr (MODE == 1) {
                    int b = rg / 576, n = rg - b * 576;
                    int h = cg >> 7, d = cg & 127;
                    idx = ((long)(b * 8 + h) * 576 + n) * 128 + d;
                } else if constexpr (MODE == 5) {
                    int b = rg / 4608, kv = rg - b * 4608;
                    int h = cg >> 7, d = cg & 127;
                    idx = ((long)(b * 8 + h) * 4608 + kv) * 128 + d;
                } else {
                    int b = rg / 576, n = rg - b * 576;
                    idx = ((long)b * 4608 + (long)z * 576 + n) * 1024 + cg;
                }
                C[idx] = f2us(val);
            }
        }
    }
}

// KV-split flash attention, XCD-swizzled linear grid of 9*32*8 = 2304 blocks.
// Q pre-scaled by 1/sqrt(128)*log2(e); softmax in exp2 domain; defer-max (thr=8).
__global__ __launch_bounds__(256)
void attn_kernel3(const unsigned short* __restrict__ Qh, const unsigned short* __restrict__ Kh,
                  const unsigned short* __restrict__ VTh, unsigned short* __restrict__ Opart,
                  float2* __restrict__ Ml)
{
    // bijective XCD grouping: all 9 q-tiles of one (bh,sp) on one XCD
    const int bid = blockIdx.x;
    const int logical = (bid & 7) * 288 + (bid >> 3);
    const int bhsp = logical / 9;
    const int qt = logical - bhsp * 9;
    const int bh = bhsp >> 3;
    const int sp = bhsp & 7;

    const int tid = threadIdx.x;
    const int lane = tid & 63, wid = tid >> 6;
    const int r0 = lane & 15, hi = lane >> 4;
    const int k8 = hi * 8, jr = hi * 4;

    __shared__ __align__(16) unsigned short Ks[64 * 128];
    __shared__ __align__(16) unsigned short VT[128 * 64];
    __shared__ __align__(16) unsigned short Pl[4 * 16 * 64];
    unsigned short* Plw = &Pl[wid * 1024];

    const float SCL2 = 0.08838834764831845f * 1.4426950408889634f;
    short8 qf[4];
    {
        const long qoff = ((long)bh * NTOK + qt * 64 + wid * 16 + r0) * HD;
        #pragma unroll
        for (int kd = 0; kd < 4; ++kd) {
            short8 q = *reinterpret_cast<const short8*>(Qh + qoff + kd * 32 + k8);
            short8 qs;
            #pragma unroll
            for (int e = 0; e < 8; ++e)
                qs[e] = (short)cvt_bf16(us2f((unsigned short)q[e]) * SCL2);
            qf[kd] = qs;
        }
    }

    f32x4 zz = {0.f, 0.f, 0.f, 0.f};
    f32x4 oacc[8];
    #pragma unroll
    for (int i = 0; i < 8; ++i) oacc[i] = zz;
    float mrun[4], lrun[4];
    #pragma unroll
    for (int j = 0; j < 4; ++j) { mrun[j] = -1e30f; lrun[j] = 0.f; }

    const unsigned short* kbase0 = Kh + (long)bh * KN * HD;
    const unsigned short* vbase  = VTh + (long)bh * HD * KN;

    for (int kt = 0; kt < KN / NSPLIT / 64; ++kt) {
        const int kv0 = sp * (KN / NSPLIT) + kt * 64;
        const unsigned short* kb = kbase0 + (long)kv0 * HD;
        #pragma unroll
        for (int j = 0; j < 4; ++j) {
            int li = wid * 4 + j;
            int r = li * 4 + hi;                                  // K tile row 0..63
            int scK = (((lane & 15) ^ (r & 7)) << 3);
            async16(kb + (long)r * HD + scK, &Ks[(li * 4) * 128]);
            int rv = li * 8 + (lane >> 3);                        // V tile row (=d) 0..127
            int scV = (((lane & 7) ^ (rv & 7)) << 3);
            async16(vbase + (long)rv * KN + kv0 + scV, &VT[(li * 8) * 64]);
        }
        __syncthreads();

        f32x4 s[4];
        #pragma unroll
        for (int nb = 0; nb < 4; ++nb) s[nb] = zz;
        __builtin_amdgcn_s_setprio(1);
        #pragma unroll
        for (int nb = 0; nb < 4; ++nb) {
            const int krow = nb * 16 + r0;
            #pragma unroll
            for (int kd = 0; kd < 4; ++kd) {
                short8 kf = *reinterpret_cast<const short8*>(
                    &Ks[krow * 128 + (((kd * 4 + hi) ^ (r0 & 7)) << 3)]);
                s[nb] = __builtin_amdgcn_mfma_f32_16x16x32_bf16(qf[kd], kf, s[nb], 0, 0, 0);
            }
        }
        __builtin_amdgcn_s_setprio(0);

        // s is already in log2 domain (Q pre-scaled)
        float mt[4], rt[4];
        #pragma unroll
        for (int j = 0; j < 4; ++j)
            mt[j] = fmaxf(fmaxf(s[0][j], s[1][j]), fmaxf(s[2][j], s[3][j]));
        #pragma unroll
        for (int off = 1; off < 16; off <<= 1)
            #pragma unroll
            for (int j = 0; j < 4; ++j)
                mt[j] = fmaxf(mt[j], __shfl_xor(mt[j], off));
        float growth = fmaxf(fmaxf(mt[0] - mrun[0], mt[1] - mrun[1]),
                             fmaxf(mt[2] - mrun[2], mt[3] - mrun[3]));
        if (!__all(growth <= 8.0f)) {
            #pragma unroll
            for (int j = 0; j < 4; ++j) {
                float mn = fmaxf(mrun[j], mt[j]);
                float scl = exp2f(mrun[j] - mn);
                mrun[j] = mn;
                lrun[j] *= scl;
                #pragma unroll
                for (int db = 0; db < 8; ++db)
                    oacc[db][j] *= scl;
            }
        }
        #pragma unroll
        for (int j = 0; j < 4; ++j) rt[j] = 0.f;
        #pragma unroll
        for (int nb = 0; nb < 4; ++nb)
            #pragma unroll
            for (int j = 0; j < 4; ++j) {
                float p = exp2f(s[nb][j] - mrun[j]);
                rt[j] += p;
                int row = jr + j;
                int g = nb * 2 + (r0 >> 3);
                Plw[row * 64 + ((g ^ (row & 7)) << 3) + (r0 & 7)] = cvt_bf16(p);
            }
        #pragma unroll
        for (int off = 1; off < 16; off <<= 1)
            #pragma unroll
            for (int j = 0; j < 4; ++j)
                rt[j] += __shfl_xor(rt[j], off);
        #pragma unroll
        for (int j = 0; j < 4; ++j)
            lrun[j] += rt[j];

        __builtin_amdgcn_s_setprio(1);
        #pragma unroll
        for (int kb2 = 0; kb2 < 2; ++kb2) {
            const int pg = ((kb2 * 4 + hi) ^ (r0 & 7)) << 3;
            short8 ap = *reinterpret_cast<const short8*>(&Plw[r0 * 64 + pg]);
            #pragma unroll
            for (int db = 0; db < 8; ++db) {
                short8 vf = *reinterpret_cast<const short8*>(&VT[(db * 16 + r0) * 64 + pg]);
                oacc[db] = __builtin_amdgcn_mfma_f32_16x16x32_bf16(ap, vf, oacc[db], 0, 0, 0);
            }
        }
        __builtin_amdgcn_s_setprio(0);
        __syncthreads();
    }

    float inv[4];
    #pragma unroll
    for (int j = 0; j < 4; ++j) inv[j] = 1.f / lrun[j];
    const long po = ((long)(sp * 32 + bh) * NTOK + qt * 64 + wid * 16) * HD;
    #pragma unroll
    for (int db = 0; db < 8; ++db)
        #pragma unroll
        for (int j = 0; j < 4; ++j)
            Opart[po + (long)(jr + j) * HD + db * 16 + r0] = f2us(oacc[db][j] * inv[j]);
    if (r0 == 0) {
        const long mo = (long)(sp * 32 + bh) * NTOK + qt * 64 + wid * 16;
        #pragma unroll
        for (int j = 0; j < 4; ++j)
            Ml[mo + jr + j] = make_float2(mrun[j], lrun[j]);   // m in log2 domain
    }
}

// Combine NSPLIT partials -> Ob[(b*576+n)*1024 + h*128 + d]
__global__ __launch_bounds__(256)
void attn_reduce(const unsigned short* __restrict__ Opart, const float2* __restrict__ Ml,
                 unsigned short* __restrict__ Ob)
{
    const int qt = blockIdx.x, bh = blockIdx.y;
    const int t = threadIdx.x;
    const int rl = t >> 2, dc = (t & 3) * 32;
    const int q = qt * 64 + rl;

    float m[NSPLIT], l[NSPLIT];
    float M = -1e30f;
    #pragma unroll
    for (int sp = 0; sp < NSPLIT; ++sp) {
        float2 v = Ml[(long)(sp * 32 + bh) * NTOK + q];
        m[sp] = v.x; l[sp] = v.y;
        M = fmaxf(M, v.x);
    }
    float w[NSPLIT], denom = 0.f;
    #pragma unroll
    for (int sp = 0; sp < NSPLIT; ++sp) {
        w[sp] = l[sp] * exp2f(m[sp] - M);
        denom += w[sp];
    }
    const float inv = 1.f / denom;
    const int b = bh >> 3, h = bh & 7;
    #pragma unroll
    for (int dj = 0; dj < 4; ++dj) {
        float a[8];
        #pragma unroll
        for (int e = 0; e < 8; ++e) a[e] = 0.f;
        #pragma unroll
        for (int sp = 0; sp < NSPLIT; ++sp) {
            short8 v = *reinterpret_cast<const short8*>(
                &Opart[((long)(sp * 32 + bh) * NTOK + q) * HD + dc + dj * 8]);
            #pragma unroll
            for (int e = 0; e < 8; ++e)
                a[e] += w[sp] * us2f((unsigned short)v[e]);
        }
        short8 o;
        #pragma unroll
        for (int e = 0; e < 8; ++e) o[e] = (short)f2us(a[e] * inv);
        *reinterpret_cast<short8*>(&Ob[((long)b * NTOK + q) * 1024 + h * 128 + dc + dj * 8]) = o;
    }
}

// LayerNorm(y)*g + b + vision; output dtype per meta[0]
__global__ __launch_bounds__(256)
void ln2_kernel(const unsigned short* __restrict__ Y, const unsigned short* __restrict__ g,
                const unsigned short* __restrict__ be, const unsigned short* __restrict__ vis,
                void* __restrict__ dout, const int* __restrict__ meta)
{
    const int row = blockIdx.x;
    const int tid = threadIdx.x;
    const int lane = tid & 63, wid = tid >> 6;
    const unsigned short* yr = Y + (long)row * DIM;
    ushort4 raw = reinterpret_cast<const ushort4*>(yr)[tid];
    float v[4];
    v[0] = us2f(raw.x); v[1] = us2f(raw.y); v[2] = us2f(raw.z); v[3] = us2f(raw.w);
    float s1 = 0.f, s2 = 0.f;
    #pragma unroll
    for (int i = 0; i < 4; ++i) { s1 += v[i]; s2 += v[i] * v[i]; }
    #pragma unroll
    for (int off = 1; off < 64; off <<= 1) {
        s1 += __shfl_xor(s1, off);
        s2 += __shfl_xor(s2, off);
    }
    __shared__ float red[2][4];
    if (lane == 0) { red[0][wid] = s1; red[1][wid] = s2; }
    __syncthreads();
    s1 = red[0][0] + red[0][1] + red[0][2] + red[0][3];
    s2 = red[1][0] + red[1][1] + red[1][2] + red[1][3];
    const float mu = s1 * (1.f / DIM);
    const float var = s2 * (1.f / DIM) - mu * mu;
    const float inv = rsqrtf(var + 1e-5f);
    ushort4 gg = reinterpret_cast<const ushort4*>(g)[tid];
    ushort4 bb = reinterpret_cast<const ushort4*>(be)[tid];
    ushort4 vv = reinterpret_cast<const ushort4*>(vis + (long)row * DIM)[tid];
    float o0 = (v[0] - mu) * inv * us2f(gg.x) + us2f(bb.x) + us2f(vv.x);
    float o1 = (v[1] - mu) * inv * us2f(gg.y) + us2f(bb.y) + us2f(vv.y);
    float o2 = (v[2] - mu) * inv * us2f(gg.z) + us2f(bb.z) + us2f(vv.z);
    float o3 = (v[3] - mu) * inv * us2f(gg.w) + us2f(bb.w) + us2f(vv.w);
    if (meta[0]) {
        ushort4 o;
        o.x = f2us(o0); o.y = f2us(o1); o.z = f2us(o2); o.w = f2us(o3);
        reinterpret_cast<ushort4*>((unsigned short*)dout + (long)row * DIM)[tid] = o;
    } else {
        float4 o = make_float4(o0, o1, o2, o3);
        reinterpret_cast<float4*>((float*)dout + (long)row * DIM)[tid] = o;
    }
}

extern "C" void kernel_launch(void* const* d_in, const int* in_sizes, int n_in,
                              void* d_out, int out_size, void* d_ws, size_t ws_size,
                              hipStream_t stream)
{
    // scan_idx (d_in[11]) unused: all 8 scans are bijections on the 576 cells and
    // softmax over the full K*N key axis (K,V share row order) is permutation-
    // invariant per direction block -> gather elided.
    unsigned long long w = (unsigned long long)d_ws;
    int* meta = (int*)w; w += 256;

    const int cidx[10] = {0, 2, 3, 4, 5, 6, 7, 8, 9, 10};
    const long csz[10] = {
        (long)NB * NTOK * DIM,  // vision
        (long)KDIR * DIM,       // dirb
        3L * DIM * DIM,         // inW
        3L * DIM,               // inB
        (long)DIM * DIM,        // outW
        DIM,                    // outB
        (long)DIM * DIM,        // finW
        DIM, DIM, DIM           // finB, lng, lnb
    };
    unsigned short* cv[10];
    for (int i = 0; i < 10; ++i) {
        cv[i] = (unsigned short*)w;
        w += (csz[i] * 2 + 255) & ~255ULL;
    }
    unsigned short* dWT = (unsigned short*)w; w += (long)KDIR * DIM * DIM * 2;

    const size_t big = (size_t)NB * KDIR * NTOK * DIM * 2;   // 37.75 MB
    const size_t sml = (size_t)NB * NTOK * DIM * 2;          // 4.72 MB
    unsigned short* dirs = (unsigned short*)w; w += big;     // aliased as Opart later
    unsigned short* Kh   = (unsigned short*)w; w += big;
    unsigned short* VTh  = (unsigned short*)w; w += big;
    unsigned short* Qh   = (unsigned short*)w; w += sml;
    unsigned short* Ob   = (unsigned short*)w; w += sml;
    unsigned short* Fu   = (unsigned short*)w; w += sml;
    unsigned short* Y2   = (unsigned short*)w; w += sml;
    float2* Ml = (float2*)w; w += (long)NSPLIT * 32 * NTOK * sizeof(float2);
    unsigned short* Opart = dirs;   // dirs is dead once KV GEMM completes

    const unsigned short* vision = cv[0];
    const unsigned short* dirb = cv[1];
    const unsigned short* inW = cv[2];
    const unsigned short* inB = cv[3];
    const unsigned short* outW = cv[4];
    const unsigned short* outB = cv[5];
    const unsigned short* finW = cv[6];
    const unsigned short* finB = cv[7];
    const unsigned short* lng = cv[8];
    const unsigned short* lnbt = cv[9];

    dim3 blk(256, 1, 1);

    // 0. dtype detect
    detect_kernel<<<dim3(1), dim3(64), 0, stream>>>((const unsigned int*)d_in[1], meta);

    // 1. convert inputs to bf16 (+ transposed dirW)
    for (int i = 0; i < 10; ++i)
        conv_kernel<<<dim3(256), blk, 0, stream>>>(d_in[cidx[i]], cv[i], csz[i] / 4, meta);
    transpose_conv<<<dim3(1024, KDIR), blk, 0, stream>>>(d_in[1], dWT, meta);

    // 2. dirs[b,k] = vision[b] @ dirW[k] + dirb[k]; flat GEMM M=2304, batch z=k
    gemm_glds<4, 8><<<dim3(18 * 8, KDIR), blk, 0, stream>>>(
        vision, dWT, dirb, dirs, nullptr, NB * NTOK, (long)DIM * DIM, DIM);

    // 3. Q -> Qh [b,h,n,d]
    gemm_glds<1, 8><<<dim3(18 * 8, 1), blk, 0, stream>>>(
        vision, inW, inB, Qh, nullptr, NB * NTOK, 0L, 0L);

    // 4. fused K+V GEMM (wk||wv contiguous in in_proj_w): K->Kh, V->VTh
    gemm_glds<5, 16><<<dim3(144 * 16, 1), blk, 0, stream>>>(
        dirs, inW + DIM * DIM, inB + DIM, Kh, VTh, NB * KN, 0L, 0L);

    // 5. KV-split flash attention -> Opart (aliases dirs) + Ml
    attn_kernel3<<<dim3(9 * 32 * NSPLIT), blk, 0, stream>>>(Qh, Kh, VTh, Opart, Ml);

    // 6. combine partials -> Ob [b,n,h*128+d]
    attn_reduce<<<dim3(9, 32), blk, 0, stream>>>(Opart, Ml, Ob);

    // 7. fused = Ob @ out_proj^T + b
    gemm_glds<0, 8><<<dim3(18 * 8, 1), blk, 0, stream>>>(
        Ob, outW, outB, Fu, nullptr, NB * NTOK, 0L, 0L);

    // 8. y = fused @ fin^T + b
    gemm_glds<0, 8><<<dim3(18 * 8, 1), blk, 0, stream>>>(
        Fu, finW, finB, Y2, nullptr, NB * NTOK, 0L, 0L);

    // 9. LayerNorm + residual -> d_out
    ln2_kernel<<<dim3(NB * NTOK), blk, 0, stream>>>(Y2, lng, lnbt, vision, d_out, meta);
}

// Round 5
// 432.782 us; speedup vs baseline: 2.3067x; 1.0182x over previous
//
#include <hip/hip_runtime.h>
#include <hip/hip_bf16.h>

typedef __attribute__((ext_vector_type(8))) short short8;
typedef __attribute__((ext_vector_type(4))) float f32x4;

#define NTOK 576
#define DIM  1024
#define NB   4
#define NH   8
#define HD   128
#define KDIR 8
#define KN   4608
#define NSPLIT 8

__device__ __forceinline__ float us2f(unsigned short u) {
    unsigned int x = ((unsigned int)u) << 16;
    return __uint_as_float(x);
}
__device__ __forceinline__ unsigned short f2us(float f) {
    unsigned int x = __float_as_uint(f);
    unsigned int r = x + 0x7fffu + ((x >> 16) & 1u);
    return (unsigned short)(r >> 16);
}
__device__ __forceinline__ unsigned short cvt_bf16(float f) {
    unsigned int pk;
    asm("v_cvt_pk_bf16_f32 %0, %1, %2" : "=v"(pk) : "v"(f), "v"(f));
    return (unsigned short)(pk & 0xffffu);
}

typedef __attribute__((address_space(3))) unsigned int lds_uint;
typedef const __attribute__((address_space(1))) unsigned int glb_uint;
__device__ __forceinline__ void async16(const unsigned short* g, unsigned short* l) {
    __builtin_amdgcn_global_load_lds((glb_uint*)g, (lds_uint*)l, 16, 0, 0);
}
__device__ __forceinline__ void wait_vm0_barrier() {
    asm volatile("s_waitcnt vmcnt(0)" ::: "memory");
    __builtin_amdgcn_s_barrier();
    __builtin_amdgcn_sched_barrier(0);
}

// meta[0] = 1 if device buffers are bf16, 0 if f32
__global__ void detect_kernel(const unsigned int* __restrict__ src, int* meta)
{
    if (threadIdx.x == 0) {
        int cnt = 0;
        for (int i = 0; i < 256; ++i) {
            unsigned u = src[(long)i * 16384] & 0xFFFFu;
            unsigned e = (u >> 7) & 0xFFu;
            cnt += (e >= 90 && e <= 150) ? 1 : 0;
        }
        meta[0] = (cnt >= 192) ? 1 : 0;
    }
}

// All 10 small conversions in one launch. Each block handles 1024 ushort4 of one job.
struct ConvJobs {
    const void* src[10];
    unsigned short* dst[10];
    int n4[10];
    int bstart[10];
};
__global__ __launch_bounds__(256)
void conv_all(ConvJobs J, const int* __restrict__ meta)
{
    const int b = blockIdx.x;
    int ji = 0;
    #pragma unroll
    for (int i = 1; i < 10; ++i) if (b >= J.bstart[i]) ji = i;
    const long base = (long)(b - J.bstart[ji]) * 1024 + threadIdx.x;
    const long n4 = J.n4[ji];
    if (meta[0]) {
        const ushort4* s = (const ushort4*)J.src[ji];
        ushort4* d = (ushort4*)J.dst[ji];
        #pragma unroll
        for (int t = 0; t < 4; ++t) {
            long i = base + t * 256;
            if (i < n4) d[i] = s[i];
        }
    } else {
        const float4* s = (const float4*)J.src[ji];
        ushort4* d = (ushort4*)J.dst[ji];
        #pragma unroll
        for (int t = 0; t < 4; ++t) {
            long i = base + t * 256;
            if (i < n4) {
                float4 v = s[i];
                ushort4 o;
                o.x = f2us(v.x); o.y = f2us(v.y); o.z = f2us(v.z); o.w = f2us(v.w);
                d[i] = o;
            }
        }
    }
}

// dirW [8][1024 d][1024 e] -> dWT [8][1024 e][1024 d], with dtype conversion
__global__ __launch_bounds__(256)
void transpose_conv(const void* __restrict__ src, unsigned short* __restrict__ dst,
                    const int* __restrict__ meta)
{
    const int k = blockIdx.y;
    const int ty = blockIdx.x >> 5, tx = blockIdx.x & 31;
    const int d0 = ty * 32, e0 = tx * 32;
    __shared__ float tl[32][33];
    const int t = threadIdx.x;
    const int row = t >> 3, c4 = (t & 7) * 4;
    const long sbase = ((long)k * 1024 + d0 + row) * 1024 + e0 + c4;
    if (meta[0]) {
        const unsigned short* s = (const unsigned short*)src;
        ushort4 v = *(const ushort4*)(s + sbase);
        tl[row][c4+0] = us2f(v.x); tl[row][c4+1] = us2f(v.y);
        tl[row][c4+2] = us2f(v.z); tl[row][c4+3] = us2f(v.w);
    } else {
        const float* s = (const float*)src;
        float4 v = *(const float4*)(s + sbase);
        tl[row][c4+0] = v.x; tl[row][c4+1] = v.y;
        tl[row][c4+2] = v.z; tl[row][c4+3] = v.w;
    }
    __syncthreads();
    ushort4 o;
    o.x = f2us(tl[c4+0][row]); o.y = f2us(tl[c4+1][row]);
    o.z = f2us(tl[c4+2][row]); o.w = f2us(tl[c4+3][row]);
    *(ushort4*)(dst + ((long)k * 1024 + e0 + row) * 1024 + d0 + c4) = o;
}

// C = A[M x 1024] @ B^T + bias.  B row-major (TN*128 rows, K=1024). BK=64, tile 128x128.
// Double-buffered global_load_lds staging; one barrier per K-step, counted prefetch.
// MODE: 0 row-major; 1 Qh [bh][n][d]; 4 dirs [(b*4608+z*576+n)*1024+cg];
//       5 fused KV: cg<1024 -> Kh [bh][kv][128]; cg>=1024 -> VTh [bh][128][kv]
template<int MODE, int TN>
__global__ __launch_bounds__(256)
void gemm_glds(const unsigned short* __restrict__ A, const unsigned short* __restrict__ Bw,
               const unsigned short* __restrict__ bias, unsigned short* __restrict__ C,
               unsigned short* __restrict__ C2,
               int M, long bStride, long biasStride)
{
    const int z = blockIdx.y;
    const unsigned short* Bb = Bw + (long)z * bStride;
    const unsigned short* Gb = bias + (long)z * biasStride;
    const int tm = blockIdx.x / TN;
    const int tn = blockIdx.x % TN;

    __shared__ __align__(16) unsigned short As[2][128 * 64];
    __shared__ __align__(16) unsigned short Bs[2][128 * 64];

    const int tid = threadIdx.x, lane = tid & 63, wid = tid >> 6;
    const int wm = wid >> 1, wn = wid & 1;
    const int r0 = lane & 15, hi = lane >> 4;
    const int lr = lane >> 3;
    const int lg = lane & 7;

    f32x4 zz = {0.f, 0.f, 0.f, 0.f};
    f32x4 acc[4][4];
    #pragma unroll
    for (int i = 0; i < 4; ++i)
        #pragma unroll
        for (int j = 0; j < 4; ++j) acc[i][j] = zz;

    const int sgc = ((lg ^ (lr & 7)) << 3);

    auto stage = [&](int k0, int buf) {
        #pragma unroll
        for (int j = 0; j < 4; ++j) {
            int rb = wid * 32 + j * 8;
            int r = rb + lr;
            async16(A  + (long)(tm * 128 + r) * 1024 + k0 + sgc, &As[buf][rb * 64]);
            async16(Bb + (long)(tn * 128 + r) * 1024 + k0 + sgc, &Bs[buf][rb * 64]);
        }
    };

    stage(0, 0);
    for (int kt = 0; kt < 16; ++kt) {
        wait_vm0_barrier();
        if (kt < 15) stage((kt + 1) * 64, (kt + 1) & 1);
        const unsigned short* Asb = As[kt & 1];
        const unsigned short* Bsb = Bs[kt & 1];
        __builtin_amdgcn_s_setprio(1);
        #pragma unroll
        for (int kd = 0; kd < 2; ++kd) {
            const int pg = ((kd * 4 + hi) ^ (r0 & 7)) << 3;
            short8 af[4], bfr[4];
            #pragma unroll
            for (int mi = 0; mi < 4; ++mi)
                af[mi] = *reinterpret_cast<const short8*>(&Asb[(wm * 64 + mi * 16 + r0) * 64 + pg]);
            #pragma unroll
            for (int ni = 0; ni < 4; ++ni)
                bfr[ni] = *reinterpret_cast<const short8*>(&Bsb[(wn * 64 + ni * 16 + r0) * 64 + pg]);
            #pragma unroll
            for (int mi = 0; mi < 4; ++mi)
                #pragma unroll
                for (int ni = 0; ni < 4; ++ni)
                    acc[mi][ni] = __builtin_amdgcn_mfma_f32_16x16x32_bf16(af[mi], bfr[ni], acc[mi][ni], 0, 0, 0);
        }
        __builtin_amdgcn_s_setprio(0);
    }

    const int jr = hi * 4;
    #pragma unroll
    for (int ni = 0; ni < 4; ++ni) {
        int cg = tn * 128 + wn * 64 + ni * 16 + r0;
        float bv = us2f(Gb[cg]);
        if constexpr (MODE == 5) {
            if (cg >= 1024) {
                int cg2 = cg - 1024;
                int h = cg2 >> 7, d = cg2 & 127;
                #pragma unroll
                for (int mi = 0; mi < 4; ++mi) {
                    int rgb = tm * 128 + wm * 64 + mi * 16 + jr;
                    int b = rgb / 4608, kv = rgb - b * 4608;
                    ushort4 o;
                    o.x = f2us(acc[mi][ni][0] + bv);
                    o.y = f2us(acc[mi][ni][1] + bv);
                    o.z = f2us(acc[mi][ni][2] + bv);
                    o.w = f2us(acc[mi][ni][3] + bv);
                    *(ushort4*)&C2[((long)(b * 8 + h) * 128 + d) * 4608 + kv] = o;
                }
                continue;
            }
        }
        #pragma unroll
        for (int mi = 0; mi < 4; ++mi) {
            #pragma unroll
            for (int j = 0; j < 4; ++j) {
                int rg = tm * 128 + wm * 64 + mi * 16 + jr + j;
                float val = acc[mi][ni][j] + bv;
                long idx;
                if constexpr (MODE == 0) {
                    idx = (long)rg * 1024 + cg;
                } else if constexpr (MODE == 1) {
                    int b = rg / 576, n = rg - b * 576;
                    int h = cg >> 7, d = cg & 127;
                    idx = ((long)(b * 8 + h) * 576 + n) * 128 + d;
                } else if constexpr (MODE == 5) {
                    int b = rg / 4608, kv = rg - b * 4608;
                    int h = cg >> 7, d = cg & 127;
                    idx = ((long)(b * 8 + h) * 4608 + kv) * 128 + d;
                } else {
                    int b = rg / 576, n = rg - b * 576;
                    idx = ((long)b * 4608 + (long)z * 576 + n) * 1024 + cg;
                }
                C[idx] = f2us(val);
            }
        }
    }
}

// KV-split flash attention, XCD-swizzled, double-buffered K/V prefetch.
// Q pre-scaled by 1/sqrt(128)*log2(e); exp2-domain softmax; defer-max (thr=8).
__global__ __launch_bounds__(256)
void attn_kernel4(const unsigned short* __restrict__ Qh, const unsigned short* __restrict__ Kh,
                  const unsigned short* __restrict__ VTh, unsigned short* __restrict__ Opart,
                  float2* __restrict__ Ml)
{
    const int bid = blockIdx.x;
    const int logical = (bid & 7) * 288 + (bid >> 3);
    const int bhsp = logical / 9;
    const int qt = logical - bhsp * 9;
    const int bh = bhsp >> 3;
    const int sp = bhsp & 7;

    const int tid = threadIdx.x;
    const int lane = tid & 63, wid = tid >> 6;
    const int r0 = lane & 15, hi = lane >> 4;
    const int k8 = hi * 8, jr = hi * 4;

    __shared__ __align__(16) unsigned short Ks[2][64 * 128];
    __shared__ __align__(16) unsigned short VT[2][128 * 64];
    __shared__ __align__(16) unsigned short Pl[4 * 16 * 64];
    unsigned short* Plw = &Pl[wid * 1024];

    const float SCL2 = 0.08838834764831845f * 1.4426950408889634f;
    short8 qf[4];
    {
        const long qoff = ((long)bh * NTOK + qt * 64 + wid * 16 + r0) * HD;
        #pragma unroll
        for (int kd = 0; kd < 4; ++kd) {
            short8 q = *reinterpret_cast<const short8*>(Qh + qoff + kd * 32 + k8);
            short8 qs;
            #pragma unroll
            for (int e = 0; e < 8; ++e)
                qs[e] = (short)cvt_bf16(us2f((unsigned short)q[e]) * SCL2);
            qf[kd] = qs;
        }
    }

    f32x4 zz = {0.f, 0.f, 0.f, 0.f};
    f32x4 oacc[8];
    #pragma unroll
    for (int i = 0; i < 8; ++i) oacc[i] = zz;
    float mrun[4], lrun[4];
    #pragma unroll
    for (int j = 0; j < 4; ++j) { mrun[j] = -1e30f; lrun[j] = 0.f; }

    const unsigned short* kbase0 = Kh + (long)bh * KN * HD;
    const unsigned short* vbase  = VTh + (long)bh * HD * KN;

    auto stage = [&](int kt, int buf) {
        const int kv0 = sp * (KN / NSPLIT) + kt * 64;
        const unsigned short* kb = kbase0 + (long)kv0 * HD;
        #pragma unroll
        for (int j = 0; j < 4; ++j) {
            int li = wid * 4 + j;
            int r = li * 4 + hi;
            int scK = (((lane & 15) ^ (r & 7)) << 3);
            async16(kb + (long)r * HD + scK, &Ks[buf][(li * 4) * 128]);
            int rv = li * 8 + (lane >> 3);
            int scV = (((lane & 7) ^ (rv & 7)) << 3);
            async16(vbase + (long)rv * KN + kv0 + scV, &VT[buf][(li * 8) * 64]);
        }
    };

    stage(0, 0);
    for (int kt = 0; kt < KN / NSPLIT / 64; ++kt) {
        wait_vm0_barrier();
        if (kt < KN / NSPLIT / 64 - 1) stage(kt + 1, (kt + 1) & 1);
        const unsigned short* Ksb = Ks[kt & 1];
        const unsigned short* VTb = VT[kt & 1];

        f32x4 s[4];
        #pragma unroll
        for (int nb = 0; nb < 4; ++nb) s[nb] = zz;
        __builtin_amdgcn_s_setprio(1);
        #pragma unroll
        for (int nb = 0; nb < 4; ++nb) {
            const int krow = nb * 16 + r0;
            #pragma unroll
            for (int kd = 0; kd < 4; ++kd) {
                short8 kf = *reinterpret_cast<const short8*>(
                    &Ksb[krow * 128 + (((kd * 4 + hi) ^ (r0 & 7)) << 3)]);
                s[nb] = __builtin_amdgcn_mfma_f32_16x16x32_bf16(qf[kd], kf, s[nb], 0, 0, 0);
            }
        }
        __builtin_amdgcn_s_setprio(0);

        float mt[4], rt[4];
        #pragma unroll
        for (int j = 0; j < 4; ++j)
            mt[j] = fmaxf(fmaxf(s[0][j], s[1][j]), fmaxf(s[2][j], s[3][j]));
        #pragma unroll
        for (int off = 1; off < 16; off <<= 1)
            #pragma unroll
            for (int j = 0; j < 4; ++j)
                mt[j] = fmaxf(mt[j], __shfl_xor(mt[j], off));
        float growth = fmaxf(fmaxf(mt[0] - mrun[0], mt[1] - mrun[1]),
                             fmaxf(mt[2] - mrun[2], mt[3] - mrun[3]));
        if (!__all(growth <= 8.0f)) {
            #pragma unroll
            for (int j = 0; j < 4; ++j) {
                float mn = fmaxf(mrun[j], mt[j]);
                float scl = exp2f(mrun[j] - mn);
                mrun[j] = mn;
                lrun[j] *= scl;
                #pragma unroll
                for (int db = 0; db < 8; ++db)
                    oacc[db][j] *= scl;
            }
        }
        #pragma unroll
        for (int j = 0; j < 4; ++j) rt[j] = 0.f;
        #pragma unroll
        for (int nb = 0; nb < 4; ++nb)
            #pragma unroll
            for (int j = 0; j < 4; ++j) {
                float p = exp2f(s[nb][j] - mrun[j]);
                rt[j] += p;
                int row = jr + j;
                int g = nb * 2 + (r0 >> 3);
                Plw[row * 64 + ((g ^ (row & 7)) << 3) + (r0 & 7)] = cvt_bf16(p);
            }
        #pragma unroll
        for (int off = 1; off < 16; off <<= 1)
            #pragma unroll
            for (int j = 0; j < 4; ++j)
                rt[j] += __shfl_xor(rt[j], off);
        #pragma unroll
        for (int j = 0; j < 4; ++j)
            lrun[j] += rt[j];

        __builtin_amdgcn_s_setprio(1);
        #pragma unroll
        for (int kb2 = 0; kb2 < 2; ++kb2) {
            const int pg = ((kb2 * 4 + hi) ^ (r0 & 7)) << 3;
            short8 ap = *reinterpret_cast<const short8*>(&Plw[r0 * 64 + pg]);
            #pragma unroll
            for (int db = 0; db < 8; ++db) {
                short8 vf = *reinterpret_cast<const short8*>(&VTb[(db * 16 + r0) * 64 + pg]);
                oacc[db] = __builtin_amdgcn_mfma_f32_16x16x32_bf16(ap, vf, oacc[db], 0, 0, 0);
            }
        }
        __builtin_amdgcn_s_setprio(0);
    }

    float inv[4];
    #pragma unroll
    for (int j = 0; j < 4; ++j) inv[j] = 1.f / lrun[j];
    const long po = ((long)(sp * 32 + bh) * NTOK + qt * 64 + wid * 16) * HD;
    #pragma unroll
    for (int db = 0; db < 8; ++db)
        #pragma unroll
        for (int j = 0; j < 4; ++j)
            Opart[po + (long)(jr + j) * HD + db * 16 + r0] = f2us(oacc[db][j] * inv[j]);
    if (r0 == 0) {
        const long mo = (long)(sp * 32 + bh) * NTOK + qt * 64 + wid * 16;
        #pragma unroll
        for (int j = 0; j < 4; ++j)
            Ml[mo + jr + j] = make_float2(mrun[j], lrun[j]);   // m in log2 domain
    }
}

// Combine NSPLIT partials -> Ob[(b*576+n)*1024 + h*128 + d]
__global__ __launch_bounds__(256)
void attn_reduce(const unsigned short* __restrict__ Opart, const float2* __restrict__ Ml,
                 unsigned short* __restrict__ Ob)
{
    const int qt = blockIdx.x, bh = blockIdx.y;
    const int t = threadIdx.x;
    const int rl = t >> 2, dc = (t & 3) * 32;
    const int q = qt * 64 + rl;

    float m[NSPLIT], l[NSPLIT];
    float M = -1e30f;
    #pragma unroll
    for (int sp = 0; sp < NSPLIT; ++sp) {
        float2 v = Ml[(long)(sp * 32 + bh) * NTOK + q];
        m[sp] = v.x; l[sp] = v.y;
        M = fmaxf(M, v.x);
    }
    float w[NSPLIT], denom = 0.f;
    #pragma unroll
    for (int sp = 0; sp < NSPLIT; ++sp) {
        w[sp] = l[sp] * exp2f(m[sp] - M);
        denom += w[sp];
    }
    const float inv = 1.f / denom;
    const int b = bh >> 3, h = bh & 7;
    #pragma unroll
    for (int dj = 0; dj < 4; ++dj) {
        float a[8];
        #pragma unroll
        for (int e = 0; e < 8; ++e) a[e] = 0.f;
        #pragma unroll
        for (int sp = 0; sp < NSPLIT; ++sp) {
            short8 v = *reinterpret_cast<const short8*>(
                &Opart[((long)(sp * 32 + bh) * NTOK + q) * HD + dc + dj * 8]);
            #pragma unroll
            for (int e = 0; e < 8; ++e)
                a[e] += w[sp] * us2f((unsigned short)v[e]);
        }
        short8 o;
        #pragma unroll
        for (int e = 0; e < 8; ++e) o[e] = (short)f2us(a[e] * inv);
        *reinterpret_cast<short8*>(&Ob[((long)b * NTOK + q) * 1024 + h * 128 + dc + dj * 8]) = o;
    }
}

// LayerNorm(y)*g + b + vision; output dtype per meta[0]
__global__ __launch_bounds__(256)
void ln2_kernel(const unsigned short* __restrict__ Y, const unsigned short* __restrict__ g,
                const unsigned short* __restrict__ be, const unsigned short* __restrict__ vis,
                void* __restrict__ dout, const int* __restrict__ meta)
{
    const int row = blockIdx.x;
    const int tid = threadIdx.x;
    const int lane = tid & 63, wid = tid >> 6;
    const unsigned short* yr = Y + (long)row * DIM;
    ushort4 raw = reinterpret_cast<const ushort4*>(yr)[tid];
    float v[4];
    v[0] = us2f(raw.x); v[1] = us2f(raw.y); v[2] = us2f(raw.z); v[3] = us2f(raw.w);
    float s1 = 0.f, s2 = 0.f;
    #pragma unroll
    for (int i = 0; i < 4; ++i) { s1 += v[i]; s2 += v[i] * v[i]; }
    #pragma unroll
    for (int off = 1; off < 64; off <<= 1) {
        s1 += __shfl_xor(s1, off);
        s2 += __shfl_xor(s2, off);
    }
    __shared__ float red[2][4];
    if (lane == 0) { red[0][wid] = s1; red[1][wid] = s2; }
    __syncthreads();
    s1 = red[0][0] + red[0][1] + red[0][2] + red[0][3];
    s2 = red[1][0] + red[1][1] + red[1][2] + red[1][3];
    const float mu = s1 * (1.f / DIM);
    const float var = s2 * (1.f / DIM) - mu * mu;
    const float inv = rsqrtf(var + 1e-5f);
    ushort4 gg = reinterpret_cast<const ushort4*>(g)[tid];
    ushort4 bb = reinterpret_cast<const ushort4*>(be)[tid];
    ushort4 vv = reinterpret_cast<const ushort4*>(vis + (long)row * DIM)[tid];
    float o0 = (v[0] - mu) * inv * us2f(gg.x) + us2f(bb.x) + us2f(vv.x);
    float o1 = (v[1] - mu) * inv * us2f(gg.y) + us2f(bb.y) + us2f(vv.y);
    float o2 = (v[2] - mu) * inv * us2f(gg.z) + us2f(bb.z) + us2f(vv.z);
    float o3 = (v[3] - mu) * inv * us2f(gg.w) + us2f(bb.w) + us2f(vv.w);
    if (meta[0]) {
        ushort4 o;
        o.x = f2us(o0); o.y = f2us(o1); o.z = f2us(o2); o.w = f2us(o3);
        reinterpret_cast<ushort4*>((unsigned short*)dout + (long)row * DIM)[tid] = o;
    } else {
        float4 o = make_float4(o0, o1, o2, o3);
        reinterpret_cast<float4*>((float*)dout + (long)row * DIM)[tid] = o;
    }
}

extern "C" void kernel_launch(void* const* d_in, const int* in_sizes, int n_in,
                              void* d_out, int out_size, void* d_ws, size_t ws_size,
                              hipStream_t stream)
{
    // scan_idx (d_in[11]) unused: all 8 scans are bijections on the 576 cells and
    // softmax over the full K*N key axis (K,V share row order) is permutation-
    // invariant per direction block -> gather elided.
    unsigned long long w = (unsigned long long)d_ws;
    int* meta = (int*)w; w += 256;

    const int cidx[10] = {0, 2, 3, 4, 5, 6, 7, 8, 9, 10};
    const long csz[10] = {
        (long)NB * NTOK * DIM,  // vision
        (long)KDIR * DIM,       // dirb
        3L * DIM * DIM,         // inW
        3L * DIM,               // inB
        (long)DIM * DIM,        // outW
        DIM,                    // outB
        (long)DIM * DIM,        // finW
        DIM, DIM, DIM           // finB, lng, lnb
    };
    unsigned short* cv[10];
    for (int i = 0; i < 10; ++i) {
        cv[i] = (unsigned short*)w;
        w += (csz[i] * 2 + 255) & ~255ULL;
    }
    unsigned short* dWT = (unsigned short*)w; w += (long)KDIR * DIM * DIM * 2;

    const size_t big = (size_t)NB * KDIR * NTOK * DIM * 2;   // 37.75 MB
    const size_t sml = (size_t)NB * NTOK * DIM * 2;          // 4.72 MB
    unsigned short* dirs = (unsigned short*)w; w += big;     // aliased as Opart later
    unsigned short* Kh   = (unsigned short*)w; w += big;
    unsigned short* VTh  = (unsigned short*)w; w += big;
    unsigned short* Qh   = (unsigned short*)w; w += sml;
    unsigned short* Ob   = (unsigned short*)w; w += sml;
    unsigned short* Fu   = (unsigned short*)w; w += sml;
    unsigned short* Y2   = (unsigned short*)w; w += sml;
    float2* Ml = (float2*)w; w += (long)NSPLIT * 32 * NTOK * sizeof(float2);
    unsigned short* Opart = dirs;   // dirs is dead once KV GEMM completes

    const unsigned short* vision = cv[0];
    const unsigned short* dirb = cv[1];
    const unsigned short* inW = cv[2];
    const unsigned short* inB = cv[3];
    const unsigned short* outW = cv[4];
    const unsigned short* outB = cv[5];
    const unsigned short* finW = cv[6];
    const unsigned short* finB = cv[7];
    const unsigned short* lng = cv[8];
    const unsigned short* lnbt = cv[9];

    dim3 blk(256, 1, 1);

    // 0. dtype detect
    detect_kernel<<<dim3(1), dim3(64), 0, stream>>>((const unsigned int*)d_in[1], meta);

    // 1. single fused conversion launch (+ transposed dirW)
    ConvJobs J;
    int bacc = 0;
    for (int i = 0; i < 10; ++i) {
        J.src[i] = d_in[cidx[i]];
        J.dst[i] = cv[i];
        J.n4[i] = (int)(csz[i] / 4);
        J.bstart[i] = bacc;
        bacc += (int)((csz[i] / 4 + 1023) / 1024);
    }
    conv_all<<<dim3(bacc), blk, 0, stream>>>(J, meta);
    transpose_conv<<<dim3(1024, KDIR), blk, 0, stream>>>(d_in[1], dWT, meta);

    // 2. dirs[b,k] = vision[b] @ dirW[k] + dirb[k]; flat GEMM M=2304, batch z=k
    gemm_glds<4, 8><<<dim3(18 * 8, KDIR), blk, 0, stream>>>(
        vision, dWT, dirb, dirs, nullptr, NB * NTOK, (long)DIM * DIM, DIM);

    // 3. Q -> Qh [b,h,n,d]
    gemm_glds<1, 8><<<dim3(18 * 8, 1), blk, 0, stream>>>(
        vision, inW, inB, Qh, nullptr, NB * NTOK, 0L, 0L);

    // 4. fused K+V GEMM (wk||wv contiguous in in_proj_w): K->Kh, V->VTh
    gemm_glds<5, 16><<<dim3(144 * 16, 1), blk, 0, stream>>>(
        dirs, inW + DIM * DIM, inB + DIM, Kh, VTh, NB * KN, 0L, 0L);

    // 5. KV-split flash attention -> Opart (aliases dirs) + Ml
    attn_kernel4<<<dim3(9 * 32 * NSPLIT), blk, 0, stream>>>(Qh, Kh, VTh, Opart, Ml);

    // 6. combine partials -> Ob [b,n,h*128+d]
    attn_reduce<<<dim3(9, 32), blk, 0, stream>>>(Opart, Ml, Ob);

    // 7. fused = Ob @ out_proj^T + b
    gemm_glds<0, 8><<<dim3(18 * 8, 1), blk, 0, stream>>>(
        Ob, outW, outB, Fu, nullptr, NB * NTOK, 0L, 0L);

    // 8. y = fused @ fin^T + b
    gemm_glds<0, 8><<<dim3(18 * 8, 1), blk, 0, stream>>>(
        Fu, finW, finB, Y2, nullptr, NB * NTOK, 0L, 0L);

    // 9. LayerNorm + residual -> d_out
    ln2_kernel<<<dim3(NB * NTOK), blk, 0, stream>>>(Y2, lng, lnbt, vision, d_out, meta);
}

// Round 6
// 391.198 us; speedup vs baseline: 2.5519x; 1.1063x over previous
//
#include <hip/hip_runtime.h>
#include <hip/hip_bf16.h>

typedef __attribute__((ext_vector_type(8))) short short8;
typedef __attribute__((ext_vector_type(4))) float f32x4;
typedef __attribute__((ext_vector_type(4))) int i32x4;

#define NTOK 576
#define DIM  1024
#define NB   4
#define NH   8
#define HD   128
#define KDIR 8
#define KN   4608
#define NSPLIT 8

__device__ __forceinline__ float us2f(unsigned short u) {
    unsigned int x = ((unsigned int)u) << 16;
    return __uint_as_float(x);
}
__device__ __forceinline__ unsigned short f2us(float f) {
    unsigned int x = __float_as_uint(f);
    unsigned int r = x + 0x7fffu + ((x >> 16) & 1u);
    return (unsigned short)(r >> 16);
}
__device__ __forceinline__ unsigned short cvt_bf16(float f) {
    unsigned int pk;
    asm("v_cvt_pk_bf16_f32 %0, %1, %2" : "=v"(pk) : "v"(f), "v"(f));
    return (unsigned short)(pk & 0xffffu);
}

typedef __attribute__((address_space(3))) unsigned int lds_uint;
typedef const __attribute__((address_space(1))) unsigned int glb_uint;
__device__ __forceinline__ void async16(const unsigned short* g, unsigned short* l) {
    __builtin_amdgcn_global_load_lds((glb_uint*)g, (lds_uint*)l, 16, 0, 0);
}
__device__ __forceinline__ void wait_vm0_barrier() {
    asm volatile("s_waitcnt vmcnt(0)" ::: "memory");
    __builtin_amdgcn_s_barrier();
    __builtin_amdgcn_sched_barrier(0);
}

// meta[0] = 1 if device buffers are bf16, 0 if f32
__global__ void detect_kernel(const unsigned int* __restrict__ src, int* meta)
{
    if (threadIdx.x == 0) {
        int cnt = 0;
        for (int i = 0; i < 256; ++i) {
            unsigned u = src[(long)i * 16384] & 0xFFFFu;
            unsigned e = (u >> 7) & 0xFFu;
            cnt += (e >= 90 && e <= 150) ? 1 : 0;
        }
        meta[0] = (cnt >= 192) ? 1 : 0;
    }
}

// All 10 small conversions in one launch.
struct ConvJobs {
    const void* src[10];
    unsigned short* dst[10];
    int n4[10];
    int bstart[10];
};
__global__ __launch_bounds__(256)
void conv_all(ConvJobs J, const int* __restrict__ meta)
{
    const int b = blockIdx.x;
    int ji = 0;
    #pragma unroll
    for (int i = 1; i < 10; ++i) if (b >= J.bstart[i]) ji = i;
    const long base = (long)(b - J.bstart[ji]) * 1024 + threadIdx.x;
    const long n4 = J.n4[ji];
    if (meta[0]) {
        const ushort4* s = (const ushort4*)J.src[ji];
        ushort4* d = (ushort4*)J.dst[ji];
        #pragma unroll
        for (int t = 0; t < 4; ++t) {
            long i = base + t * 256;
            if (i < n4) d[i] = s[i];
        }
    } else {
        const float4* s = (const float4*)J.src[ji];
        ushort4* d = (ushort4*)J.dst[ji];
        #pragma unroll
        for (int t = 0; t < 4; ++t) {
            long i = base + t * 256;
            if (i < n4) {
                float4 v = s[i];
                ushort4 o;
                o.x = f2us(v.x); o.y = f2us(v.y); o.z = f2us(v.z); o.w = f2us(v.w);
                d[i] = o;
            }
        }
    }
}

// dirW [8][1024 d][1024 e] -> dWT [8][1024 e][1024 d]
__global__ __launch_bounds__(256)
void transpose_conv(const void* __restrict__ src, unsigned short* __restrict__ dst,
                    const int* __restrict__ meta)
{
    const int k = blockIdx.y;
    const int ty = blockIdx.x >> 5, tx = blockIdx.x & 31;
    const int d0 = ty * 32, e0 = tx * 32;
    __shared__ float tl[32][33];
    const int t = threadIdx.x;
    const int row = t >> 3, c4 = (t & 7) * 4;
    const long sbase = ((long)k * 1024 + d0 + row) * 1024 + e0 + c4;
    if (meta[0]) {
        const unsigned short* s = (const unsigned short*)src;
        ushort4 v = *(const ushort4*)(s + sbase);
        tl[row][c4+0] = us2f(v.x); tl[row][c4+1] = us2f(v.y);
        tl[row][c4+2] = us2f(v.z); tl[row][c4+3] = us2f(v.w);
    } else {
        const float* s = (const float*)src;
        float4 v = *(const float4*)(s + sbase);
        tl[row][c4+0] = v.x; tl[row][c4+1] = v.y;
        tl[row][c4+2] = v.z; tl[row][c4+3] = v.w;
    }
    __syncthreads();
    ushort4 o;
    o.x = f2us(tl[c4+0][row]); o.y = f2us(tl[c4+1][row]);
    o.z = f2us(tl[c4+2][row]); o.w = f2us(tl[c4+3][row]);
    *(ushort4*)(dst + ((long)k * 1024 + e0 + row) * 1024 + d0 + c4) = o;
}

// C = A[M x 1024] @ B^T + bias. Tile BM x BN, BK=64, double-buffered glds staging.
// MODE: 0 row-major C; 5 fused KV (cg<1024 -> Kh [bh][kv][128], else VTh [bh][128][kv]);
//       6 merged dirs(z<8)+Q(z==8)
template<int MODE, int TN, int BM, int BN>
__global__ __launch_bounds__(256)
void gemm_glds(const unsigned short* __restrict__ A, const unsigned short* __restrict__ Bw,
               const unsigned short* __restrict__ bias, unsigned short* __restrict__ C,
               const unsigned short* __restrict__ B2, const unsigned short* __restrict__ bias2,
               unsigned short* __restrict__ C2,
               int M, long bStride, long biasStride)
{
    constexpr int MI = BM / 32, NI = BN / 32;
    const int z = blockIdx.y;
    const unsigned short* Bb;
    const unsigned short* Gb;
    if constexpr (MODE == 6) {
        Bb = (z < 8) ? Bw + (long)z * bStride : B2;
        Gb = (z < 8) ? bias + (long)z * biasStride : bias2;
    } else {
        Bb = Bw + (long)z * bStride;
        Gb = bias + (long)z * biasStride;
    }
    const int tm = blockIdx.x / TN;
    const int tn = blockIdx.x % TN;

    __shared__ __align__(16) unsigned short As[2][BM * 64];
    __shared__ __align__(16) unsigned short Bs[2][BN * 64];

    const int tid = threadIdx.x, lane = tid & 63, wid = tid >> 6;
    const int wm = wid >> 1, wn = wid & 1;
    const int r0 = lane & 15, hi = lane >> 4;
    const int lr = lane >> 3;
    const int lg = lane & 7;

    f32x4 zz = {0.f, 0.f, 0.f, 0.f};
    f32x4 acc[MI][NI];
    #pragma unroll
    for (int i = 0; i < MI; ++i)
        #pragma unroll
        for (int j = 0; j < NI; ++j) acc[i][j] = zz;

    const int sgc = ((lg ^ (lr & 7)) << 3);

    auto stage = [&](int k0, int buf) {
        #pragma unroll
        for (int j = 0; j < BM / 32; ++j) {
            int rb = wid * (BM / 4) + j * 8;
            async16(A + (long)(tm * BM + rb + lr) * 1024 + k0 + sgc, &As[buf][rb * 64]);
        }
        #pragma unroll
        for (int j = 0; j < BN / 32; ++j) {
            int rb = wid * (BN / 4) + j * 8;
            async16(Bb + (long)(tn * BN + rb + lr) * 1024 + k0 + sgc, &Bs[buf][rb * 64]);
        }
    };

    stage(0, 0);
    for (int kt = 0; kt < 16; ++kt) {
        wait_vm0_barrier();
        if (kt < 15) stage((kt + 1) * 64, (kt + 1) & 1);
        const unsigned short* Asb = As[kt & 1];
        const unsigned short* Bsb = Bs[kt & 1];
        __builtin_amdgcn_s_setprio(1);
        #pragma unroll
        for (int kd = 0; kd < 2; ++kd) {
            const int pg = ((kd * 4 + hi) ^ (r0 & 7)) << 3;
            short8 af[MI], bfr[NI];
            #pragma unroll
            for (int mi = 0; mi < MI; ++mi)
                af[mi] = *reinterpret_cast<const short8*>(&Asb[(wm * (BM/2) + mi * 16 + r0) * 64 + pg]);
            #pragma unroll
            for (int ni = 0; ni < NI; ++ni)
                bfr[ni] = *reinterpret_cast<const short8*>(&Bsb[(wn * (BN/2) + ni * 16 + r0) * 64 + pg]);
            #pragma unroll
            for (int mi = 0; mi < MI; ++mi)
                #pragma unroll
                for (int ni = 0; ni < NI; ++ni)
                    acc[mi][ni] = __builtin_amdgcn_mfma_f32_16x16x32_bf16(af[mi], bfr[ni], acc[mi][ni], 0, 0, 0);
        }
        __builtin_amdgcn_s_setprio(0);
    }

    const int jr = hi * 4;
    #pragma unroll
    for (int ni = 0; ni < NI; ++ni) {
        int cg = tn * BN + wn * (BN/2) + ni * 16 + r0;
        float bv = us2f(Gb[cg]);
        if constexpr (MODE == 5) {
            if (cg >= 1024) {
                int cg2 = cg - 1024;
                int h = cg2 >> 7, d = cg2 & 127;
                #pragma unroll
                for (int mi = 0; mi < MI; ++mi) {
                    int rgb = tm * BM + wm * (BM/2) + mi * 16 + jr;
                    int b = rgb / 4608, kv = rgb - b * 4608;
                    ushort4 o;
                    o.x = f2us(acc[mi][ni][0] + bv);
                    o.y = f2us(acc[mi][ni][1] + bv);
                    o.z = f2us(acc[mi][ni][2] + bv);
                    o.w = f2us(acc[mi][ni][3] + bv);
                    *(ushort4*)&C2[((long)(b * 8 + h) * 128 + d) * 4608 + kv] = o;
                }
                continue;
            }
        }
        #pragma unroll
        for (int mi = 0; mi < MI; ++mi) {
            #pragma unroll
            for (int j = 0; j < 4; ++j) {
                int rg = tm * BM + wm * (BM/2) + mi * 16 + jr + j;
                float val = acc[mi][ni][j] + bv;
                if constexpr (MODE == 0) {
                    C[(long)rg * 1024 + cg] = f2us(val);
                } else if constexpr (MODE == 5) {
                    int b = rg / 4608, kv = rg - b * 4608;
                    int h = cg >> 7, d = cg & 127;
                    C[((long)(b * 8 + h) * 4608 + kv) * 128 + d] = f2us(val);
                } else {  // MODE 6
                    int b = rg / 576, n = rg - b * 576;
                    if (z == 8) {
                        int h = cg >> 7, d = cg & 127;
                        C2[((long)(b * 8 + h) * 576 + n) * 128 + d] = f2us(val);
                    } else {
                        C[((long)b * 4608 + (long)z * 576 + n) * 1024 + cg] = f2us(val);
                    }
                }
            }
        }
    }
}

// Swapped-operand flash attention: S^T = mfma(K,Q) -> lane owns full P-row for q=lane&15.
// In-lane softmax, register-only P via cvt_pk + shfl exchange, O^T = mfma(V^T, P).
__global__ __launch_bounds__(256)
void attn_kernel5(const unsigned short* __restrict__ Qh, const unsigned short* __restrict__ Kh,
                  const unsigned short* __restrict__ VTh, unsigned short* __restrict__ Opart,
                  float2* __restrict__ Ml)
{
    const int bid = blockIdx.x;
    const int logical = (bid & 7) * 288 + (bid >> 3);
    const int bhsp = logical / 9;
    const int qt = logical - bhsp * 9;
    const int bh = bhsp >> 3;
    const int sp = bhsp & 7;

    const int tid = threadIdx.x;
    const int lane = tid & 63, wid = tid >> 6;
    const int r0 = lane & 15, hi = lane >> 4;
    const int k8 = hi * 8;

    __shared__ __align__(16) unsigned short Ks[2][64 * 128];
    __shared__ __align__(16) unsigned short VT[2][128 * 64];

    const float SCL2 = 0.08838834764831845f * 1.4426950408889634f;
    short8 qf[4];
    {
        const long qoff = ((long)bh * NTOK + qt * 64 + wid * 16 + r0) * HD;
        #pragma unroll
        for (int kd = 0; kd < 4; ++kd) {
            short8 q = *reinterpret_cast<const short8*>(Qh + qoff + kd * 32 + k8);
            short8 qs;
            #pragma unroll
            for (int e = 0; e < 8; ++e)
                qs[e] = (short)cvt_bf16(us2f((unsigned short)q[e]) * SCL2);
            qf[kd] = qs;
        }
    }

    f32x4 zz = {0.f, 0.f, 0.f, 0.f};
    f32x4 oacc[8];   // oacc[db][j]: O^T[d=16db+4hi+j][q=r0]
    #pragma unroll
    for (int i = 0; i < 8; ++i) oacc[i] = zz;
    float mrun = -1e30f, lrun = 0.f;   // per-lane (q = r0), log2 domain

    const unsigned short* kbase0 = Kh + (long)bh * KN * HD;
    const unsigned short* vbase  = VTh + (long)bh * HD * KN;

    auto stage = [&](int kt, int buf) {
        const int kv0 = sp * (KN / NSPLIT) + kt * 64;
        const unsigned short* kb = kbase0 + (long)kv0 * HD;
        #pragma unroll
        for (int j = 0; j < 4; ++j) {
            int li = wid * 4 + j;
            int r = li * 4 + hi;
            int scK = (((lane & 15) ^ (r & 7)) << 3);
            async16(kb + (long)r * HD + scK, &Ks[buf][(li * 4) * 128]);
            int rv = li * 8 + (lane >> 3);
            int scV = (((lane & 7) ^ (rv & 7)) << 3);
            async16(vbase + (long)rv * KN + kv0 + scV, &VT[buf][(li * 8) * 64]);
        }
    };

    const int src0 = (lane & 15) + ((lane & 16) ? 32 : 0);  // r0 + 32*(hi&1)
    const int src1 = src0 + 16;
    const bool selhi = lane >= 32;                           // hi>>1

    stage(0, 0);
    for (int kt = 0; kt < KN / NSPLIT / 64; ++kt) {
        wait_vm0_barrier();
        if (kt < KN / NSPLIT / 64 - 1) stage(kt + 1, (kt + 1) & 1);
        const unsigned short* Ksb = Ks[kt & 1];
        const unsigned short* VTb = VT[kt & 1];

        // S^T[kv=16nb+4hi+j][q=r0] = mfma(K-rows, Q-rows)
        f32x4 s[4];
        #pragma unroll
        for (int nb = 0; nb < 4; ++nb) s[nb] = zz;
        __builtin_amdgcn_s_setprio(1);
        #pragma unroll
        for (int nb = 0; nb < 4; ++nb) {
            const int krow = nb * 16 + r0;
            #pragma unroll
            for (int kd = 0; kd < 4; ++kd) {
                short8 kf = *reinterpret_cast<const short8*>(
                    &Ksb[krow * 128 + (((kd * 4 + hi) ^ (r0 & 7)) << 3)]);
                s[nb] = __builtin_amdgcn_mfma_f32_16x16x32_bf16(kf, qf[kd], s[nb], 0, 0, 0);
            }
        }
        __builtin_amdgcn_s_setprio(0);

        // in-lane row max over the 16 held kv, then across the 4 hi-groups
        float m0 = fmaxf(fmaxf(s[0][0], s[0][1]), fmaxf(s[0][2], s[0][3]));
        float m1 = fmaxf(fmaxf(s[1][0], s[1][1]), fmaxf(s[1][2], s[1][3]));
        float m2 = fmaxf(fmaxf(s[2][0], s[2][1]), fmaxf(s[2][2], s[2][3]));
        float m3 = fmaxf(fmaxf(s[3][0], s[3][1]), fmaxf(s[3][2], s[3][3]));
        float mt = fmaxf(fmaxf(m0, m1), fmaxf(m2, m3));
        mt = fmaxf(mt, __shfl_xor(mt, 16));
        mt = fmaxf(mt, __shfl_xor(mt, 32));
        if (!__all(mt - mrun <= 8.0f)) {
            float mn = fmaxf(mrun, mt);
            float scl = exp2f(mrun - mn);
            mrun = mn;
            lrun *= scl;
            #pragma unroll
            for (int db = 0; db < 8; ++db)
                #pragma unroll
                for (int j = 0; j < 4; ++j)
                    oacc[db][j] *= scl;
        }
        float p[4][4];
        float rt = 0.f;
        #pragma unroll
        for (int nb = 0; nb < 4; ++nb)
            #pragma unroll
            for (int j = 0; j < 4; ++j) {
                p[nb][j] = exp2f(s[nb][j] - mrun);
                rt += p[nb][j];
            }
        rt += __shfl_xor(rt, 16);
        rt += __shfl_xor(rt, 32);
        lrun += rt;

        // pack P to bf16 pairs; redistribute into PV B-fragments
        unsigned pk0[4], pk1[4];
        #pragma unroll
        for (int nb = 0; nb < 4; ++nb) {
            asm("v_cvt_pk_bf16_f32 %0, %1, %2" : "=v"(pk0[nb]) : "v"(p[nb][0]), "v"(p[nb][1]));
            asm("v_cvt_pk_bf16_f32 %0, %1, %2" : "=v"(pk1[nb]) : "v"(p[nb][2]), "v"(p[nb][3]));
        }
        i32x4 pfrag[2];
        #pragma unroll
        for (int kd = 0; kd < 2; ++kd) {
            int a0 = __shfl((int)pk0[2*kd], src0), b0 = __shfl((int)pk0[2*kd+1], src0);
            int a1 = __shfl((int)pk1[2*kd], src0), b1 = __shfl((int)pk1[2*kd+1], src0);
            int a2 = __shfl((int)pk0[2*kd], src1), b2 = __shfl((int)pk0[2*kd+1], src1);
            int a3 = __shfl((int)pk1[2*kd], src1), b3 = __shfl((int)pk1[2*kd+1], src1);
            pfrag[kd][0] = selhi ? b0 : a0;
            pfrag[kd][1] = selhi ? b1 : a1;
            pfrag[kd][2] = selhi ? b2 : a2;
            pfrag[kd][3] = selhi ? b3 : a3;
        }

        // O^T += mfma(V^T-rows, P-rows)
        __builtin_amdgcn_s_setprio(1);
        #pragma unroll
        for (int kd = 0; kd < 2; ++kd) {
            short8 pf = *reinterpret_cast<const short8*>(&pfrag[kd]);
            const int pg = ((kd * 4 + hi) ^ (r0 & 7)) << 3;
            #pragma unroll
            for (int db = 0; db < 8; ++db) {
                short8 vf = *reinterpret_cast<const short8*>(&VTb[(db * 16 + r0) * 64 + pg]);
                oacc[db] = __builtin_amdgcn_mfma_f32_16x16x32_bf16(vf, pf, oacc[db], 0, 0, 0);
            }
        }
        __builtin_amdgcn_s_setprio(0);
    }

    const float inv = 1.f / lrun;
    const long po = ((long)(sp * 32 + bh) * NTOK + qt * 64 + wid * 16 + r0) * HD;
    #pragma unroll
    for (int db = 0; db < 8; ++db) {
        ushort4 o;
        o.x = f2us(oacc[db][0] * inv);
        o.y = f2us(oacc[db][1] * inv);
        o.z = f2us(oacc[db][2] * inv);
        o.w = f2us(oacc[db][3] * inv);
        *(ushort4*)&Opart[po + db * 16 + hi * 4] = o;
    }
    if (lane < 16) {
        const long mo = (long)(sp * 32 + bh) * NTOK + qt * 64 + wid * 16 + r0;
        Ml[mo] = make_float2(mrun, lrun);   // log2 domain
    }
}

// Combine NSPLIT partials -> Ob[(b*576+n)*1024 + h*128 + d]
__global__ __launch_bounds__(256)
void attn_reduce(const unsigned short* __restrict__ Opart, const float2* __restrict__ Ml,
                 unsigned short* __restrict__ Ob)
{
    const int qt = blockIdx.x, bh = blockIdx.y;
    const int t = threadIdx.x;
    const int rl = t >> 2, dc = (t & 3) * 32;
    const int q = qt * 64 + rl;

    float m[NSPLIT], l[NSPLIT];
    float M = -1e30f;
    #pragma unroll
    for (int sp = 0; sp < NSPLIT; ++sp) {
        float2 v = Ml[(long)(sp * 32 + bh) * NTOK + q];
        m[sp] = v.x; l[sp] = v.y;
        M = fmaxf(M, v.x);
    }
    float w[NSPLIT], denom = 0.f;
    #pragma unroll
    for (int sp = 0; sp < NSPLIT; ++sp) {
        w[sp] = l[sp] * exp2f(m[sp] - M);
        denom += w[sp];
    }
    const float inv = 1.f / denom;
    const int b = bh >> 3, h = bh & 7;
    #pragma unroll
    for (int dj = 0; dj < 4; ++dj) {
        float a[8];
        #pragma unroll
        for (int e = 0; e < 8; ++e) a[e] = 0.f;
        #pragma unroll
        for (int sp = 0; sp < NSPLIT; ++sp) {
            short8 v = *reinterpret_cast<const short8*>(
                &Opart[((long)(sp * 32 + bh) * NTOK + q) * HD + dc + dj * 8]);
            #pragma unroll
            for (int e = 0; e < 8; ++e)
                a[e] += w[sp] * us2f((unsigned short)v[e]);
        }
        short8 o;
        #pragma unroll
        for (int e = 0; e < 8; ++e) o[e] = (short)f2us(a[e] * inv);
        *reinterpret_cast<short8*>(&Ob[((long)b * NTOK + q) * 1024 + h * 128 + dc + dj * 8]) = o;
    }
}

// LayerNorm(y)*g + b + vision; output dtype per meta[0]
__global__ __launch_bounds__(256)
void ln2_kernel(const unsigned short* __restrict__ Y, const unsigned short* __restrict__ g,
                const unsigned short* __restrict__ be, const unsigned short* __restrict__ vis,
                void* __restrict__ dout, const int* __restrict__ meta)
{
    const int row = blockIdx.x;
    const int tid = threadIdx.x;
    const int lane = tid & 63, wid = tid >> 6;
    const unsigned short* yr = Y + (long)row * DIM;
    ushort4 raw = reinterpret_cast<const ushort4*>(yr)[tid];
    float v[4];
    v[0] = us2f(raw.x); v[1] = us2f(raw.y); v[2] = us2f(raw.z); v[3] = us2f(raw.w);
    float s1 = 0.f, s2 = 0.f;
    #pragma unroll
    for (int i = 0; i < 4; ++i) { s1 += v[i]; s2 += v[i] * v[i]; }
    #pragma unroll
    for (int off = 1; off < 64; off <<= 1) {
        s1 += __shfl_xor(s1, off);
        s2 += __shfl_xor(s2, off);
    }
    __shared__ float red[2][4];
    if (lane == 0) { red[0][wid] = s1; red[1][wid] = s2; }
    __syncthreads();
    s1 = red[0][0] + red[0][1] + red[0][2] + red[0][3];
    s2 = red[1][0] + red[1][1] + red[1][2] + red[1][3];
    const float mu = s1 * (1.f / DIM);
    const float var = s2 * (1.f / DIM) - mu * mu;
    const float inv = rsqrtf(var + 1e-5f);
    ushort4 gg = reinterpret_cast<const ushort4*>(g)[tid];
    ushort4 bb = reinterpret_cast<const ushort4*>(be)[tid];
    ushort4 vv = reinterpret_cast<const ushort4*>(vis + (long)row * DIM)[tid];
    float o0 = (v[0] - mu) * inv * us2f(gg.x) + us2f(bb.x) + us2f(vv.x);
    float o1 = (v[1] - mu) * inv * us2f(gg.y) + us2f(bb.y) + us2f(vv.y);
    float o2 = (v[2] - mu) * inv * us2f(gg.z) + us2f(bb.z) + us2f(vv.z);
    float o3 = (v[3] - mu) * inv * us2f(gg.w) + us2f(bb.w) + us2f(vv.w);
    if (meta[0]) {
        ushort4 o;
        o.x = f2us(o0); o.y = f2us(o1); o.z = f2us(o2); o.w = f2us(o3);
        reinterpret_cast<ushort4*>((unsigned short*)dout + (long)row * DIM)[tid] = o;
    } else {
        float4 o = make_float4(o0, o1, o2, o3);
        reinterpret_cast<float4*>((float*)dout + (long)row * DIM)[tid] = o;
    }
}

extern "C" void kernel_launch(void* const* d_in, const int* in_sizes, int n_in,
                              void* d_out, int out_size, void* d_ws, size_t ws_size,
                              hipStream_t stream)
{
    // scan_idx (d_in[11]) unused: all 8 scans are bijections on the 576 cells and
    // softmax over the full K*N key axis (K,V share row order) is permutation-
    // invariant per direction block -> gather elided.
    unsigned long long w = (unsigned long long)d_ws;
    int* meta = (int*)w; w += 256;

    const int cidx[10] = {0, 2, 3, 4, 5, 6, 7, 8, 9, 10};
    const long csz[10] = {
        (long)NB * NTOK * DIM,  // vision
        (long)KDIR * DIM,       // dirb
        3L * DIM * DIM,         // inW
        3L * DIM,               // inB
        (long)DIM * DIM,        // outW
        DIM,                    // outB
        (long)DIM * DIM,        // finW
        DIM, DIM, DIM           // finB, lng, lnb
    };
    unsigned short* cv[10];
    for (int i = 0; i < 10; ++i) {
        cv[i] = (unsigned short*)w;
        w += (csz[i] * 2 + 255) & ~255ULL;
    }
    unsigned short* dWT = (unsigned short*)w; w += (long)KDIR * DIM * DIM * 2;

    const size_t big = (size_t)NB * KDIR * NTOK * DIM * 2;   // 37.75 MB
    const size_t sml = (size_t)NB * NTOK * DIM * 2;          // 4.72 MB
    unsigned short* dirs = (unsigned short*)w; w += big;     // aliased as Opart later
    unsigned short* Kh   = (unsigned short*)w; w += big;
    unsigned short* VTh  = (unsigned short*)w; w += big;
    unsigned short* Qh   = (unsigned short*)w; w += sml;
    unsigned short* Ob   = (unsigned short*)w; w += sml;
    unsigned short* Fu   = (unsigned short*)w; w += sml;
    unsigned short* Y2   = (unsigned short*)w; w += sml;
    float2* Ml = (float2*)w; w += (long)NSPLIT * 32 * NTOK * sizeof(float2);
    unsigned short* Opart = dirs;   // dirs is dead once KV GEMM completes

    const unsigned short* vision = cv[0];
    const unsigned short* dirb = cv[1];
    const unsigned short* inW = cv[2];
    const unsigned short* inB = cv[3];
    const unsigned short* outW = cv[4];
    const unsigned short* outB = cv[5];
    const unsigned short* finW = cv[6];
    const unsigned short* finB = cv[7];
    const unsigned short* lng = cv[8];
    const unsigned short* lnbt = cv[9];

    dim3 blk(256, 1, 1);

    // 0. dtype detect
    detect_kernel<<<dim3(1), dim3(64), 0, stream>>>((const unsigned int*)d_in[1], meta);

    // 1. single fused conversion launch (+ transposed dirW)
    ConvJobs J;
    int bacc = 0;
    for (int i = 0; i < 10; ++i) {
        J.src[i] = d_in[cidx[i]];
        J.dst[i] = cv[i];
        J.n4[i] = (int)(csz[i] / 4);
        J.bstart[i] = bacc;
        bacc += (int)((csz[i] / 4 + 1023) / 1024);
    }
    conv_all<<<dim3(bacc), blk, 0, stream>>>(J, meta);
    transpose_conv<<<dim3(1024, KDIR), blk, 0, stream>>>(d_in[1], dWT, meta);

    // 2. merged dirs(z<8)+Q(z==8) GEMM: A=vision, M=2304
    gemm_glds<6, 8, 128, 128><<<dim3(18 * 8, 9), blk, 0, stream>>>(
        vision, dWT, dirb, dirs, inW, inB, Qh, NB * NTOK, (long)DIM * DIM, DIM);

    // 3. fused K+V GEMM (wk||wv contiguous): K->Kh, V->VTh
    gemm_glds<5, 16, 128, 128><<<dim3(144 * 16, 1), blk, 0, stream>>>(
        dirs, inW + DIM * DIM, inB + DIM, Kh, nullptr, nullptr, VTh, NB * KN, 0L, 0L);

    // 4. KV-split swapped-operand flash attention -> Opart (aliases dirs) + Ml
    attn_kernel5<<<dim3(9 * 32 * NSPLIT), blk, 0, stream>>>(Qh, Kh, VTh, Opart, Ml);

    // 5. combine partials -> Ob [b,n,h*128+d]
    attn_reduce<<<dim3(9, 32), blk, 0, stream>>>(Opart, Ml, Ob);

    // 6. fused = Ob @ out_proj^T + b   (64x64 tile: 576 blocks)
    gemm_glds<0, 16, 64, 64><<<dim3(36 * 16, 1), blk, 0, stream>>>(
        Ob, outW, outB, Fu, nullptr, nullptr, nullptr, NB * NTOK, 0L, 0L);

    // 7. y = fused @ fin^T + b
    gemm_glds<0, 16, 64, 64><<<dim3(36 * 16, 1), blk, 0, stream>>>(
        Fu, finW, finB, Y2, nullptr, nullptr, nullptr, NB * NTOK, 0L, 0L);

    // 8. LayerNorm + residual -> d_out
    ln2_kernel<<<dim3(NB * NTOK), blk, 0, stream>>>(Y2, lng, lnbt, vision, d_out, meta);
}

// Round 7
// 389.748 us; speedup vs baseline: 2.5614x; 1.0037x over previous
//
#include <hip/hip_runtime.h>
#include <hip/hip_bf16.h>

typedef __attribute__((ext_vector_type(8))) short short8;
typedef __attribute__((ext_vector_type(4))) short short4v;
typedef __attribute__((ext_vector_type(4))) float f32x4;
typedef __attribute__((ext_vector_type(4))) int i32x4;

#define NTOK 576
#define DIM  1024
#define NB   4
#define NH   8
#define HD   128
#define KDIR 8
#define KN   4608
#define NSPLIT 4
#define NT 18                 // KN/NSPLIT/64

__device__ __forceinline__ float us2f(unsigned short u) {
    unsigned int x = ((unsigned int)u) << 16;
    return __uint_as_float(x);
}
__device__ __forceinline__ unsigned short f2us(float f) {
    unsigned int x = __float_as_uint(f);
    unsigned int r = x + 0x7fffu + ((x >> 16) & 1u);
    return (unsigned short)(r >> 16);
}

typedef __attribute__((address_space(3))) unsigned int lds_uint;
typedef const __attribute__((address_space(1))) unsigned int glb_uint;
__device__ __forceinline__ void async16(const unsigned short* g, unsigned short* l) {
    __builtin_amdgcn_global_load_lds((glb_uint*)g, (lds_uint*)l, 16, 0, 0);
}
__device__ __forceinline__ void wait_vm0_barrier() {
    asm volatile("s_waitcnt vmcnt(0)" ::: "memory");
    __builtin_amdgcn_s_barrier();
    __builtin_amdgcn_sched_barrier(0);
}

// meta[0] = 1 if device buffers are bf16, 0 if f32
__global__ void detect_kernel(const unsigned int* __restrict__ src, int* meta)
{
    if (threadIdx.x == 0) {
        int cnt = 0;
        for (int i = 0; i < 256; ++i) {
            unsigned u = src[(long)i * 16384] & 0xFFFFu;
            unsigned e = (u >> 7) & 0xFFu;
            cnt += (e >= 90 && e <= 150) ? 1 : 0;
        }
        meta[0] = (cnt >= 192) ? 1 : 0;
    }
}

// All 10 small conversions in one launch.
struct ConvJobs {
    const void* src[10];
    unsigned short* dst[10];
    int n4[10];
    int bstart[10];
};
__global__ __launch_bounds__(256)
void conv_all(ConvJobs J, const int* __restrict__ meta)
{
    const int b = blockIdx.x;
    int ji = 0;
    #pragma unroll
    for (int i = 1; i < 10; ++i) if (b >= J.bstart[i]) ji = i;
    const long base = (long)(b - J.bstart[ji]) * 1024 + threadIdx.x;
    const long n4 = J.n4[ji];
    if (meta[0]) {
        const ushort4* s = (const ushort4*)J.src[ji];
        ushort4* d = (ushort4*)J.dst[ji];
        #pragma unroll
        for (int t = 0; t < 4; ++t) {
            long i = base + t * 256;
            if (i < n4) d[i] = s[i];
        }
    } else {
        const float4* s = (const float4*)J.src[ji];
        ushort4* d = (ushort4*)J.dst[ji];
        #pragma unroll
        for (int t = 0; t < 4; ++t) {
            long i = base + t * 256;
            if (i < n4) {
                float4 v = s[i];
                ushort4 o;
                o.x = f2us(v.x); o.y = f2us(v.y); o.z = f2us(v.z); o.w = f2us(v.w);
                d[i] = o;
            }
        }
    }
}

// dirW [8][1024 d][1024 e] -> dWT [8][1024 e][1024 d]
__global__ __launch_bounds__(256)
void transpose_conv(const void* __restrict__ src, unsigned short* __restrict__ dst,
                    const int* __restrict__ meta)
{
    const int k = blockIdx.y;
    const int ty = blockIdx.x >> 5, tx = blockIdx.x & 31;
    const int d0 = ty * 32, e0 = tx * 32;
    __shared__ float tl[32][33];
    const int t = threadIdx.x;
    const int row = t >> 3, c4 = (t & 7) * 4;
    const long sbase = ((long)k * 1024 + d0 + row) * 1024 + e0 + c4;
    if (meta[0]) {
        const unsigned short* s = (const unsigned short*)src;
        ushort4 v = *(const ushort4*)(s + sbase);
        tl[row][c4+0] = us2f(v.x); tl[row][c4+1] = us2f(v.y);
        tl[row][c4+2] = us2f(v.z); tl[row][c4+3] = us2f(v.w);
    } else {
        const float* s = (const float*)src;
        float4 v = *(const float4*)(s + sbase);
        tl[row][c4+0] = v.x; tl[row][c4+1] = v.y;
        tl[row][c4+2] = v.z; tl[row][c4+3] = v.w;
    }
    __syncthreads();
    ushort4 o;
    o.x = f2us(tl[c4+0][row]); o.y = f2us(tl[c4+1][row]);
    o.z = f2us(tl[c4+2][row]); o.w = f2us(tl[c4+3][row]);
    *(ushort4*)(dst + ((long)k * 1024 + e0 + row) * 1024 + d0 + c4) = o;
}

// C = A[M x 1024] @ B^T + bias. Tile BM x BN, BK=64, double-buffered glds staging.
// MODE: 0 row-major C; 5 fused KV (cg<1024 -> Kh [bh][kv][128], else VTh [bh][128][kv]);
//       6 merged dirs(z<8)+Q(z==8, pre-scaled by 1/sqrt(128)*log2e)
template<int MODE, int TN, int BM, int BN>
__global__ __launch_bounds__(256)
void gemm_glds(const unsigned short* __restrict__ A, const unsigned short* __restrict__ Bw,
               const unsigned short* __restrict__ bias, unsigned short* __restrict__ C,
               const unsigned short* __restrict__ B2, const unsigned short* __restrict__ bias2,
               unsigned short* __restrict__ C2,
               int M, long bStride, long biasStride)
{
    constexpr int MI = BM / 32, NI = BN / 32;
    const int z = blockIdx.y;
    const unsigned short* Bb;
    const unsigned short* Gb;
    if constexpr (MODE == 6) {
        Bb = (z < 8) ? Bw + (long)z * bStride : B2;
        Gb = (z < 8) ? bias + (long)z * biasStride : bias2;
    } else {
        Bb = Bw + (long)z * bStride;
        Gb = bias + (long)z * biasStride;
    }
    const int tm = blockIdx.x / TN;
    const int tn = blockIdx.x % TN;

    __shared__ __align__(16) unsigned short As[2][BM * 64];
    __shared__ __align__(16) unsigned short Bs[2][BN * 64];

    const int tid = threadIdx.x, lane = tid & 63, wid = tid >> 6;
    const int wm = wid >> 1, wn = wid & 1;
    const int r0 = lane & 15, hi = lane >> 4;
    const int lr = lane >> 3;
    const int lg = lane & 7;

    f32x4 zz = {0.f, 0.f, 0.f, 0.f};
    f32x4 acc[MI][NI];
    #pragma unroll
    for (int i = 0; i < MI; ++i)
        #pragma unroll
        for (int j = 0; j < NI; ++j) acc[i][j] = zz;

    const int sgc = ((lg ^ (lr & 7)) << 3);

    auto stage = [&](int k0, int buf) {
        #pragma unroll
        for (int j = 0; j < BM / 32; ++j) {
            int rb = wid * (BM / 4) + j * 8;
            async16(A + (long)(tm * BM + rb + lr) * 1024 + k0 + sgc, &As[buf][rb * 64]);
        }
        #pragma unroll
        for (int j = 0; j < BN / 32; ++j) {
            int rb = wid * (BN / 4) + j * 8;
            async16(Bb + (long)(tn * BN + rb + lr) * 1024 + k0 + sgc, &Bs[buf][rb * 64]);
        }
    };

    stage(0, 0);
    for (int kt = 0; kt < 16; ++kt) {
        wait_vm0_barrier();
        if (kt < 15) stage((kt + 1) * 64, (kt + 1) & 1);
        const unsigned short* Asb = As[kt & 1];
        const unsigned short* Bsb = Bs[kt & 1];
        __builtin_amdgcn_s_setprio(1);
        #pragma unroll
        for (int kd = 0; kd < 2; ++kd) {
            const int pg = ((kd * 4 + hi) ^ (r0 & 7)) << 3;
            short8 af[MI], bfr[NI];
            #pragma unroll
            for (int mi = 0; mi < MI; ++mi)
                af[mi] = *reinterpret_cast<const short8*>(&Asb[(wm * (BM/2) + mi * 16 + r0) * 64 + pg]);
            #pragma unroll
            for (int ni = 0; ni < NI; ++ni)
                bfr[ni] = *reinterpret_cast<const short8*>(&Bsb[(wn * (BN/2) + ni * 16 + r0) * 64 + pg]);
            #pragma unroll
            for (int mi = 0; mi < MI; ++mi)
                #pragma unroll
                for (int ni = 0; ni < NI; ++ni)
                    acc[mi][ni] = __builtin_amdgcn_mfma_f32_16x16x32_bf16(af[mi], bfr[ni], acc[mi][ni], 0, 0, 0);
        }
        __builtin_amdgcn_s_setprio(0);
    }

    const float QSCL = 0.08838834764831845f * 1.4426950408889634f;
    const int jr = hi * 4;
    #pragma unroll
    for (int ni = 0; ni < NI; ++ni) {
        int cg = tn * BN + wn * (BN/2) + ni * 16 + r0;
        float bv = us2f(Gb[cg]);
        if constexpr (MODE == 5) {
            if (cg >= 1024) {
                int cg2 = cg - 1024;
                int h = cg2 >> 7, d = cg2 & 127;
                #pragma unroll
                for (int mi = 0; mi < MI; ++mi) {
                    int rgb = tm * BM + wm * (BM/2) + mi * 16 + jr;
                    int b = rgb / 4608, kv = rgb - b * 4608;
                    ushort4 o;
                    o.x = f2us(acc[mi][ni][0] + bv);
                    o.y = f2us(acc[mi][ni][1] + bv);
                    o.z = f2us(acc[mi][ni][2] + bv);
                    o.w = f2us(acc[mi][ni][3] + bv);
                    *(ushort4*)&C2[((long)(b * 8 + h) * 128 + d) * 4608 + kv] = o;
                }
                continue;
            }
        }
        #pragma unroll
        for (int mi = 0; mi < MI; ++mi) {
            #pragma unroll
            for (int j = 0; j < 4; ++j) {
                int rg = tm * BM + wm * (BM/2) + mi * 16 + jr + j;
                float val = acc[mi][ni][j] + bv;
                if constexpr (MODE == 0) {
                    C[(long)rg * 1024 + cg] = f2us(val);
                } else if constexpr (MODE == 5) {
                    int b = rg / 4608, kv = rg - b * 4608;
                    int h = cg >> 7, d = cg & 127;
                    C[((long)(b * 8 + h) * 4608 + kv) * 128 + d] = f2us(val);
                } else {  // MODE 6
                    int b = rg / 576, n = rg - b * 576;
                    if (z == 8) {
                        int h = cg >> 7, d = cg & 127;
                        C2[((long)(b * 8 + h) * 576 + n) * 128 + d] = f2us(val * QSCL);
                    } else {
                        C[((long)b * 4608 + (long)z * 576 + n) * 1024 + cg] = f2us(val);
                    }
                }
            }
        }
    }
}

// Swapped-operand flash attention with ZERO-SHUFFLE PV:
// kv k-slot mapping phi(kd,8hi+e)=32kd+4hi+(e&3)+16(e>>2) makes the PV B-fragment
// lane-local ({pk0[2kd],pk1[2kd],pk0[2kd+1],pk1[2kd+1]}); V-side reads 2x ds_read_b64.
__global__ __launch_bounds__(256)
void attn_kernel6(const unsigned short* __restrict__ Qh, const unsigned short* __restrict__ Kh,
                  const unsigned short* __restrict__ VTh, unsigned short* __restrict__ Opart,
                  float2* __restrict__ Ml)
{
    const int bid = blockIdx.x;
    const int logical = (bid & 7) * 144 + (bid >> 3);   // 1152 blocks, 8-XCD grouped
    const int bhsp = logical / 9;
    const int qt = logical - bhsp * 9;
    const int bh = bhsp >> 2;
    const int sp = bhsp & 3;

    const int tid = threadIdx.x;
    const int lane = tid & 63, wid = tid >> 6;
    const int r0 = lane & 15, hi = lane >> 4;
    const int k8 = hi * 8;

    __shared__ __align__(16) unsigned short Ks[2][64 * 128];
    __shared__ __align__(16) unsigned short VT[2][128 * 64];

    short8 qf[4];
    {
        const long qoff = ((long)bh * NTOK + qt * 64 + wid * 16 + r0) * HD;
        #pragma unroll
        for (int kd = 0; kd < 4; ++kd)
            qf[kd] = *reinterpret_cast<const short8*>(Qh + qoff + kd * 32 + k8);
    }

    f32x4 zz = {0.f, 0.f, 0.f, 0.f};
    f32x4 oacc[8];   // oacc[db][j]: O^T[d=16db+4hi+j][q=r0]
    #pragma unroll
    for (int i = 0; i < 8; ++i) oacc[i] = zz;
    float mrun = -1e30f, lrun = 0.f;   // per-lane; lrun is a per-hi partial

    // hoisted staging addressing
    int offK[4], offV[4];
    #pragma unroll
    for (int j = 0; j < 4; ++j) {
        offK[j] = (wid * 16 + 4 * j + hi) * 128 + (((lane & 15) ^ ((4 * j + hi) & 7)) << 3);
        offV[j] = (wid * 32 + 8 * j + (lane >> 3)) * KN + (((lane & 7) ^ (lane >> 3)) << 3);
    }
    const unsigned short* kp = Kh + (long)bh * KN * HD + (long)(sp * (KN / NSPLIT)) * HD;
    const unsigned short* vp = VTh + (long)bh * HD * KN + sp * (KN / NSPLIT);

    auto stage = [&](int buf) {
        #pragma unroll
        for (int j = 0; j < 4; ++j) {
            async16(kp + offK[j], &Ks[buf][(wid * 16 + 4 * j) * 128]);
            async16(vp + offV[j], &VT[buf][(wid * 32 + 8 * j) * 64]);
        }
    };

    stage(0);
    for (int kt = 0; kt < NT; ++kt) {
        wait_vm0_barrier();
        if (kt < NT - 1) { kp += 64 * HD; vp += 64; stage((kt + 1) & 1); }
        const unsigned short* Ksb = Ks[kt & 1];
        const unsigned short* VTb = VT[kt & 1];

        // S^T[kv'][q=r0] = mfma(K-rows, Q-rows); s[nb][j] = P-logit[16nb+4hi+j]
        f32x4 s[4];
        #pragma unroll
        for (int nb = 0; nb < 4; ++nb) s[nb] = zz;
        __builtin_amdgcn_s_setprio(1);
        #pragma unroll
        for (int nb = 0; nb < 4; ++nb) {
            const int krow = nb * 16 + r0;
            #pragma unroll
            for (int kd = 0; kd < 4; ++kd) {
                short8 kf = *reinterpret_cast<const short8*>(
                    &Ksb[krow * 128 + (((kd * 4 + hi) ^ (r0 & 7)) << 3)]);
                s[nb] = __builtin_amdgcn_mfma_f32_16x16x32_bf16(kf, qf[kd], s[nb], 0, 0, 0);
            }
        }
        __builtin_amdgcn_s_setprio(0);

        // defer-max on per-lane partial max (equivalent: __all over the 4 hi-lanes)
        float mt = fmaxf(fmaxf(fmaxf(s[0][0], s[0][1]), fmaxf(s[0][2], s[0][3])),
                   fmaxf(fmaxf(fmaxf(s[1][0], s[1][1]), fmaxf(s[1][2], s[1][3])),
                   fmaxf(fmaxf(fmaxf(s[2][0], s[2][1]), fmaxf(s[2][2], s[2][3])),
                         fmaxf(fmaxf(s[3][0], s[3][1]), fmaxf(s[3][2], s[3][3])))));
        if (!__all(mt - mrun <= 8.0f)) {
            float mr = fmaxf(mt, __shfl_xor(mt, 16));
            mr = fmaxf(mr, __shfl_xor(mr, 32));
            float mn = fmaxf(mrun, mr);
            float scl = exp2f(mrun - mn);
            mrun = mn;
            lrun *= scl;
            #pragma unroll
            for (int db = 0; db < 8; ++db)
                #pragma unroll
                for (int j = 0; j < 4; ++j)
                    oacc[db][j] *= scl;
        }
        float p[4][4];
        float rt = 0.f;
        #pragma unroll
        for (int nb = 0; nb < 4; ++nb)
            #pragma unroll
            for (int j = 0; j < 4; ++j) {
                p[nb][j] = exp2f(s[nb][j] - mrun);
                rt += p[nb][j];
            }
        lrun += rt;   // partial; reduced across hi at the end

        unsigned pk0[4], pk1[4];
        #pragma unroll
        for (int nb = 0; nb < 4; ++nb) {
            asm("v_cvt_pk_bf16_f32 %0, %1, %2" : "=v"(pk0[nb]) : "v"(p[nb][0]), "v"(p[nb][1]));
            asm("v_cvt_pk_bf16_f32 %0, %1, %2" : "=v"(pk1[nb]) : "v"(p[nb][2]), "v"(p[nb][3]));
        }

        // O^T += mfma(V^T, P): B-frag is lane-local; V cols {32kd+4hi+0..3, +16..19}
        __builtin_amdgcn_s_setprio(1);
        #pragma unroll
        for (int kd = 0; kd < 2; ++kd) {
            i32x4 fr;
            fr[0] = (int)pk0[2 * kd];
            fr[1] = (int)pk1[2 * kd];
            fr[2] = (int)pk0[2 * kd + 1];
            fr[3] = (int)pk1[2 * kd + 1];
            short8 pf = *reinterpret_cast<short8*>(&fr);
            const int cg0 = (hi >> 1) + 4 * kd;
            const int sub = (hi & 1) << 2;
            #pragma unroll
            for (int db = 0; db < 8; ++db) {
                const int vrow = (db * 16 + r0) * 64;
                short4v lo = *(const short4v*)&VTb[vrow + ((cg0 ^ (r0 & 7)) << 3) + sub];
                short4v hh = *(const short4v*)&VTb[vrow + (((cg0 + 2) ^ (r0 & 7)) << 3) + sub];
                short8 vf = {lo[0], lo[1], lo[2], lo[3], hh[0], hh[1], hh[2], hh[3]};
                oacc[db] = __builtin_amdgcn_mfma_f32_16x16x32_bf16(vf, pf, oacc[db], 0, 0, 0);
            }
        }
        __builtin_amdgcn_s_setprio(0);
    }

    lrun += __shfl_xor(lrun, 16);
    lrun += __shfl_xor(lrun, 32);
    const float inv = 1.f / lrun;
    const long po = ((long)(sp * 32 + bh) * NTOK + qt * 64 + wid * 16 + r0) * HD;
    #pragma unroll
    for (int db = 0; db < 8; ++db) {
        ushort4 o;
        o.x = f2us(oacc[db][0] * inv);
        o.y = f2us(oacc[db][1] * inv);
        o.z = f2us(oacc[db][2] * inv);
        o.w = f2us(oacc[db][3] * inv);
        *(ushort4*)&Opart[po + db * 16 + hi * 4] = o;
    }
    if (lane < 16) {
        const long mo = (long)(sp * 32 + bh) * NTOK + qt * 64 + wid * 16 + r0;
        Ml[mo] = make_float2(mrun, lrun);   // log2 domain
    }
}

// Combine NSPLIT partials -> Ob[(b*576+n)*1024 + h*128 + d]
__global__ __launch_bounds__(256)
void attn_reduce(const unsigned short* __restrict__ Opart, const float2* __restrict__ Ml,
                 unsigned short* __restrict__ Ob)
{
    const int qt = blockIdx.x, bh = blockIdx.y;
    const int t = threadIdx.x;
    const int rl = t >> 2, dc = (t & 3) * 32;
    const int q = qt * 64 + rl;

    float m[NSPLIT], l[NSPLIT];
    float M = -1e30f;
    #pragma unroll
    for (int sp = 0; sp < NSPLIT; ++sp) {
        float2 v = Ml[(long)(sp * 32 + bh) * NTOK + q];
        m[sp] = v.x; l[sp] = v.y;
        M = fmaxf(M, v.x);
    }
    float w[NSPLIT], denom = 0.f;
    #pragma unroll
    for (int sp = 0; sp < NSPLIT; ++sp) {
        w[sp] = l[sp] * exp2f(m[sp] - M);
        denom += w[sp];
    }
    const float inv = 1.f / denom;
    const int b = bh >> 3, h = bh & 7;
    #pragma unroll
    for (int dj = 0; dj < 4; ++dj) {
        float a[8];
        #pragma unroll
        for (int e = 0; e < 8; ++e) a[e] = 0.f;
        #pragma unroll
        for (int sp = 0; sp < NSPLIT; ++sp) {
            short8 v = *reinterpret_cast<const short8*>(
                &Opart[((long)(sp * 32 + bh) * NTOK + q) * HD + dc + dj * 8]);
            #pragma unroll
            for (int e = 0; e < 8; ++e)
                a[e] += w[sp] * us2f((unsigned short)v[e]);
        }
        short8 o;
        #pragma unroll
        for (int e = 0; e < 8; ++e) o[e] = (short)f2us(a[e] * inv);
        *reinterpret_cast<short8*>(&Ob[((long)b * NTOK + q) * 1024 + h * 128 + dc + dj * 8]) = o;
    }
}

// LayerNorm(y)*g + b + vision; output dtype per meta[0]
__global__ __launch_bounds__(256)
void ln2_kernel(const unsigned short* __restrict__ Y, const unsigned short* __restrict__ g,
                const unsigned short* __restrict__ be, const unsigned short* __restrict__ vis,
                void* __restrict__ dout, const int* __restrict__ meta)
{
    const int row = blockIdx.x;
    const int tid = threadIdx.x;
    const int lane = tid & 63, wid = tid >> 6;
    const unsigned short* yr = Y + (long)row * DIM;
    ushort4 raw = reinterpret_cast<const ushort4*>(yr)[tid];
    float v[4];
    v[0] = us2f(raw.x); v[1] = us2f(raw.y); v[2] = us2f(raw.z); v[3] = us2f(raw.w);
    float s1 = 0.f, s2 = 0.f;
    #pragma unroll
    for (int i = 0; i < 4; ++i) { s1 += v[i]; s2 += v[i] * v[i]; }
    #pragma unroll
    for (int off = 1; off < 64; off <<= 1) {
        s1 += __shfl_xor(s1, off);
        s2 += __shfl_xor(s2, off);
    }
    __shared__ float red[2][4];
    if (lane == 0) { red[0][wid] = s1; red[1][wid] = s2; }
    __syncthreads();
    s1 = red[0][0] + red[0][1] + red[0][2] + red[0][3];
    s2 = red[1][0] + red[1][1] + red[1][2] + red[1][3];
    const float mu = s1 * (1.f / DIM);
    const float var = s2 * (1.f / DIM) - mu * mu;
    const float inv = rsqrtf(var + 1e-5f);
    ushort4 gg = reinterpret_cast<const ushort4*>(g)[tid];
    ushort4 bb = reinterpret_cast<const ushort4*>(be)[tid];
    ushort4 vv = reinterpret_cast<const ushort4*>(vis + (long)row * DIM)[tid];
    float o0 = (v[0] - mu) * inv * us2f(gg.x) + us2f(bb.x) + us2f(vv.x);
    float o1 = (v[1] - mu) * inv * us2f(gg.y) + us2f(bb.y) + us2f(vv.y);
    float o2 = (v[2] - mu) * inv * us2f(gg.z) + us2f(bb.z) + us2f(vv.z);
    float o3 = (v[3] - mu) * inv * us2f(gg.w) + us2f(bb.w) + us2f(vv.w);
    if (meta[0]) {
        ushort4 o;
        o.x = f2us(o0); o.y = f2us(o1); o.z = f2us(o2); o.w = f2us(o3);
        reinterpret_cast<ushort4*>((unsigned short*)dout + (long)row * DIM)[tid] = o;
    } else {
        float4 o = make_float4(o0, o1, o2, o3);
        reinterpret_cast<float4*>((float*)dout + (long)row * DIM)[tid] = o;
    }
}

extern "C" void kernel_launch(void* const* d_in, const int* in_sizes, int n_in,
                              void* d_out, int out_size, void* d_ws, size_t ws_size,
                              hipStream_t stream)
{
    // scan_idx (d_in[11]) unused: all 8 scans are bijections on the 576 cells and
    // softmax over the full K*N key axis (K,V share row order) is permutation-
    // invariant per direction block -> gather elided.
    unsigned long long w = (unsigned long long)d_ws;
    int* meta = (int*)w; w += 256;

    const int cidx[10] = {0, 2, 3, 4, 5, 6, 7, 8, 9, 10};
    const long csz[10] = {
        (long)NB * NTOK * DIM,  // vision
        (long)KDIR * DIM,       // dirb
        3L * DIM * DIM,         // inW
        3L * DIM,               // inB
        (long)DIM * DIM,        // outW
        DIM,                    // outB
        (long)DIM * DIM,        // finW
        DIM, DIM, DIM           // finB, lng, lnb
    };
    unsigned short* cv[10];
    for (int i = 0; i < 10; ++i) {
        cv[i] = (unsigned short*)w;
        w += (csz[i] * 2 + 255) & ~255ULL;
    }
    unsigned short* dWT = (unsigned short*)w; w += (long)KDIR * DIM * DIM * 2;

    const size_t big = (size_t)NB * KDIR * NTOK * DIM * 2;   // 37.75 MB
    const size_t sml = (size_t)NB * NTOK * DIM * 2;          // 4.72 MB
    unsigned short* dirs = (unsigned short*)w; w += big;     // aliased as Opart later
    unsigned short* Kh   = (unsigned short*)w; w += big;
    unsigned short* VTh  = (unsigned short*)w; w += big;
    unsigned short* Qh   = (unsigned short*)w; w += sml;
    unsigned short* Ob   = (unsigned short*)w; w += sml;
    unsigned short* Fu   = (unsigned short*)w; w += sml;
    unsigned short* Y2   = (unsigned short*)w; w += sml;
    float2* Ml = (float2*)w; w += (long)NSPLIT * 32 * NTOK * sizeof(float2);
    unsigned short* Opart = dirs;   // dirs is dead once KV GEMM completes

    const unsigned short* vision = cv[0];
    const unsigned short* dirb = cv[1];
    const unsigned short* inW = cv[2];
    const unsigned short* inB = cv[3];
    const unsigned short* outW = cv[4];
    const unsigned short* outB = cv[5];
    const unsigned short* finW = cv[6];
    const unsigned short* finB = cv[7];
    const unsigned short* lng = cv[8];
    const unsigned short* lnbt = cv[9];

    dim3 blk(256, 1, 1);

    // 0. dtype detect
    detect_kernel<<<dim3(1), dim3(64), 0, stream>>>((const unsigned int*)d_in[1], meta);

    // 1. single fused conversion launch (+ transposed dirW)
    ConvJobs J;
    int bacc = 0;
    for (int i = 0; i < 10; ++i) {
        J.src[i] = d_in[cidx[i]];
        J.dst[i] = cv[i];
        J.n4[i] = (int)(csz[i] / 4);
        J.bstart[i] = bacc;
        bacc += (int)((csz[i] / 4 + 1023) / 1024);
    }
    conv_all<<<dim3(bacc), blk, 0, stream>>>(J, meta);
    transpose_conv<<<dim3(1024, KDIR), blk, 0, stream>>>(d_in[1], dWT, meta);

    // 2. merged dirs(z<8)+Q(z==8, pre-scaled) GEMM: A=vision, M=2304
    gemm_glds<6, 8, 128, 128><<<dim3(18 * 8, 9), blk, 0, stream>>>(
        vision, dWT, dirb, dirs, inW, inB, Qh, NB * NTOK, (long)DIM * DIM, DIM);

    // 3. fused K+V GEMM (wk||wv contiguous): K->Kh, V->VTh
    gemm_glds<5, 16, 128, 128><<<dim3(144 * 16, 1), blk, 0, stream>>>(
        dirs, inW + DIM * DIM, inB + DIM, Kh, nullptr, nullptr, VTh, NB * KN, 0L, 0L);

    // 4. KV-split zero-shuffle flash attention -> Opart (aliases dirs) + Ml
    attn_kernel6<<<dim3(9 * 32 * NSPLIT), blk, 0, stream>>>(Qh, Kh, VTh, Opart, Ml);

    // 5. combine partials -> Ob [b,n,h*128+d]
    attn_reduce<<<dim3(9, 32), blk, 0, stream>>>(Opart, Ml, Ob);

    // 6. fused = Ob @ out_proj^T + b   (64x64 tile: 576 blocks)
    gemm_glds<0, 16, 64, 64><<<dim3(36 * 16, 1), blk, 0, stream>>>(
        Ob, outW, outB, Fu, nullptr, nullptr, nullptr, NB * NTOK, 0L, 0L);

    // 7. y = fused @ fin^T + b
    gemm_glds<0, 16, 64, 64><<<dim3(36 * 16, 1), blk, 0, stream>>>(
        Fu, finW, finB, Y2, nullptr, nullptr, nullptr, NB * NTOK, 0L, 0L);

    // 8. LayerNorm + residual -> d_out
    ln2_kernel<<<dim3(NB * NTOK), blk, 0, stream>>>(Y2, lng, lnbt, vision, d_out, meta);
}

// Round 8
// 346.234 us; speedup vs baseline: 2.8833x; 1.1257x over previous
//
#include <hip/hip_runtime.h>
#include <hip/hip_bf16.h>

typedef __attribute__((ext_vector_type(8))) short short8;
typedef __attribute__((ext_vector_type(4))) float f32x4;
typedef __attribute__((ext_vector_type(4))) int i32x4;

#define NTOK 576
#define DIM  1024
#define NB   4
#define NH   8
#define HD   128
#define KDIR 8
#define KN   4608
#define NSPLIT 8
#define NT 9                  // KN/NSPLIT/64

__device__ __forceinline__ float us2f(unsigned short u) {
    unsigned int x = ((unsigned int)u) << 16;
    return __uint_as_float(x);
}
__device__ __forceinline__ unsigned short f2us(float f) {
    unsigned int x = __float_as_uint(f);
    unsigned int r = x + 0x7fffu + ((x >> 16) & 1u);
    return (unsigned short)(r >> 16);
}

typedef __attribute__((address_space(3))) unsigned int lds_uint;
typedef const __attribute__((address_space(1))) unsigned int glb_uint;
__device__ __forceinline__ void async16(const unsigned short* g, unsigned short* l) {
    __builtin_amdgcn_global_load_lds((glb_uint*)g, (lds_uint*)l, 16, 0, 0);
}
__device__ __forceinline__ void wait_vm0_barrier() {
    asm volatile("s_waitcnt vmcnt(0)" ::: "memory");
    __builtin_amdgcn_s_barrier();
    __builtin_amdgcn_sched_barrier(0);
}

// meta[0] = 1 if device buffers are bf16, 0 if f32
__global__ void detect_kernel(const unsigned int* __restrict__ src, int* meta)
{
    if (threadIdx.x == 0) {
        int cnt = 0;
        for (int i = 0; i < 256; ++i) {
            unsigned u = src[(long)i * 16384] & 0xFFFFu;
            unsigned e = (u >> 7) & 0xFFu;
            cnt += (e >= 90 && e <= 150) ? 1 : 0;
        }
        meta[0] = (cnt >= 192) ? 1 : 0;
    }
}

// All 10 small conversions in one launch.
struct ConvJobs {
    const void* src[10];
    unsigned short* dst[10];
    int n4[10];
    int bstart[10];
};
__global__ __launch_bounds__(256)
void conv_all(ConvJobs J, const int* __restrict__ meta)
{
    const int b = blockIdx.x;
    int ji = 0;
    #pragma unroll
    for (int i = 1; i < 10; ++i) if (b >= J.bstart[i]) ji = i;
    const long base = (long)(b - J.bstart[ji]) * 1024 + threadIdx.x;
    const long n4 = J.n4[ji];
    if (meta[0]) {
        const ushort4* s = (const ushort4*)J.src[ji];
        ushort4* d = (ushort4*)J.dst[ji];
        #pragma unroll
        for (int t = 0; t < 4; ++t) {
            long i = base + t * 256;
            if (i < n4) d[i] = s[i];
        }
    } else {
        const float4* s = (const float4*)J.src[ji];
        ushort4* d = (ushort4*)J.dst[ji];
        #pragma unroll
        for (int t = 0; t < 4; ++t) {
            long i = base + t * 256;
            if (i < n4) {
                float4 v = s[i];
                ushort4 o;
                o.x = f2us(v.x); o.y = f2us(v.y); o.z = f2us(v.z); o.w = f2us(v.w);
                d[i] = o;
            }
        }
    }
}

// dirW [8][1024 d][1024 e] -> dWT [8][1024 e][1024 d]
__global__ __launch_bounds__(256)
void transpose_conv(const void* __restrict__ src, unsigned short* __restrict__ dst,
                    const int* __restrict__ meta)
{
    const int k = blockIdx.y;
    const int ty = blockIdx.x >> 5, tx = blockIdx.x & 31;
    const int d0 = ty * 32, e0 = tx * 32;
    __shared__ float tl[32][33];
    const int t = threadIdx.x;
    const int row = t >> 3, c4 = (t & 7) * 4;
    const long sbase = ((long)k * 1024 + d0 + row) * 1024 + e0 + c4;
    if (meta[0]) {
        const unsigned short* s = (const unsigned short*)src;
        ushort4 v = *(const ushort4*)(s + sbase);
        tl[row][c4+0] = us2f(v.x); tl[row][c4+1] = us2f(v.y);
        tl[row][c4+2] = us2f(v.z); tl[row][c4+3] = us2f(v.w);
    } else {
        const float* s = (const float*)src;
        float4 v = *(const float4*)(s + sbase);
        tl[row][c4+0] = v.x; tl[row][c4+1] = v.y;
        tl[row][c4+2] = v.z; tl[row][c4+3] = v.w;
    }
    __syncthreads();
    ushort4 o;
    o.x = f2us(tl[c4+0][row]); o.y = f2us(tl[c4+1][row]);
    o.z = f2us(tl[c4+2][row]); o.w = f2us(tl[c4+3][row]);
    *(ushort4*)(dst + ((long)k * 1024 + e0 + row) * 1024 + d0 + c4) = o;
}

// C = A[M x 1024] @ B^T + bias. Tile BM x BN, BK=64, double-buffered glds staging.
// MODE: 0 row-major C; 5 fused KV (cg<1024 -> Kh [bh][kv][128], else VTh [bh][128][4608]
//       with kv phi-permuted within each 64-block for the attn b128 PV reads);
//       6 merged dirs(z<8)+Q(z==8, pre-scaled by 1/sqrt(128)*log2e)
template<int MODE, int TN, int BM, int BN>
__global__ __launch_bounds__(256)
void gemm_glds(const unsigned short* __restrict__ A, const unsigned short* __restrict__ Bw,
               const unsigned short* __restrict__ bias, unsigned short* __restrict__ C,
               const unsigned short* __restrict__ B2, const unsigned short* __restrict__ bias2,
               unsigned short* __restrict__ C2,
               int M, long bStride, long biasStride)
{
    constexpr int MI = BM / 32, NI = BN / 32;
    const int z = blockIdx.y;
    const unsigned short* Bb;
    const unsigned short* Gb;
    if constexpr (MODE == 6) {
        Bb = (z < 8) ? Bw + (long)z * bStride : B2;
        Gb = (z < 8) ? bias + (long)z * biasStride : bias2;
    } else {
        Bb = Bw + (long)z * bStride;
        Gb = bias + (long)z * biasStride;
    }
    const int tm = blockIdx.x / TN;
    const int tn = blockIdx.x % TN;

    __shared__ __align__(16) unsigned short As[2][BM * 64];
    __shared__ __align__(16) unsigned short Bs[2][BN * 64];

    const int tid = threadIdx.x, lane = tid & 63, wid = tid >> 6;
    const int wm = wid >> 1, wn = wid & 1;
    const int r0 = lane & 15, hi = lane >> 4;
    const int lr = lane >> 3;
    const int lg = lane & 7;

    f32x4 zz = {0.f, 0.f, 0.f, 0.f};
    f32x4 acc[MI][NI];
    #pragma unroll
    for (int i = 0; i < MI; ++i)
        #pragma unroll
        for (int j = 0; j < NI; ++j) acc[i][j] = zz;

    const int sgc = ((lg ^ (lr & 7)) << 3);

    auto stage = [&](int k0, int buf) {
        #pragma unroll
        for (int j = 0; j < BM / 32; ++j) {
            int rb = wid * (BM / 4) + j * 8;
            async16(A + (long)(tm * BM + rb + lr) * 1024 + k0 + sgc, &As[buf][rb * 64]);
        }
        #pragma unroll
        for (int j = 0; j < BN / 32; ++j) {
            int rb = wid * (BN / 4) + j * 8;
            async16(Bb + (long)(tn * BN + rb + lr) * 1024 + k0 + sgc, &Bs[buf][rb * 64]);
        }
    };

    stage(0, 0);
    for (int kt = 0; kt < 16; ++kt) {
        wait_vm0_barrier();
        if (kt < 15) stage((kt + 1) * 64, (kt + 1) & 1);
        const unsigned short* Asb = As[kt & 1];
        const unsigned short* Bsb = Bs[kt & 1];
        __builtin_amdgcn_s_setprio(1);
        #pragma unroll
        for (int kd = 0; kd < 2; ++kd) {
            const int pg = ((kd * 4 + hi) ^ (r0 & 7)) << 3;
            short8 af[MI], bfr[NI];
            #pragma unroll
            for (int mi = 0; mi < MI; ++mi)
                af[mi] = *reinterpret_cast<const short8*>(&Asb[(wm * (BM/2) + mi * 16 + r0) * 64 + pg]);
            #pragma unroll
            for (int ni = 0; ni < NI; ++ni)
                bfr[ni] = *reinterpret_cast<const short8*>(&Bsb[(wn * (BN/2) + ni * 16 + r0) * 64 + pg]);
            #pragma unroll
            for (int mi = 0; mi < MI; ++mi)
                #pragma unroll
                for (int ni = 0; ni < NI; ++ni)
                    acc[mi][ni] = __builtin_amdgcn_mfma_f32_16x16x32_bf16(af[mi], bfr[ni], acc[mi][ni], 0, 0, 0);
        }
        __builtin_amdgcn_s_setprio(0);
    }

    const float QSCL = 0.08838834764831845f * 1.4426950408889634f;
    const int jr = hi * 4;
    #pragma unroll
    for (int ni = 0; ni < NI; ++ni) {
        int cg = tn * BN + wn * (BN/2) + ni * 16 + r0;
        float bv = us2f(Gb[cg]);
        if constexpr (MODE == 5) {
            if (cg >= 1024) {
                int cg2 = cg - 1024;
                int h = cg2 >> 7, d = cg2 & 127;
                #pragma unroll
                for (int mi = 0; mi < MI; ++mi) {
                    int rgb = tm * BM + wm * (BM/2) + mi * 16 + jr;
                    int b = rgb / 4608, kv = rgb - b * 4608;
                    // phi-permute kv within its 64-block: P = [b5][b3][b2][b4][b1b0]
                    int r = kv & 63;
                    int P = ((r >> 5) & 1) * 32 + ((r >> 3) & 1) * 16 + ((r >> 2) & 1) * 8
                          + ((r >> 4) & 1) * 4 + (r & 3);
                    ushort4 o;
                    o.x = f2us(acc[mi][ni][0] + bv);
                    o.y = f2us(acc[mi][ni][1] + bv);
                    o.z = f2us(acc[mi][ni][2] + bv);
                    o.w = f2us(acc[mi][ni][3] + bv);
                    *(ushort4*)&C2[((long)(b * 8 + h) * 128 + d) * 4608 + (kv & ~63) + P] = o;
                }
                continue;
            }
        }
        #pragma unroll
        for (int mi = 0; mi < MI; ++mi) {
            #pragma unroll
            for (int j = 0; j < 4; ++j) {
                int rg = tm * BM + wm * (BM/2) + mi * 16 + jr + j;
                float val = acc[mi][ni][j] + bv;
                if constexpr (MODE == 0) {
                    C[(long)rg * 1024 + cg] = f2us(val);
                } else if constexpr (MODE == 5) {
                    int b = rg / 4608, kv = rg - b * 4608;
                    int h = cg >> 7, d = cg & 127;
                    C[((long)(b * 8 + h) * 4608 + kv) * 128 + d] = f2us(val);
                } else {  // MODE 6
                    int b = rg / 576, n = rg - b * 576;
                    if (z == 8) {
                        int h = cg >> 7, d = cg & 127;
                        C2[((long)(b * 8 + h) * 576 + n) * 128 + d] = f2us(val * QSCL);
                    } else {
                        C[((long)b * 4608 + (long)z * 576 + n) * 1024 + cg] = f2us(val);
                    }
                }
            }
        }
    }
}

// 3-chunk swapped-operand flash attention: 192 q rows per block (48/wave).
// Each K/V LDS b128 read feeds 3 MFMAs (one per q-chunk) -> 3x LDS amortization.
// V^T global is phi-permuted so the PV A-fragment is one contiguous b128 and the
// P B-fragment is lane-local (zero shuffles, zero extra conflicts).
__global__ __launch_bounds__(256, 2)
void attn_kernel7(const unsigned short* __restrict__ Qh, const unsigned short* __restrict__ Kh,
                  const unsigned short* __restrict__ VTh, unsigned short* __restrict__ Opart,
                  float2* __restrict__ Ml)
{
    const int bid = blockIdx.x;
    const int logical = (bid & 7) * 96 + (bid >> 3);   // 768 blocks, XCD-grouped
    const int bhsp = logical / 3;
    const int qt = logical - bhsp * 3;                 // 0..2, 192-q tiles
    const int bh = bhsp >> 3;
    const int sp = bhsp & 7;

    const int tid = threadIdx.x;
    const int lane = tid & 63, wid = tid >> 6;
    const int r0 = lane & 15, hi = lane >> 4;

    __shared__ __align__(16) unsigned short Ks[2][64 * 128];
    __shared__ __align__(16) unsigned short VT[2][128 * 64];

    short8 qf[3][4];
    #pragma unroll
    for (int c = 0; c < 3; ++c) {
        const long qoff = ((long)bh * NTOK + qt * 192 + c * 64 + wid * 16 + r0) * HD + hi * 8;
        #pragma unroll
        for (int kd = 0; kd < 4; ++kd)
            qf[c][kd] = *reinterpret_cast<const short8*>(Qh + qoff + kd * 32);
    }

    f32x4 zz = {0.f, 0.f, 0.f, 0.f};
    f32x4 oacc[3][8];
    #pragma unroll
    for (int c = 0; c < 3; ++c)
        #pragma unroll
        for (int i = 0; i < 8; ++i) oacc[c][i] = zz;
    float mrun[3], lrun[3];
    #pragma unroll
    for (int c = 0; c < 3; ++c) { mrun[c] = -1e30f; lrun[c] = 0.f; }

    int offK[4], offV[4];
    #pragma unroll
    for (int j = 0; j < 4; ++j) {
        offK[j] = (wid * 16 + 4 * j + hi) * 128 + (((lane & 15) ^ ((4 * j + hi) & 7)) << 3);
        offV[j] = (wid * 32 + 8 * j + (lane >> 3)) * KN + (((lane & 7) ^ (lane >> 3)) << 3);
    }
    const unsigned short* kp = Kh + (long)bh * KN * HD + (long)(sp * (KN / NSPLIT)) * HD;
    const unsigned short* vp = VTh + (long)bh * HD * KN + sp * (KN / NSPLIT);

    auto stage = [&](int buf) {
        #pragma unroll
        for (int j = 0; j < 4; ++j) {
            async16(kp + offK[j], &Ks[buf][(wid * 16 + 4 * j) * 128]);
            async16(vp + offV[j], &VT[buf][(wid * 32 + 8 * j) * 64]);
        }
    };

    stage(0);
    for (int kt = 0; kt < NT; ++kt) {
        wait_vm0_barrier();
        if (kt < NT - 1) { kp += 64 * HD; vp += 64; stage((kt + 1) & 1); }
        const unsigned short* Ksb = Ks[kt & 1];
        const unsigned short* VTb = VT[kt & 1];

        // QK: each kf read feeds 3 MFMAs
        f32x4 s[3][4];
        #pragma unroll
        for (int c = 0; c < 3; ++c)
            #pragma unroll
            for (int nb = 0; nb < 4; ++nb) s[c][nb] = zz;
        __builtin_amdgcn_s_setprio(1);
        #pragma unroll
        for (int nb = 0; nb < 4; ++nb) {
            #pragma unroll
            for (int kd = 0; kd < 4; ++kd) {
                short8 kf = *reinterpret_cast<const short8*>(
                    &Ksb[(nb * 16 + r0) * 128 + (((kd * 4 + hi) ^ (r0 & 7)) << 3)]);
                s[0][nb] = __builtin_amdgcn_mfma_f32_16x16x32_bf16(kf, qf[0][kd], s[0][nb], 0, 0, 0);
                s[1][nb] = __builtin_amdgcn_mfma_f32_16x16x32_bf16(kf, qf[1][kd], s[1][nb], 0, 0, 0);
                s[2][nb] = __builtin_amdgcn_mfma_f32_16x16x32_bf16(kf, qf[2][kd], s[2][nb], 0, 0, 0);
            }
        }
        __builtin_amdgcn_s_setprio(0);

        // softmax per chunk (per-lane, exp2 domain, defer-max)
        unsigned pk0[3][4], pk1[3][4];
        #pragma unroll
        for (int c = 0; c < 3; ++c) {
            float mt = fmaxf(fmaxf(fmaxf(s[c][0][0], s[c][0][1]), fmaxf(s[c][0][2], s[c][0][3])),
                       fmaxf(fmaxf(fmaxf(s[c][1][0], s[c][1][1]), fmaxf(s[c][1][2], s[c][1][3])),
                       fmaxf(fmaxf(fmaxf(s[c][2][0], s[c][2][1]), fmaxf(s[c][2][2], s[c][2][3])),
                             fmaxf(fmaxf(s[c][3][0], s[c][3][1]), fmaxf(s[c][3][2], s[c][3][3])))));
            if (!__all(mt - mrun[c] <= 8.0f)) {
                float mr = fmaxf(mt, __shfl_xor(mt, 16));
                mr = fmaxf(mr, __shfl_xor(mr, 32));
                float mn = fmaxf(mrun[c], mr);
                float scl = exp2f(mrun[c] - mn);
                mrun[c] = mn;
                lrun[c] *= scl;
                #pragma unroll
                for (int db = 0; db < 8; ++db)
                    #pragma unroll
                    for (int j = 0; j < 4; ++j)
                        oacc[c][db][j] *= scl;
            }
            float rt = 0.f;
            #pragma unroll
            for (int nb = 0; nb < 4; ++nb)
                #pragma unroll
                for (int j = 0; j < 4; ++j) {
                    s[c][nb][j] = exp2f(s[c][nb][j] - mrun[c]);
                    rt += s[c][nb][j];
                }
            lrun[c] += rt;   // per-hi partial; reduced at the end
            #pragma unroll
            for (int nb = 0; nb < 4; ++nb) {
                asm("v_cvt_pk_bf16_f32 %0, %1, %2" : "=v"(pk0[c][nb]) : "v"(s[c][nb][0]), "v"(s[c][nb][1]));
                asm("v_cvt_pk_bf16_f32 %0, %1, %2" : "=v"(pk1[c][nb]) : "v"(s[c][nb][2]), "v"(s[c][nb][3]));
            }
        }

        // PV: each vf read feeds 3 MFMAs; P-fragment lane-local
        __builtin_amdgcn_s_setprio(1);
        #pragma unroll
        for (int kd = 0; kd < 2; ++kd) {
            short8 pf[3];
            #pragma unroll
            for (int c = 0; c < 3; ++c) {
                i32x4 fr;
                fr[0] = (int)pk0[c][2 * kd];
                fr[1] = (int)pk1[c][2 * kd];
                fr[2] = (int)pk0[c][2 * kd + 1];
                fr[3] = (int)pk1[c][2 * kd + 1];
                pf[c] = *reinterpret_cast<short8*>(&fr);
            }
            #pragma unroll
            for (int db = 0; db < 8; ++db) {
                short8 vf = *reinterpret_cast<const short8*>(
                    &VTb[(db * 16 + r0) * 64 + (((kd * 4 + hi) ^ (r0 & 7)) << 3)]);
                oacc[0][db] = __builtin_amdgcn_mfma_f32_16x16x32_bf16(vf, pf[0], oacc[0][db], 0, 0, 0);
                oacc[1][db] = __builtin_amdgcn_mfma_f32_16x16x32_bf16(vf, pf[1], oacc[1][db], 0, 0, 0);
                oacc[2][db] = __builtin_amdgcn_mfma_f32_16x16x32_bf16(vf, pf[2], oacc[2][db], 0, 0, 0);
            }
        }
        __builtin_amdgcn_s_setprio(0);
    }

    #pragma unroll
    for (int c = 0; c < 3; ++c) {
        float lr = lrun[c];
        lr += __shfl_xor(lr, 16);
        lr += __shfl_xor(lr, 32);
        const float inv = 1.f / lr;
        const long po = ((long)(sp * 32 + bh) * NTOK + qt * 192 + c * 64 + wid * 16 + r0) * HD;
        #pragma unroll
        for (int db = 0; db < 8; ++db) {
            ushort4 o;
            o.x = f2us(oacc[c][db][0] * inv);
            o.y = f2us(oacc[c][db][1] * inv);
            o.z = f2us(oacc[c][db][2] * inv);
            o.w = f2us(oacc[c][db][3] * inv);
            *(ushort4*)&Opart[po + db * 16 + hi * 4] = o;
        }
        if (lane < 16) {
            const long mo = (long)(sp * 32 + bh) * NTOK + qt * 192 + c * 64 + wid * 16 + r0;
            Ml[mo] = make_float2(mrun[c], lr);   // log2 domain
        }
    }
}

// Combine NSPLIT partials -> Ob[(b*576+n)*1024 + h*128 + d]
__global__ __launch_bounds__(256)
void attn_reduce(const unsigned short* __restrict__ Opart, const float2* __restrict__ Ml,
                 unsigned short* __restrict__ Ob)
{
    const int qt = blockIdx.x, bh = blockIdx.y;
    const int t = threadIdx.x;
    const int rl = t >> 2, dc = (t & 3) * 32;
    const int q = qt * 64 + rl;

    float m[NSPLIT], l[NSPLIT];
    float M = -1e30f;
    #pragma unroll
    for (int sp = 0; sp < NSPLIT; ++sp) {
        float2 v = Ml[(long)(sp * 32 + bh) * NTOK + q];
        m[sp] = v.x; l[sp] = v.y;
        M = fmaxf(M, v.x);
    }
    float w[NSPLIT], denom = 0.f;
    #pragma unroll
    for (int sp = 0; sp < NSPLIT; ++sp) {
        w[sp] = l[sp] * exp2f(m[sp] - M);
        denom += w[sp];
    }
    const float inv = 1.f / denom;
    const int b = bh >> 3, h = bh & 7;
    #pragma unroll
    for (int dj = 0; dj < 4; ++dj) {
        float a[8];
        #pragma unroll
        for (int e = 0; e < 8; ++e) a[e] = 0.f;
        #pragma unroll
        for (int sp = 0; sp < NSPLIT; ++sp) {
            short8 v = *reinterpret_cast<const short8*>(
                &Opart[((long)(sp * 32 + bh) * NTOK + q) * HD + dc + dj * 8]);
            #pragma unroll
            for (int e = 0; e < 8; ++e)
                a[e] += w[sp] * us2f((unsigned short)v[e]);
        }
        short8 o;
        #pragma unroll
        for (int e = 0; e < 8; ++e) o[e] = (short)f2us(a[e] * inv);
        *reinterpret_cast<short8*>(&Ob[((long)b * NTOK + q) * 1024 + h * 128 + dc + dj * 8]) = o;
    }
}

// LayerNorm(y)*g + b + vision; output dtype per meta[0]
__global__ __launch_bounds__(256)
void ln2_kernel(const unsigned short* __restrict__ Y, const unsigned short* __restrict__ g,
                const unsigned short* __restrict__ be, const unsigned short* __restrict__ vis,
                void* __restrict__ dout, const int* __restrict__ meta)
{
    const int row = blockIdx.x;
    const int tid = threadIdx.x;
    const int lane = tid & 63, wid = tid >> 6;
    const unsigned short* yr = Y + (long)row * DIM;
    ushort4 raw = reinterpret_cast<const ushort4*>(yr)[tid];
    float v[4];
    v[0] = us2f(raw.x); v[1] = us2f(raw.y); v[2] = us2f(raw.z); v[3] = us2f(raw.w);
    float s1 = 0.f, s2 = 0.f;
    #pragma unroll
    for (int i = 0; i < 4; ++i) { s1 += v[i]; s2 += v[i] * v[i]; }
    #pragma unroll
    for (int off = 1; off < 64; off <<= 1) {
        s1 += __shfl_xor(s1, off);
        s2 += __shfl_xor(s2, off);
    }
    __shared__ float red[2][4];
    if (lane == 0) { red[0][wid] = s1; red[1][wid] = s2; }
    __syncthreads();
    s1 = red[0][0] + red[0][1] + red[0][2] + red[0][3];
    s2 = red[1][0] + red[1][1] + red[1][2] + red[1][3];
    const float mu = s1 * (1.f / DIM);
    const float var = s2 * (1.f / DIM) - mu * mu;
    const float inv = rsqrtf(var + 1e-5f);
    ushort4 gg = reinterpret_cast<const ushort4*>(g)[tid];
    ushort4 bb = reinterpret_cast<const ushort4*>(be)[tid];
    ushort4 vv = reinterpret_cast<const ushort4*>(vis + (long)row * DIM)[tid];
    float o0 = (v[0] - mu) * inv * us2f(gg.x) + us2f(bb.x) + us2f(vv.x);
    float o1 = (v[1] - mu) * inv * us2f(gg.y) + us2f(bb.y) + us2f(vv.y);
    float o2 = (v[2] - mu) * inv * us2f(gg.z) + us2f(bb.z) + us2f(vv.z);
    float o3 = (v[3] - mu) * inv * us2f(gg.w) + us2f(bb.w) + us2f(vv.w);
    if (meta[0]) {
        ushort4 o;
        o.x = f2us(o0); o.y = f2us(o1); o.z = f2us(o2); o.w = f2us(o3);
        reinterpret_cast<ushort4*>((unsigned short*)dout + (long)row * DIM)[tid] = o;
    } else {
        float4 o = make_float4(o0, o1, o2, o3);
        reinterpret_cast<float4*>((float*)dout + (long)row * DIM)[tid] = o;
    }
}

extern "C" void kernel_launch(void* const* d_in, const int* in_sizes, int n_in,
                              void* d_out, int out_size, void* d_ws, size_t ws_size,
                              hipStream_t stream)
{
    // scan_idx (d_in[11]) unused: all 8 scans are bijections on the 576 cells and
    // softmax over the full K*N key axis (K,V share row order) is permutation-
    // invariant per direction block -> gather elided.
    unsigned long long w = (unsigned long long)d_ws;
    int* meta = (int*)w; w += 256;

    const int cidx[10] = {0, 2, 3, 4, 5, 6, 7, 8, 9, 10};
    const long csz[10] = {
        (long)NB * NTOK * DIM,  // vision
        (long)KDIR * DIM,       // dirb
        3L * DIM * DIM,         // inW
        3L * DIM,               // inB
        (long)DIM * DIM,        // outW
        DIM,                    // outB
        (long)DIM * DIM,        // finW
        DIM, DIM, DIM           // finB, lng, lnb
    };
    unsigned short* cv[10];
    for (int i = 0; i < 10; ++i) {
        cv[i] = (unsigned short*)w;
        w += (csz[i] * 2 + 255) & ~255ULL;
    }
    unsigned short* dWT = (unsigned short*)w; w += (long)KDIR * DIM * DIM * 2;

    const size_t big = (size_t)NB * KDIR * NTOK * DIM * 2;   // 37.75 MB
    const size_t sml = (size_t)NB * NTOK * DIM * 2;          // 4.72 MB
    unsigned short* dirs = (unsigned short*)w; w += big;     // aliased as Opart later
    unsigned short* Kh   = (unsigned short*)w; w += big;
    unsigned short* VTh  = (unsigned short*)w; w += big;
    unsigned short* Qh   = (unsigned short*)w; w += sml;
    unsigned short* Ob   = (unsigned short*)w; w += sml;
    unsigned short* Fu   = (unsigned short*)w; w += sml;
    unsigned short* Y2   = (unsigned short*)w; w += sml;
    float2* Ml = (float2*)w; w += (long)NSPLIT * 32 * NTOK * sizeof(float2);
    unsigned short* Opart = dirs;   // dirs is dead once KV GEMM completes (37.75MB = exact fit)

    const unsigned short* vision = cv[0];
    const unsigned short* dirb = cv[1];
    const unsigned short* inW = cv[2];
    const unsigned short* inB = cv[3];
    const unsigned short* outW = cv[4];
    const unsigned short* outB = cv[5];
    const unsigned short* finW = cv[6];
    const unsigned short* finB = cv[7];
    const unsigned short* lng = cv[8];
    const unsigned short* lnbt = cv[9];

    dim3 blk(256, 1, 1);

    // 0. dtype detect
    detect_kernel<<<dim3(1), dim3(64), 0, stream>>>((const unsigned int*)d_in[1], meta);

    // 1. single fused conversion launch (+ transposed dirW)
    ConvJobs J;
    int bacc = 0;
    for (int i = 0; i < 10; ++i) {
        J.src[i] = d_in[cidx[i]];
        J.dst[i] = cv[i];
        J.n4[i] = (int)(csz[i] / 4);
        J.bstart[i] = bacc;
        bacc += (int)((csz[i] / 4 + 1023) / 1024);
    }
    conv_all<<<dim3(bacc), blk, 0, stream>>>(J, meta);
    transpose_conv<<<dim3(1024, KDIR), blk, 0, stream>>>(d_in[1], dWT, meta);

    // 2. merged dirs(z<8)+Q(z==8, pre-scaled) GEMM: A=vision, M=2304
    gemm_glds<6, 8, 128, 128><<<dim3(18 * 8, 9), blk, 0, stream>>>(
        vision, dWT, dirb, dirs, inW, inB, Qh, NB * NTOK, (long)DIM * DIM, DIM);

    // 3. fused K+V GEMM (wk||wv contiguous): K->Kh, V->VTh (phi-permuted)
    gemm_glds<5, 16, 128, 128><<<dim3(144 * 16, 1), blk, 0, stream>>>(
        dirs, inW + DIM * DIM, inB + DIM, Kh, nullptr, nullptr, VTh, NB * KN, 0L, 0L);

    // 4. 3-chunk KV-split flash attention -> Opart (aliases dirs) + Ml
    attn_kernel7<<<dim3(3 * 32 * NSPLIT), blk, 0, stream>>>(Qh, Kh, VTh, Opart, Ml);

    // 5. combine partials -> Ob [b,n,h*128+d]
    attn_reduce<<<dim3(9, 32), blk, 0, stream>>>(Opart, Ml, Ob);

    // 6. fused = Ob @ out_proj^T + b   (64x64 tile: 576 blocks)
    gemm_glds<0, 16, 64, 64><<<dim3(36 * 16, 1), blk, 0, stream>>>(
        Ob, outW, outB, Fu, nullptr, nullptr, nullptr, NB * NTOK, 0L, 0L);

    // 7. y = fused @ fin^T + b
    gemm_glds<0, 16, 64, 64><<<dim3(36 * 16, 1), blk, 0, stream>>>(
        Fu, finW, finB, Y2, nullptr, nullptr, nullptr, NB * NTOK, 0L, 0L);

    // 8. LayerNorm + residual -> d_out
    ln2_kernel<<<dim3(NB * NTOK), blk, 0, stream>>>(Y2, lng, lnbt, vision, d_out, meta);
}

// Round 9
// 342.259 us; speedup vs baseline: 2.9168x; 1.0116x over previous
//
#include <hip/hip_runtime.h>
#include <hip/hip_bf16.h>

typedef __attribute__((ext_vector_type(8))) short short8;
typedef __attribute__((ext_vector_type(4))) float f32x4;
typedef __attribute__((ext_vector_type(4))) int i32x4;

#define NTOK 576
#define DIM  1024
#define NB   4
#define NH   8
#define HD   128
#define KDIR 8
#define KN   4608
#define NSPLIT 4
#define NT 18                 // KN/NSPLIT/64

__device__ __forceinline__ float us2f(unsigned short u) {
    unsigned int x = ((unsigned int)u) << 16;
    return __uint_as_float(x);
}
__device__ __forceinline__ unsigned short f2us(float f) {
    unsigned int x = __float_as_uint(f);
    unsigned int r = x + 0x7fffu + ((x >> 16) & 1u);
    return (unsigned short)(r >> 16);
}

typedef __attribute__((address_space(3))) unsigned int lds_uint;
typedef const __attribute__((address_space(1))) unsigned int glb_uint;
__device__ __forceinline__ void async16(const unsigned short* g, unsigned short* l) {
    __builtin_amdgcn_global_load_lds((glb_uint*)g, (lds_uint*)l, 16, 0, 0);
}
__device__ __forceinline__ void wait_vm0_barrier() {
    asm volatile("s_waitcnt vmcnt(0)" ::: "memory");
    __builtin_amdgcn_s_barrier();
    __builtin_amdgcn_sched_barrier(0);
}

// meta[0] = 1 if device buffers are bf16, 0 if f32
__global__ void detect_kernel(const unsigned int* __restrict__ src, int* meta)
{
    if (threadIdx.x == 0) {
        int cnt = 0;
        for (int i = 0; i < 256; ++i) {
            unsigned u = src[(long)i * 16384] & 0xFFFFu;
            unsigned e = (u >> 7) & 0xFFu;
            cnt += (e >= 90 && e <= 150) ? 1 : 0;
        }
        meta[0] = (cnt >= 192) ? 1 : 0;
    }
}

// All 10 small conversions in one launch.
struct ConvJobs {
    const void* src[10];
    unsigned short* dst[10];
    int n4[10];
    int bstart[10];
};
__global__ __launch_bounds__(256)
void conv_all(ConvJobs J, const int* __restrict__ meta)
{
    const int b = blockIdx.x;
    int ji = 0;
    #pragma unroll
    for (int i = 1; i < 10; ++i) if (b >= J.bstart[i]) ji = i;
    const long base = (long)(b - J.bstart[ji]) * 1024 + threadIdx.x;
    const long n4 = J.n4[ji];
    if (meta[0]) {
        const ushort4* s = (const ushort4*)J.src[ji];
        ushort4* d = (ushort4*)J.dst[ji];
        #pragma unroll
        for (int t = 0; t < 4; ++t) {
            long i = base + t * 256;
            if (i < n4) d[i] = s[i];
        }
    } else {
        const float4* s = (const float4*)J.src[ji];
        ushort4* d = (ushort4*)J.dst[ji];
        #pragma unroll
        for (int t = 0; t < 4; ++t) {
            long i = base + t * 256;
            if (i < n4) {
                float4 v = s[i];
                ushort4 o;
                o.x = f2us(v.x); o.y = f2us(v.y); o.z = f2us(v.z); o.w = f2us(v.w);
                d[i] = o;
            }
        }
    }
}

// dirW [8][1024 d][1024 e] -> dWT [8][1024 e][1024 d]
__global__ __launch_bounds__(256)
void transpose_conv(const void* __restrict__ src, unsigned short* __restrict__ dst,
                    const int* __restrict__ meta)
{
    const int k = blockIdx.y;
    const int ty = blockIdx.x >> 5, tx = blockIdx.x & 31;
    const int d0 = ty * 32, e0 = tx * 32;
    __shared__ float tl[32][33];
    const int t = threadIdx.x;
    const int row = t >> 3, c4 = (t & 7) * 4;
    const long sbase = ((long)k * 1024 + d0 + row) * 1024 + e0 + c4;
    if (meta[0]) {
        const unsigned short* s = (const unsigned short*)src;
        ushort4 v = *(const ushort4*)(s + sbase);
        tl[row][c4+0] = us2f(v.x); tl[row][c4+1] = us2f(v.y);
        tl[row][c4+2] = us2f(v.z); tl[row][c4+3] = us2f(v.w);
    } else {
        const float* s = (const float*)src;
        float4 v = *(const float4*)(s + sbase);
        tl[row][c4+0] = v.x; tl[row][c4+1] = v.y;
        tl[row][c4+2] = v.z; tl[row][c4+3] = v.w;
    }
    __syncthreads();
    ushort4 o;
    o.x = f2us(tl[c4+0][row]); o.y = f2us(tl[c4+1][row]);
    o.z = f2us(tl[c4+2][row]); o.w = f2us(tl[c4+3][row]);
    *(ushort4*)(dst + ((long)k * 1024 + e0 + row) * 1024 + d0 + c4) = o;
}

// C = A[M x 1024] @ B^T + bias. Tile BM x BN, BK=64, double-buffered glds staging.
// MODE: 0 row-major C; 5 fused KV (cg<1024 -> Kh [bh][kv][128], else VTh [bh][128][4608]
//       with kv phi-permuted within each 64-block for the attn b128 PV reads);
//       6 merged dirs(z<8)+Q(z==8, pre-scaled by 1/sqrt(128)*log2e)
// SWZ: 0 none; 1 KV grid (tm=144,tn=16): XCD-chunked tm, tn-inner (B 4MB hot/XCD);
//      2 dirs grid (tm=18,tn=8): XCD-chunked lin.
template<int MODE, int TN, int BM, int BN, int SWZ>
__global__ __launch_bounds__(256)
void gemm_glds(const unsigned short* __restrict__ A, const unsigned short* __restrict__ Bw,
               const unsigned short* __restrict__ bias, unsigned short* __restrict__ C,
               const unsigned short* __restrict__ B2, const unsigned short* __restrict__ bias2,
               unsigned short* __restrict__ C2,
               int M, long bStride, long biasStride)
{
    constexpr int MI = BM / 32, NI = BN / 32;
    const int z = blockIdx.y;
    const unsigned short* Bb;
    const unsigned short* Gb;
    if constexpr (MODE == 6) {
        Bb = (z < 8) ? Bw + (long)z * bStride : B2;
        Gb = (z < 8) ? bias + (long)z * biasStride : bias2;
    } else {
        Bb = Bw + (long)z * bStride;
        Gb = bias + (long)z * biasStride;
    }
    int tm, tn;
    if constexpr (SWZ == 1) {
        const int xcd = blockIdx.x & 7, idx = blockIdx.x >> 3;   // idx 0..287
        tm = xcd * 18 + (idx >> 4);
        tn = idx & 15;
    } else if constexpr (SWZ == 2) {
        const int xcd = blockIdx.x & 7, idx = blockIdx.x >> 3;   // idx 0..17
        const int lin = xcd * 18 + idx;
        tm = lin >> 3;
        tn = lin & 7;
    } else {
        tm = blockIdx.x / TN;
        tn = blockIdx.x % TN;
    }

    __shared__ __align__(16) unsigned short As[2][BM * 64];
    __shared__ __align__(16) unsigned short Bs[2][BN * 64];

    const int tid = threadIdx.x, lane = tid & 63, wid = tid >> 6;
    const int wm = wid >> 1, wn = wid & 1;
    const int r0 = lane & 15, hi = lane >> 4;
    const int lr = lane >> 3;
    const int lg = lane & 7;

    f32x4 zz = {0.f, 0.f, 0.f, 0.f};
    f32x4 acc[MI][NI];
    #pragma unroll
    for (int i = 0; i < MI; ++i)
        #pragma unroll
        for (int j = 0; j < NI; ++j) acc[i][j] = zz;

    const int sgc = ((lg ^ (lr & 7)) << 3);

    auto stage = [&](int k0, int buf) {
        #pragma unroll
        for (int j = 0; j < BM / 32; ++j) {
            int rb = wid * (BM / 4) + j * 8;
            async16(A + (long)(tm * BM + rb + lr) * 1024 + k0 + sgc, &As[buf][rb * 64]);
        }
        #pragma unroll
        for (int j = 0; j < BN / 32; ++j) {
            int rb = wid * (BN / 4) + j * 8;
            async16(Bb + (long)(tn * BN + rb + lr) * 1024 + k0 + sgc, &Bs[buf][rb * 64]);
        }
    };

    stage(0, 0);
    for (int kt = 0; kt < 16; ++kt) {
        wait_vm0_barrier();
        if (kt < 15) stage((kt + 1) * 64, (kt + 1) & 1);
        const unsigned short* Asb = As[kt & 1];
        const unsigned short* Bsb = Bs[kt & 1];
        __builtin_amdgcn_s_setprio(1);
        #pragma unroll
        for (int kd = 0; kd < 2; ++kd) {
            const int pg = ((kd * 4 + hi) ^ (r0 & 7)) << 3;
            short8 af[MI], bfr[NI];
            #pragma unroll
            for (int mi = 0; mi < MI; ++mi)
                af[mi] = *reinterpret_cast<const short8*>(&Asb[(wm * (BM/2) + mi * 16 + r0) * 64 + pg]);
            #pragma unroll
            for (int ni = 0; ni < NI; ++ni)
                bfr[ni] = *reinterpret_cast<const short8*>(&Bsb[(wn * (BN/2) + ni * 16 + r0) * 64 + pg]);
            #pragma unroll
            for (int mi = 0; mi < MI; ++mi)
                #pragma unroll
                for (int ni = 0; ni < NI; ++ni)
                    acc[mi][ni] = __builtin_amdgcn_mfma_f32_16x16x32_bf16(af[mi], bfr[ni], acc[mi][ni], 0, 0, 0);
        }
        __builtin_amdgcn_s_setprio(0);
    }

    const float QSCL = 0.08838834764831845f * 1.4426950408889634f;
    const int jr = hi * 4;
    #pragma unroll
    for (int ni = 0; ni < NI; ++ni) {
        int cg = tn * BN + wn * (BN/2) + ni * 16 + r0;
        float bv = us2f(Gb[cg]);
        if constexpr (MODE == 5) {
            if (cg >= 1024) {
                int cg2 = cg - 1024;
                int h = cg2 >> 7, d = cg2 & 127;
                #pragma unroll
                for (int mi = 0; mi < MI; ++mi) {
                    int rgb = tm * BM + wm * (BM/2) + mi * 16 + jr;
                    int b = rgb / 4608, kv = rgb - b * 4608;
                    // phi-permute kv within its 64-block: P = [b5][b3][b2][b4][b1b0]
                    int r = kv & 63;
                    int P = ((r >> 5) & 1) * 32 + ((r >> 3) & 1) * 16 + ((r >> 2) & 1) * 8
                          + ((r >> 4) & 1) * 4 + (r & 3);
                    ushort4 o;
                    o.x = f2us(acc[mi][ni][0] + bv);
                    o.y = f2us(acc[mi][ni][1] + bv);
                    o.z = f2us(acc[mi][ni][2] + bv);
                    o.w = f2us(acc[mi][ni][3] + bv);
                    *(ushort4*)&C2[((long)(b * 8 + h) * 128 + d) * 4608 + (kv & ~63) + P] = o;
                }
                continue;
            }
        }
        #pragma unroll
        for (int mi = 0; mi < MI; ++mi) {
            #pragma unroll
            for (int j = 0; j < 4; ++j) {
                int rg = tm * BM + wm * (BM/2) + mi * 16 + jr + j;
                float val = acc[mi][ni][j] + bv;
                if constexpr (MODE == 0) {
                    C[(long)rg * 1024 + cg] = f2us(val);
                } else if constexpr (MODE == 5) {
                    int b = rg / 4608, kv = rg - b * 4608;
                    int h = cg >> 7, d = cg & 127;
                    C[((long)(b * 8 + h) * 4608 + kv) * 128 + d] = f2us(val);
                } else {  // MODE 6
                    int b = rg / 576, n = rg - b * 576;
                    if (z == 8) {
                        int h = cg >> 7, d = cg & 127;
                        C2[((long)(b * 8 + h) * 576 + n) * 128 + d] = f2us(val * QSCL);
                    } else {
                        C[((long)b * 4608 + (long)z * 576 + n) * 1024 + cg] = f2us(val);
                    }
                }
            }
        }
    }
}

// 3-chunk swapped-operand flash attention: 192 q rows per block (48/wave).
// Each K/V LDS b128 read feeds 3 MFMAs (one per q-chunk) -> 3x LDS amortization.
// V^T global is phi-permuted so the PV A-fragment is one contiguous b128 and the
// P B-fragment is lane-local (zero shuffles, zero extra conflicts).
__global__ __launch_bounds__(256, 2)
void attn_kernel7(const unsigned short* __restrict__ Qh, const unsigned short* __restrict__ Kh,
                  const unsigned short* __restrict__ VTh, unsigned short* __restrict__ Opart,
                  float2* __restrict__ Ml)
{
    const int bid = blockIdx.x;
    const int logical = (bid & 7) * 48 + (bid >> 3);   // 384 blocks, XCD-grouped
    const int bhsp = logical / 3;
    const int qt = logical - bhsp * 3;                 // 0..2, 192-q tiles
    const int bh = bhsp >> 2;
    const int sp = bhsp & 3;

    const int tid = threadIdx.x;
    const int lane = tid & 63, wid = tid >> 6;
    const int r0 = lane & 15, hi = lane >> 4;

    __shared__ __align__(16) unsigned short Ks[2][64 * 128];
    __shared__ __align__(16) unsigned short VT[2][128 * 64];

    short8 qf[3][4];
    #pragma unroll
    for (int c = 0; c < 3; ++c) {
        const long qoff = ((long)bh * NTOK + qt * 192 + c * 64 + wid * 16 + r0) * HD + hi * 8;
        #pragma unroll
        for (int kd = 0; kd < 4; ++kd)
            qf[c][kd] = *reinterpret_cast<const short8*>(Qh + qoff + kd * 32);
    }

    f32x4 zz = {0.f, 0.f, 0.f, 0.f};
    f32x4 oacc[3][8];
    #pragma unroll
    for (int c = 0; c < 3; ++c)
        #pragma unroll
        for (int i = 0; i < 8; ++i) oacc[c][i] = zz;
    float mrun[3], lrun[3];
    #pragma unroll
    for (int c = 0; c < 3; ++c) { mrun[c] = -1e30f; lrun[c] = 0.f; }

    int offK[4], offV[4];
    #pragma unroll
    for (int j = 0; j < 4; ++j) {
        offK[j] = (wid * 16 + 4 * j + hi) * 128 + (((lane & 15) ^ ((4 * j + hi) & 7)) << 3);
        offV[j] = (wid * 32 + 8 * j + (lane >> 3)) * KN + (((lane & 7) ^ (lane >> 3)) << 3);
    }
    const unsigned short* kp = Kh + (long)bh * KN * HD + (long)(sp * (KN / NSPLIT)) * HD;
    const unsigned short* vp = VTh + (long)bh * HD * KN + sp * (KN / NSPLIT);

    auto stage = [&](int buf) {
        #pragma unroll
        for (int j = 0; j < 4; ++j) {
            async16(kp + offK[j], &Ks[buf][(wid * 16 + 4 * j) * 128]);
            async16(vp + offV[j], &VT[buf][(wid * 32 + 8 * j) * 64]);
        }
    };

    stage(0);
    for (int kt = 0; kt < NT; ++kt) {
        wait_vm0_barrier();
        if (kt < NT - 1) { kp += 64 * HD; vp += 64; stage((kt + 1) & 1); }
        const unsigned short* Ksb = Ks[kt & 1];
        const unsigned short* VTb = VT[kt & 1];

        // QK: each kf read feeds 3 MFMAs
        f32x4 s[3][4];
        #pragma unroll
        for (int c = 0; c < 3; ++c)
            #pragma unroll
            for (int nb = 0; nb < 4; ++nb) s[c][nb] = zz;
        __builtin_amdgcn_s_setprio(1);
        #pragma unroll
        for (int nb = 0; nb < 4; ++nb) {
            #pragma unroll
            for (int kd = 0; kd < 4; ++kd) {
                short8 kf = *reinterpret_cast<const short8*>(
                    &Ksb[(nb * 16 + r0) * 128 + (((kd * 4 + hi) ^ (r0 & 7)) << 3)]);
                s[0][nb] = __builtin_amdgcn_mfma_f32_16x16x32_bf16(kf, qf[0][kd], s[0][nb], 0, 0, 0);
                s[1][nb] = __builtin_amdgcn_mfma_f32_16x16x32_bf16(kf, qf[1][kd], s[1][nb], 0, 0, 0);
                s[2][nb] = __builtin_amdgcn_mfma_f32_16x16x32_bf16(kf, qf[2][kd], s[2][nb], 0, 0, 0);
            }
        }
        __builtin_amdgcn_s_setprio(0);

        // softmax per chunk (per-lane, exp2 domain, defer-max)
        unsigned pk0[3][4], pk1[3][4];
        #pragma unroll
        for (int c = 0; c < 3; ++c) {
            float mt = fmaxf(fmaxf(fmaxf(s[c][0][0], s[c][0][1]), fmaxf(s[c][0][2], s[c][0][3])),
                       fmaxf(fmaxf(fmaxf(s[c][1][0], s[c][1][1]), fmaxf(s[c][1][2], s[c][1][3])),
                       fmaxf(fmaxf(fmaxf(s[c][2][0], s[c][2][1]), fmaxf(s[c][2][2], s[c][2][3])),
                             fmaxf(fmaxf(s[c][3][0], s[c][3][1]), fmaxf(s[c][3][2], s[c][3][3])))));
            if (!__all(mt - mrun[c] <= 8.0f)) {
                float mr = fmaxf(mt, __shfl_xor(mt, 16));
                mr = fmaxf(mr, __shfl_xor(mr, 32));
                float mn = fmaxf(mrun[c], mr);
                float scl = exp2f(mrun[c] - mn);
                mrun[c] = mn;
                lrun[c] *= scl;
                #pragma unroll
                for (int db = 0; db < 8; ++db)
                    #pragma unroll
                    for (int j = 0; j < 4; ++j)
                        oacc[c][db][j] *= scl;
            }
            float rt = 0.f;
            #pragma unroll
            for (int nb = 0; nb < 4; ++nb)
                #pragma unroll
                for (int j = 0; j < 4; ++j) {
                    s[c][nb][j] = exp2f(s[c][nb][j] - mrun[c]);
                    rt += s[c][nb][j];
                }
            lrun[c] += rt;   // per-hi partial; reduced at the end
            #pragma unroll
            for (int nb = 0; nb < 4; ++nb) {
                asm("v_cvt_pk_bf16_f32 %0, %1, %2" : "=v"(pk0[c][nb]) : "v"(s[c][nb][0]), "v"(s[c][nb][1]));
                asm("v_cvt_pk_bf16_f32 %0, %1, %2" : "=v"(pk1[c][nb]) : "v"(s[c][nb][2]), "v"(s[c][nb][3]));
            }
        }

        // PV: each vf read feeds 3 MFMAs; P-fragment lane-local
        __builtin_amdgcn_s_setprio(1);
        #pragma unroll
        for (int kd = 0; kd < 2; ++kd) {
            short8 pf[3];
            #pragma unroll
            for (int c = 0; c < 3; ++c) {
                i32x4 fr;
                fr[0] = (int)pk0[c][2 * kd];
                fr[1] = (int)pk1[c][2 * kd];
                fr[2] = (int)pk0[c][2 * kd + 1];
                fr[3] = (int)pk1[c][2 * kd + 1];
                pf[c] = *reinterpret_cast<short8*>(&fr);
            }
            #pragma unroll
            for (int db = 0; db < 8; ++db) {
                short8 vf = *reinterpret_cast<const short8*>(
                    &VTb[(db * 16 + r0) * 64 + (((kd * 4 + hi) ^ (r0 & 7)) << 3)]);
                oacc[0][db] = __builtin_amdgcn_mfma_f32_16x16x32_bf16(vf, pf[0], oacc[0][db], 0, 0, 0);
                oacc[1][db] = __builtin_amdgcn_mfma_f32_16x16x32_bf16(vf, pf[1], oacc[1][db], 0, 0, 0);
                oacc[2][db] = __builtin_amdgcn_mfma_f32_16x16x32_bf16(vf, pf[2], oacc[2][db], 0, 0, 0);
            }
        }
        __builtin_amdgcn_s_setprio(0);
    }

    #pragma unroll
    for (int c = 0; c < 3; ++c) {
        float lr = lrun[c];
        lr += __shfl_xor(lr, 16);
        lr += __shfl_xor(lr, 32);
        const float inv = 1.f / lr;
        const long po = ((long)(sp * 32 + bh) * NTOK + qt * 192 + c * 64 + wid * 16 + r0) * HD;
        #pragma unroll
        for (int db = 0; db < 8; ++db) {
            ushort4 o;
            o.x = f2us(oacc[c][db][0] * inv);
            o.y = f2us(oacc[c][db][1] * inv);
            o.z = f2us(oacc[c][db][2] * inv);
            o.w = f2us(oacc[c][db][3] * inv);
            *(ushort4*)&Opart[po + db * 16 + hi * 4] = o;
        }
        if (lane < 16) {
            const long mo = (long)(sp * 32 + bh) * NTOK + qt * 192 + c * 64 + wid * 16 + r0;
            Ml[mo] = make_float2(mrun[c], lr);   // log2 domain
        }
    }
}

// Combine NSPLIT partials -> Ob[(b*576+n)*1024 + h*128 + d]
__global__ __launch_bounds__(256)
void attn_reduce(const unsigned short* __restrict__ Opart, const float2* __restrict__ Ml,
                 unsigned short* __restrict__ Ob)
{
    const int qt = blockIdx.x, bh = blockIdx.y;
    const int t = threadIdx.x;
    const int rl = t >> 2, dc = (t & 3) * 32;
    const int q = qt * 64 + rl;

    float m[NSPLIT], l[NSPLIT];
    float M = -1e30f;
    #pragma unroll
    for (int sp = 0; sp < NSPLIT; ++sp) {
        float2 v = Ml[(long)(sp * 32 + bh) * NTOK + q];
        m[sp] = v.x; l[sp] = v.y;
        M = fmaxf(M, v.x);
    }
    float w[NSPLIT], denom = 0.f;
    #pragma unroll
    for (int sp = 0; sp < NSPLIT; ++sp) {
        w[sp] = l[sp] * exp2f(m[sp] - M);
        denom += w[sp];
    }
    const float inv = 1.f / denom;
    const int b = bh >> 3, h = bh & 7;
    #pragma unroll
    for (int dj = 0; dj < 4; ++dj) {
        float a[8];
        #pragma unroll
        for (int e = 0; e < 8; ++e) a[e] = 0.f;
        #pragma unroll
        for (int sp = 0; sp < NSPLIT; ++sp) {
            short8 v = *reinterpret_cast<const short8*>(
                &Opart[((long)(sp * 32 + bh) * NTOK + q) * HD + dc + dj * 8]);
            #pragma unroll
            for (int e = 0; e < 8; ++e)
                a[e] += w[sp] * us2f((unsigned short)v[e]);
        }
        short8 o;
        #pragma unroll
        for (int e = 0; e < 8; ++e) o[e] = (short)f2us(a[e] * inv);
        *reinterpret_cast<short8*>(&Ob[((long)b * NTOK + q) * 1024 + h * 128 + dc + dj * 8]) = o;
    }
}

// LayerNorm(y)*g + b + vision; output dtype per meta[0]
__global__ __launch_bounds__(256)
void ln2_kernel(const unsigned short* __restrict__ Y, const unsigned short* __restrict__ g,
                const unsigned short* __restrict__ be, const unsigned short* __restrict__ vis,
                void* __restrict__ dout, const int* __restrict__ meta)
{
    const int row = blockIdx.x;
    const int tid = threadIdx.x;
    const int lane = tid & 63, wid = tid >> 6;
    const unsigned short* yr = Y + (long)row * DIM;
    ushort4 raw = reinterpret_cast<const ushort4*>(yr)[tid];
    float v[4];
    v[0] = us2f(raw.x); v[1] = us2f(raw.y); v[2] = us2f(raw.z); v[3] = us2f(raw.w);
    float s1 = 0.f, s2 = 0.f;
    #pragma unroll
    for (int i = 0; i < 4; ++i) { s1 += v[i]; s2 += v[i] * v[i]; }
    #pragma unroll
    for (int off = 1; off < 64; off <<= 1) {
        s1 += __shfl_xor(s1, off);
        s2 += __shfl_xor(s2, off);
    }
    __shared__ float red[2][4];
    if (lane == 0) { red[0][wid] = s1; red[1][wid] = s2; }
    __syncthreads();
    s1 = red[0][0] + red[0][1] + red[0][2] + red[0][3];
    s2 = red[1][0] + red[1][1] + red[1][2] + red[1][3];
    const float mu = s1 * (1.f / DIM);
    const float var = s2 * (1.f / DIM) - mu * mu;
    const float inv = rsqrtf(var + 1e-5f);
    ushort4 gg = reinterpret_cast<const ushort4*>(g)[tid];
    ushort4 bb = reinterpret_cast<const ushort4*>(be)[tid];
    ushort4 vv = reinterpret_cast<const ushort4*>(vis + (long)row * DIM)[tid];
    float o0 = (v[0] - mu) * inv * us2f(gg.x) + us2f(bb.x) + us2f(vv.x);
    float o1 = (v[1] - mu) * inv * us2f(gg.y) + us2f(bb.y) + us2f(vv.y);
    float o2 = (v[2] - mu) * inv * us2f(gg.z) + us2f(bb.z) + us2f(vv.z);
    float o3 = (v[3] - mu) * inv * us2f(gg.w) + us2f(bb.w) + us2f(vv.w);
    if (meta[0]) {
        ushort4 o;
        o.x = f2us(o0); o.y = f2us(o1); o.z = f2us(o2); o.w = f2us(o3);
        reinterpret_cast<ushort4*>((unsigned short*)dout + (long)row * DIM)[tid] = o;
    } else {
        float4 o = make_float4(o0, o1, o2, o3);
        reinterpret_cast<float4*>((float*)dout + (long)row * DIM)[tid] = o;
    }
}

extern "C" void kernel_launch(void* const* d_in, const int* in_sizes, int n_in,
                              void* d_out, int out_size, void* d_ws, size_t ws_size,
                              hipStream_t stream)
{
    // scan_idx (d_in[11]) unused: all 8 scans are bijections on the 576 cells and
    // softmax over the full K*N key axis (K,V share row order) is permutation-
    // invariant per direction block -> gather elided.
    unsigned long long w = (unsigned long long)d_ws;
    int* meta = (int*)w; w += 256;

    const int cidx[10] = {0, 2, 3, 4, 5, 6, 7, 8, 9, 10};
    const long csz[10] = {
        (long)NB * NTOK * DIM,  // vision
        (long)KDIR * DIM,       // dirb
        3L * DIM * DIM,         // inW
        3L * DIM,               // inB
        (long)DIM * DIM,        // outW
        DIM,                    // outB
        (long)DIM * DIM,        // finW
        DIM, DIM, DIM           // finB, lng, lnb
    };
    unsigned short* cv[10];
    for (int i = 0; i < 10; ++i) {
        cv[i] = (unsigned short*)w;
        w += (csz[i] * 2 + 255) & ~255ULL;
    }
    unsigned short* dWT = (unsigned short*)w; w += (long)KDIR * DIM * DIM * 2;

    const size_t big = (size_t)NB * KDIR * NTOK * DIM * 2;   // 37.75 MB
    const size_t sml = (size_t)NB * NTOK * DIM * 2;          // 4.72 MB
    unsigned short* dirs = (unsigned short*)w; w += big;     // aliased as Opart later
    unsigned short* Kh   = (unsigned short*)w; w += big;
    unsigned short* VTh  = (unsigned short*)w; w += big;
    unsigned short* Qh   = (unsigned short*)w; w += sml;
    unsigned short* Ob   = (unsigned short*)w; w += sml;
    unsigned short* Fu   = (unsigned short*)w; w += sml;
    unsigned short* Y2   = (unsigned short*)w; w += sml;
    float2* Ml = (float2*)w; w += (long)NSPLIT * 32 * NTOK * sizeof(float2);
    unsigned short* Opart = dirs;   // dirs is dead once KV GEMM completes (18.9MB < 37.75MB)

    const unsigned short* vision = cv[0];
    const unsigned short* dirb = cv[1];
    const unsigned short* inW = cv[2];
    const unsigned short* inB = cv[3];
    const unsigned short* outW = cv[4];
    const unsigned short* outB = cv[5];
    const unsigned short* finW = cv[6];
    const unsigned short* finB = cv[7];
    const unsigned short* lng = cv[8];
    const unsigned short* lnbt = cv[9];

    dim3 blk(256, 1, 1);

    // 0. dtype detect
    detect_kernel<<<dim3(1), dim3(64), 0, stream>>>((const unsigned int*)d_in[1], meta);

    // 1. single fused conversion launch (+ transposed dirW)
    ConvJobs J;
    int bacc = 0;
    for (int i = 0; i < 10; ++i) {
        J.src[i] = d_in[cidx[i]];
        J.dst[i] = cv[i];
        J.n4[i] = (int)(csz[i] / 4);
        J.bstart[i] = bacc;
        bacc += (int)((csz[i] / 4 + 1023) / 1024);
    }
    conv_all<<<dim3(bacc), blk, 0, stream>>>(J, meta);
    transpose_conv<<<dim3(1024, KDIR), blk, 0, stream>>>(d_in[1], dWT, meta);

    // 2. merged dirs(z<8)+Q(z==8, pre-scaled) GEMM: A=vision, M=2304, XCD-swizzled
    gemm_glds<6, 8, 128, 128, 2><<<dim3(18 * 8, 9), blk, 0, stream>>>(
        vision, dWT, dirb, dirs, inW, inB, Qh, NB * NTOK, (long)DIM * DIM, DIM);

    // 3. fused K+V GEMM (wk||wv contiguous): K->Kh, V->VTh (phi-permuted), XCD-swizzled
    gemm_glds<5, 16, 128, 128, 1><<<dim3(144 * 16, 1), blk, 0, stream>>>(
        dirs, inW + DIM * DIM, inB + DIM, Kh, nullptr, nullptr, VTh, NB * KN, 0L, 0L);

    // 4. 3-chunk KV-split flash attention -> Opart (aliases dirs) + Ml
    attn_kernel7<<<dim3(3 * 32 * NSPLIT), blk, 0, stream>>>(Qh, Kh, VTh, Opart, Ml);

    // 5. combine partials -> Ob [b,n,h*128+d]
    attn_reduce<<<dim3(9, 32), blk, 0, stream>>>(Opart, Ml, Ob);

    // 6. fused = Ob @ out_proj^T + b   (64x64 tile: 576 blocks)
    gemm_glds<0, 16, 64, 64, 0><<<dim3(36 * 16, 1), blk, 0, stream>>>(
        Ob, outW, outB, Fu, nullptr, nullptr, nullptr, NB * NTOK, 0L, 0L);

    // 7. y = fused @ fin^T + b
    gemm_glds<0, 16, 64, 64, 0><<<dim3(36 * 16, 1), blk, 0, stream>>>(
        Fu, finW, finB, Y2, nullptr, nullptr, nullptr, NB * NTOK, 0L, 0L);

    // 8. LayerNorm + residual -> d_out
    ln2_kernel<<<dim3(NB * NTOK), blk, 0, stream>>>(Y2, lng, lnbt, vision, d_out, meta);
}

// Round 10
// 333.029 us; speedup vs baseline: 2.9977x; 1.0277x over previous
//
#include <hip/hip_runtime.h>
#include <hip/hip_bf16.h>

typedef __attribute__((ext_vector_type(8))) short short8;
typedef __attribute__((ext_vector_type(4))) float f32x4;
typedef __attribute__((ext_vector_type(4))) int i32x4;

#define NTOK 576
#define DIM  1024
#define NB   4
#define NH   8
#define HD   128
#define KDIR 8
#define KN   4608
#define NSPLIT 4
#define NT 18                 // KN/NSPLIT/64

__device__ __forceinline__ float us2f(unsigned short u) {
    unsigned int x = ((unsigned int)u) << 16;
    return __uint_as_float(x);
}
__device__ __forceinline__ unsigned short f2us(float f) {
    unsigned int x = __float_as_uint(f);
    unsigned int r = x + 0x7fffu + ((x >> 16) & 1u);
    return (unsigned short)(r >> 16);
}

typedef __attribute__((address_space(3))) unsigned int lds_uint;
typedef const __attribute__((address_space(1))) unsigned int glb_uint;
__device__ __forceinline__ void async16(const unsigned short* g, unsigned short* l) {
    __builtin_amdgcn_global_load_lds((glb_uint*)g, (lds_uint*)l, 16, 0, 0);
}
__device__ __forceinline__ void wait_vm0_barrier() {
    asm volatile("s_waitcnt vmcnt(0)" ::: "memory");
    __builtin_amdgcn_s_barrier();
    __builtin_amdgcn_sched_barrier(0);
}

// meta[0] = 1 if device buffers are bf16, 0 if f32
__global__ void detect_kernel(const unsigned int* __restrict__ src, int* meta)
{
    if (threadIdx.x == 0) {
        int cnt = 0;
        for (int i = 0; i < 256; ++i) {
            unsigned u = src[(long)i * 16384] & 0xFFFFu;
            unsigned e = (u >> 7) & 0xFFu;
            cnt += (e >= 90 && e <= 150) ? 1 : 0;
        }
        meta[0] = (cnt >= 192) ? 1 : 0;
    }
}

// All 10 small conversions in one launch.
struct ConvJobs {
    const void* src[10];
    unsigned short* dst[10];
    int n4[10];
    int bstart[10];
};
__global__ __launch_bounds__(256)
void conv_all(ConvJobs J, const int* __restrict__ meta)
{
    const int b = blockIdx.x;
    int ji = 0;
    #pragma unroll
    for (int i = 1; i < 10; ++i) if (b >= J.bstart[i]) ji = i;
    const long base = (long)(b - J.bstart[ji]) * 1024 + threadIdx.x;
    const long n4 = J.n4[ji];
    if (meta[0]) {
        const ushort4* s = (const ushort4*)J.src[ji];
        ushort4* d = (ushort4*)J.dst[ji];
        #pragma unroll
        for (int t = 0; t < 4; ++t) {
            long i = base + t * 256;
            if (i < n4) d[i] = s[i];
        }
    } else {
        const float4* s = (const float4*)J.src[ji];
        ushort4* d = (ushort4*)J.dst[ji];
        #pragma unroll
        for (int t = 0; t < 4; ++t) {
            long i = base + t * 256;
            if (i < n4) {
                float4 v = s[i];
                ushort4 o;
                o.x = f2us(v.x); o.y = f2us(v.y); o.z = f2us(v.z); o.w = f2us(v.w);
                d[i] = o;
            }
        }
    }
}

// dirW [8][1024 d][1024 e] -> dWT [8][1024 e][1024 d]
__global__ __launch_bounds__(256)
void transpose_conv(const void* __restrict__ src, unsigned short* __restrict__ dst,
                    const int* __restrict__ meta)
{
    const int k = blockIdx.y;
    const int ty = blockIdx.x >> 5, tx = blockIdx.x & 31;
    const int d0 = ty * 32, e0 = tx * 32;
    __shared__ float tl[32][33];
    const int t = threadIdx.x;
    const int row = t >> 3, c4 = (t & 7) * 4;
    const long sbase = ((long)k * 1024 + d0 + row) * 1024 + e0 + c4;
    if (meta[0]) {
        const unsigned short* s = (const unsigned short*)src;
        ushort4 v = *(const ushort4*)(s + sbase);
        tl[row][c4+0] = us2f(v.x); tl[row][c4+1] = us2f(v.y);
        tl[row][c4+2] = us2f(v.z); tl[row][c4+3] = us2f(v.w);
    } else {
        const float* s = (const float*)src;
        float4 v = *(const float4*)(s + sbase);
        tl[row][c4+0] = v.x; tl[row][c4+1] = v.y;
        tl[row][c4+2] = v.z; tl[row][c4+3] = v.w;
    }
    __syncthreads();
    ushort4 o;
    o.x = f2us(tl[c4+0][row]); o.y = f2us(tl[c4+1][row]);
    o.z = f2us(tl[c4+2][row]); o.w = f2us(tl[c4+3][row]);
    *(ushort4*)(dst + ((long)k * 1024 + e0 + row) * 1024 + d0 + c4) = o;
}

// C = A[M x 1024] @ B^T + bias. Tile BM x BN, BK=64, SINGLE-buffer glds staging
// (m97 structure: 32KB LDS -> 5 blocks/CU; implicit wave-level overlap hides drain).
// MODE: 0 row-major C; 5 fused KV (cg<1024 -> Kh [bh][kv][128], else VTh [bh][128][4608]
//       with kv phi-permuted within each 64-block for the attn b128 PV reads);
//       6 merged dirs(z<8)+Q(z==8, pre-scaled by 1/sqrt(128)*log2e)
template<int MODE, int TN, int BM, int BN>
__global__ __launch_bounds__(256)
void gemm_glds(const unsigned short* __restrict__ A, const unsigned short* __restrict__ Bw,
               const unsigned short* __restrict__ bias, unsigned short* __restrict__ C,
               const unsigned short* __restrict__ B2, const unsigned short* __restrict__ bias2,
               unsigned short* __restrict__ C2,
               int M, long bStride, long biasStride)
{
    constexpr int MI = BM / 32, NI = BN / 32;
    const int z = blockIdx.y;
    const unsigned short* Bb;
    const unsigned short* Gb;
    if constexpr (MODE == 6) {
        Bb = (z < 8) ? Bw + (long)z * bStride : B2;
        Gb = (z < 8) ? bias + (long)z * biasStride : bias2;
    } else {
        Bb = Bw + (long)z * bStride;
        Gb = bias + (long)z * biasStride;
    }
    const int tm = blockIdx.x / TN;
    const int tn = blockIdx.x % TN;

    __shared__ __align__(16) unsigned short As[BM * 64];
    __shared__ __align__(16) unsigned short Bs[BN * 64];

    const int tid = threadIdx.x, lane = tid & 63, wid = tid >> 6;
    const int wm = wid >> 1, wn = wid & 1;
    const int r0 = lane & 15, hi = lane >> 4;
    const int lr = lane >> 3;
    const int lg = lane & 7;

    f32x4 zz = {0.f, 0.f, 0.f, 0.f};
    f32x4 acc[MI][NI];
    #pragma unroll
    for (int i = 0; i < MI; ++i)
        #pragma unroll
        for (int j = 0; j < NI; ++j) acc[i][j] = zz;

    const int sgc = ((lg ^ (lr & 7)) << 3);

    for (int k0 = 0; k0 < 1024; k0 += 64) {
        #pragma unroll
        for (int j = 0; j < BM / 32; ++j) {
            int rb = wid * (BM / 4) + j * 8;
            async16(A + (long)(tm * BM + rb + lr) * 1024 + k0 + sgc, &As[rb * 64]);
        }
        #pragma unroll
        for (int j = 0; j < BN / 32; ++j) {
            int rb = wid * (BN / 4) + j * 8;
            async16(Bb + (long)(tn * BN + rb + lr) * 1024 + k0 + sgc, &Bs[rb * 64]);
        }
        __syncthreads();
        __builtin_amdgcn_s_setprio(1);
        #pragma unroll
        for (int kd = 0; kd < 2; ++kd) {
            const int pg = ((kd * 4 + hi) ^ (r0 & 7)) << 3;
            short8 af[MI], bfr[NI];
            #pragma unroll
            for (int mi = 0; mi < MI; ++mi)
                af[mi] = *reinterpret_cast<const short8*>(&As[(wm * (BM/2) + mi * 16 + r0) * 64 + pg]);
            #pragma unroll
            for (int ni = 0; ni < NI; ++ni)
                bfr[ni] = *reinterpret_cast<const short8*>(&Bs[(wn * (BN/2) + ni * 16 + r0) * 64 + pg]);
            #pragma unroll
            for (int mi = 0; mi < MI; ++mi)
                #pragma unroll
                for (int ni = 0; ni < NI; ++ni)
                    acc[mi][ni] = __builtin_amdgcn_mfma_f32_16x16x32_bf16(af[mi], bfr[ni], acc[mi][ni], 0, 0, 0);
        }
        __builtin_amdgcn_s_setprio(0);
        __syncthreads();
    }

    const float QSCL = 0.08838834764831845f * 1.4426950408889634f;
    const int jr = hi * 4;
    #pragma unroll
    for (int ni = 0; ni < NI; ++ni) {
        int cg = tn * BN + wn * (BN/2) + ni * 16 + r0;
        float bv = us2f(Gb[cg]);
        if constexpr (MODE == 5) {
            if (cg >= 1024) {
                int cg2 = cg - 1024;
                int h = cg2 >> 7, d = cg2 & 127;
                #pragma unroll
                for (int mi = 0; mi < MI; ++mi) {
                    int rgb = tm * BM + wm * (BM/2) + mi * 16 + jr;
                    int b = rgb / 4608, kv = rgb - b * 4608;
                    // phi-permute kv within its 64-block: P = [b5][b3][b2][b4][b1b0]
                    int r = kv & 63;
                    int P = ((r >> 5) & 1) * 32 + ((r >> 3) & 1) * 16 + ((r >> 2) & 1) * 8
                          + ((r >> 4) & 1) * 4 + (r & 3);
                    ushort4 o;
                    o.x = f2us(acc[mi][ni][0] + bv);
                    o.y = f2us(acc[mi][ni][1] + bv);
                    o.z = f2us(acc[mi][ni][2] + bv);
                    o.w = f2us(acc[mi][ni][3] + bv);
                    *(ushort4*)&C2[((long)(b * 8 + h) * 128 + d) * 4608 + (kv & ~63) + P] = o;
                }
                continue;
            }
        }
        #pragma unroll
        for (int mi = 0; mi < MI; ++mi) {
            #pragma unroll
            for (int j = 0; j < 4; ++j) {
                int rg = tm * BM + wm * (BM/2) + mi * 16 + jr + j;
                float val = acc[mi][ni][j] + bv;
                if constexpr (MODE == 0) {
                    C[(long)rg * 1024 + cg] = f2us(val);
                } else if constexpr (MODE == 5) {
                    int b = rg / 4608, kv = rg - b * 4608;
                    int h = cg >> 7, d = cg & 127;
                    C[((long)(b * 8 + h) * 4608 + kv) * 128 + d] = f2us(val);
                } else {  // MODE 6
                    int b = rg / 576, n = rg - b * 576;
                    if (z == 8) {
                        int h = cg >> 7, d = cg & 127;
                        C2[((long)(b * 8 + h) * 576 + n) * 128 + d] = f2us(val * QSCL);
                    } else {
                        C[((long)b * 4608 + (long)z * 576 + n) * 1024 + cg] = f2us(val);
                    }
                }
            }
        }
    }
}

// 3-chunk swapped-operand flash attention: 192 q rows per block (48/wave).
// Each K/V LDS b128 read feeds 3 MFMAs (one per q-chunk) -> 3x LDS amortization.
// V^T global is phi-permuted so the PV A-fragment is one contiguous b128 and the
// P B-fragment is lane-local (zero shuffles, zero extra conflicts).
__global__ __launch_bounds__(256, 2)
void attn_kernel7(const unsigned short* __restrict__ Qh, const unsigned short* __restrict__ Kh,
                  const unsigned short* __restrict__ VTh, unsigned short* __restrict__ Opart,
                  float2* __restrict__ Ml)
{
    const int bid = blockIdx.x;
    const int logical = (bid & 7) * 48 + (bid >> 3);   // 384 blocks, XCD-grouped
    const int bhsp = logical / 3;
    const int qt = logical - bhsp * 3;                 // 0..2, 192-q tiles
    const int bh = bhsp >> 2;
    const int sp = bhsp & 3;

    const int tid = threadIdx.x;
    const int lane = tid & 63, wid = tid >> 6;
    const int r0 = lane & 15, hi = lane >> 4;

    __shared__ __align__(16) unsigned short Ks[2][64 * 128];
    __shared__ __align__(16) unsigned short VT[2][128 * 64];

    short8 qf[3][4];
    #pragma unroll
    for (int c = 0; c < 3; ++c) {
        const long qoff = ((long)bh * NTOK + qt * 192 + c * 64 + wid * 16 + r0) * HD + hi * 8;
        #pragma unroll
        for (int kd = 0; kd < 4; ++kd)
            qf[c][kd] = *reinterpret_cast<const short8*>(Qh + qoff + kd * 32);
    }

    f32x4 zz = {0.f, 0.f, 0.f, 0.f};
    f32x4 oacc[3][8];
    #pragma unroll
    for (int c = 0; c < 3; ++c)
        #pragma unroll
        for (int i = 0; i < 8; ++i) oacc[c][i] = zz;
    float mrun[3], lrun[3];
    #pragma unroll
    for (int c = 0; c < 3; ++c) { mrun[c] = -1e30f; lrun[c] = 0.f; }

    int offK[4], offV[4];
    #pragma unroll
    for (int j = 0; j < 4; ++j) {
        offK[j] = (wid * 16 + 4 * j + hi) * 128 + (((lane & 15) ^ ((4 * j + hi) & 7)) << 3);
        offV[j] = (wid * 32 + 8 * j + (lane >> 3)) * KN + (((lane & 7) ^ (lane >> 3)) << 3);
    }
    const unsigned short* kp = Kh + (long)bh * KN * HD + (long)(sp * (KN / NSPLIT)) * HD;
    const unsigned short* vp = VTh + (long)bh * HD * KN + sp * (KN / NSPLIT);

    auto stage = [&](int buf) {
        #pragma unroll
        for (int j = 0; j < 4; ++j) {
            async16(kp + offK[j], &Ks[buf][(wid * 16 + 4 * j) * 128]);
            async16(vp + offV[j], &VT[buf][(wid * 32 + 8 * j) * 64]);
        }
    };

    stage(0);
    for (int kt = 0; kt < NT; ++kt) {
        wait_vm0_barrier();
        if (kt < NT - 1) { kp += 64 * HD; vp += 64; stage((kt + 1) & 1); }
        const unsigned short* Ksb = Ks[kt & 1];
        const unsigned short* VTb = VT[kt & 1];

        // QK: each kf read feeds 3 MFMAs
        f32x4 s[3][4];
        #pragma unroll
        for (int c = 0; c < 3; ++c)
            #pragma unroll
            for (int nb = 0; nb < 4; ++nb) s[c][nb] = zz;
        __builtin_amdgcn_s_setprio(1);
        #pragma unroll
        for (int nb = 0; nb < 4; ++nb) {
            #pragma unroll
            for (int kd = 0; kd < 4; ++kd) {
                short8 kf = *reinterpret_cast<const short8*>(
                    &Ksb[(nb * 16 + r0) * 128 + (((kd * 4 + hi) ^ (r0 & 7)) << 3)]);
                s[0][nb] = __builtin_amdgcn_mfma_f32_16x16x32_bf16(kf, qf[0][kd], s[0][nb], 0, 0, 0);
                s[1][nb] = __builtin_amdgcn_mfma_f32_16x16x32_bf16(kf, qf[1][kd], s[1][nb], 0, 0, 0);
                s[2][nb] = __builtin_amdgcn_mfma_f32_16x16x32_bf16(kf, qf[2][kd], s[2][nb], 0, 0, 0);
            }
        }
        __builtin_amdgcn_s_setprio(0);

        // softmax per chunk (per-lane, exp2 domain, defer-max)
        unsigned pk0[3][4], pk1[3][4];
        #pragma unroll
        for (int c = 0; c < 3; ++c) {
            float mt = fmaxf(fmaxf(fmaxf(s[c][0][0], s[c][0][1]), fmaxf(s[c][0][2], s[c][0][3])),
                       fmaxf(fmaxf(fmaxf(s[c][1][0], s[c][1][1]), fmaxf(s[c][1][2], s[c][1][3])),
                       fmaxf(fmaxf(fmaxf(s[c][2][0], s[c][2][1]), fmaxf(s[c][2][2], s[c][2][3])),
                             fmaxf(fmaxf(s[c][3][0], s[c][3][1]), fmaxf(s[c][3][2], s[c][3][3])))));
            if (!__all(mt - mrun[c] <= 8.0f)) {
                float mr = fmaxf(mt, __shfl_xor(mt, 16));
                mr = fmaxf(mr, __shfl_xor(mr, 32));
                float mn = fmaxf(mrun[c], mr);
                float scl = exp2f(mrun[c] - mn);
                mrun[c] = mn;
                lrun[c] *= scl;
                #pragma unroll
                for (int db = 0; db < 8; ++db)
                    #pragma unroll
                    for (int j = 0; j < 4; ++j)
                        oacc[c][db][j] *= scl;
            }
            float rt = 0.f;
            #pragma unroll
            for (int nb = 0; nb < 4; ++nb)
                #pragma unroll
                for (int j = 0; j < 4; ++j) {
                    s[c][nb][j] = exp2f(s[c][nb][j] - mrun[c]);
                    rt += s[c][nb][j];
                }
            lrun[c] += rt;   // per-hi partial; reduced at the end
            #pragma unroll
            for (int nb = 0; nb < 4; ++nb) {
                asm("v_cvt_pk_bf16_f32 %0, %1, %2" : "=v"(pk0[c][nb]) : "v"(s[c][nb][0]), "v"(s[c][nb][1]));
                asm("v_cvt_pk_bf16_f32 %0, %1, %2" : "=v"(pk1[c][nb]) : "v"(s[c][nb][2]), "v"(s[c][nb][3]));
            }
        }

        // PV: each vf read feeds 3 MFMAs; P-fragment lane-local
        __builtin_amdgcn_s_setprio(1);
        #pragma unroll
        for (int kd = 0; kd < 2; ++kd) {
            short8 pf[3];
            #pragma unroll
            for (int c = 0; c < 3; ++c) {
                i32x4 fr;
                fr[0] = (int)pk0[c][2 * kd];
                fr[1] = (int)pk1[c][2 * kd];
                fr[2] = (int)pk0[c][2 * kd + 1];
                fr[3] = (int)pk1[c][2 * kd + 1];
                pf[c] = *reinterpret_cast<short8*>(&fr);
            }
            #pragma unroll
            for (int db = 0; db < 8; ++db) {
                short8 vf = *reinterpret_cast<const short8*>(
                    &VTb[(db * 16 + r0) * 64 + (((kd * 4 + hi) ^ (r0 & 7)) << 3)]);
                oacc[0][db] = __builtin_amdgcn_mfma_f32_16x16x32_bf16(vf, pf[0], oacc[0][db], 0, 0, 0);
                oacc[1][db] = __builtin_amdgcn_mfma_f32_16x16x32_bf16(vf, pf[1], oacc[1][db], 0, 0, 0);
                oacc[2][db] = __builtin_amdgcn_mfma_f32_16x16x32_bf16(vf, pf[2], oacc[2][db], 0, 0, 0);
            }
        }
        __builtin_amdgcn_s_setprio(0);
    }

    #pragma unroll
    for (int c = 0; c < 3; ++c) {
        float lr = lrun[c];
        lr += __shfl_xor(lr, 16);
        lr += __shfl_xor(lr, 32);
        const float inv = 1.f / lr;
        const long po = ((long)(sp * 32 + bh) * NTOK + qt * 192 + c * 64 + wid * 16 + r0) * HD;
        #pragma unroll
        for (int db = 0; db < 8; ++db) {
            ushort4 o;
            o.x = f2us(oacc[c][db][0] * inv);
            o.y = f2us(oacc[c][db][1] * inv);
            o.z = f2us(oacc[c][db][2] * inv);
            o.w = f2us(oacc[c][db][3] * inv);
            *(ushort4*)&Opart[po + db * 16 + hi * 4] = o;
        }
        if (lane < 16) {
            const long mo = (long)(sp * 32 + bh) * NTOK + qt * 192 + c * 64 + wid * 16 + r0;
            Ml[mo] = make_float2(mrun[c], lr);   // log2 domain
        }
    }
}

// Combine NSPLIT partials -> Ob[(b*576+n)*1024 + h*128 + d]
__global__ __launch_bounds__(256)
void attn_reduce(const unsigned short* __restrict__ Opart, const float2* __restrict__ Ml,
                 unsigned short* __restrict__ Ob)
{
    const int qt = blockIdx.x, bh = blockIdx.y;
    const int t = threadIdx.x;
    const int rl = t >> 2, dc = (t & 3) * 32;
    const int q = qt * 64 + rl;

    float m[NSPLIT], l[NSPLIT];
    float M = -1e30f;
    #pragma unroll
    for (int sp = 0; sp < NSPLIT; ++sp) {
        float2 v = Ml[(long)(sp * 32 + bh) * NTOK + q];
        m[sp] = v.x; l[sp] = v.y;
        M = fmaxf(M, v.x);
    }
    float w[NSPLIT], denom = 0.f;
    #pragma unroll
    for (int sp = 0; sp < NSPLIT; ++sp) {
        w[sp] = l[sp] * exp2f(m[sp] - M);
        denom += w[sp];
    }
    const float inv = 1.f / denom;
    const int b = bh >> 3, h = bh & 7;
    #pragma unroll
    for (int dj = 0; dj < 4; ++dj) {
        float a[8];
        #pragma unroll
        for (int e = 0; e < 8; ++e) a[e] = 0.f;
        #pragma unroll
        for (int sp = 0; sp < NSPLIT; ++sp) {
            short8 v = *reinterpret_cast<const short8*>(
                &Opart[((long)(sp * 32 + bh) * NTOK + q) * HD + dc + dj * 8]);
            #pragma unroll
            for (int e = 0; e < 8; ++e)
                a[e] += w[sp] * us2f((unsigned short)v[e]);
        }
        short8 o;
        #pragma unroll
        for (int e = 0; e < 8; ++e) o[e] = (short)f2us(a[e] * inv);
        *reinterpret_cast<short8*>(&Ob[((long)b * NTOK + q) * 1024 + h * 128 + dc + dj * 8]) = o;
    }
}

// LayerNorm(y)*g + b + vision; output dtype per meta[0]
__global__ __launch_bounds__(256)
void ln2_kernel(const unsigned short* __restrict__ Y, const unsigned short* __restrict__ g,
                const unsigned short* __restrict__ be, const unsigned short* __restrict__ vis,
                void* __restrict__ dout, const int* __restrict__ meta)
{
    const int row = blockIdx.x;
    const int tid = threadIdx.x;
    const int lane = tid & 63, wid = tid >> 6;
    const unsigned short* yr = Y + (long)row * DIM;
    ushort4 raw = reinterpret_cast<const ushort4*>(yr)[tid];
    float v[4];
    v[0] = us2f(raw.x); v[1] = us2f(raw.y); v[2] = us2f(raw.z); v[3] = us2f(raw.w);
    float s1 = 0.f, s2 = 0.f;
    #pragma unroll
    for (int i = 0; i < 4; ++i) { s1 += v[i]; s2 += v[i] * v[i]; }
    #pragma unroll
    for (int off = 1; off < 64; off <<= 1) {
        s1 += __shfl_xor(s1, off);
        s2 += __shfl_xor(s2, off);
    }
    __shared__ float red[2][4];
    if (lane == 0) { red[0][wid] = s1; red[1][wid] = s2; }
    __syncthreads();
    s1 = red[0][0] + red[0][1] + red[0][2] + red[0][3];
    s2 = red[1][0] + red[1][1] + red[1][2] + red[1][3];
    const float mu = s1 * (1.f / DIM);
    const float var = s2 * (1.f / DIM) - mu * mu;
    const float inv = rsqrtf(var + 1e-5f);
    ushort4 gg = reinterpret_cast<const ushort4*>(g)[tid];
    ushort4 bb = reinterpret_cast<const ushort4*>(be)[tid];
    ushort4 vv = reinterpret_cast<const ushort4*>(vis + (long)row * DIM)[tid];
    float o0 = (v[0] - mu) * inv * us2f(gg.x) + us2f(bb.x) + us2f(vv.x);
    float o1 = (v[1] - mu) * inv * us2f(gg.y) + us2f(bb.y) + us2f(vv.y);
    float o2 = (v[2] - mu) * inv * us2f(gg.z) + us2f(bb.z) + us2f(vv.z);
    float o3 = (v[3] - mu) * inv * us2f(gg.w) + us2f(bb.w) + us2f(vv.w);
    if (meta[0]) {
        ushort4 o;
        o.x = f2us(o0); o.y = f2us(o1); o.z = f2us(o2); o.w = f2us(o3);
        reinterpret_cast<ushort4*>((unsigned short*)dout + (long)row * DIM)[tid] = o;
    } else {
        float4 o = make_float4(o0, o1, o2, o3);
        reinterpret_cast<float4*>((float*)dout + (long)row * DIM)[tid] = o;
    }
}

extern "C" void kernel_launch(void* const* d_in, const int* in_sizes, int n_in,
                              void* d_out, int out_size, void* d_ws, size_t ws_size,
                              hipStream_t stream)
{
    // scan_idx (d_in[11]) unused: all 8 scans are bijections on the 576 cells and
    // softmax over the full K*N key axis (K,V share row order) is permutation-
    // invariant per direction block -> gather elided.
    unsigned long long w = (unsigned long long)d_ws;
    int* meta = (int*)w; w += 256;

    const int cidx[10] = {0, 2, 3, 4, 5, 6, 7, 8, 9, 10};
    const long csz[10] = {
        (long)NB * NTOK * DIM,  // vision
        (long)KDIR * DIM,       // dirb
        3L * DIM * DIM,         // inW
        3L * DIM,               // inB
        (long)DIM * DIM,        // outW
        DIM,                    // outB
        (long)DIM * DIM,        // finW
        DIM, DIM, DIM           // finB, lng, lnb
    };
    unsigned short* cv[10];
    for (int i = 0; i < 10; ++i) {
        cv[i] = (unsigned short*)w;
        w += (csz[i] * 2 + 255) & ~255ULL;
    }
    unsigned short* dWT = (unsigned short*)w; w += (long)KDIR * DIM * DIM * 2;

    const size_t big = (size_t)NB * KDIR * NTOK * DIM * 2;   // 37.75 MB
    const size_t sml = (size_t)NB * NTOK * DIM * 2;          // 4.72 MB
    unsigned short* dirs = (unsigned short*)w; w += big;     // aliased as Opart later
    unsigned short* Kh   = (unsigned short*)w; w += big;
    unsigned short* VTh  = (unsigned short*)w; w += big;
    unsigned short* Qh   = (unsigned short*)w; w += sml;
    unsigned short* Ob   = (unsigned short*)w; w += sml;
    unsigned short* Fu   = (unsigned short*)w; w += sml;
    unsigned short* Y2   = (unsigned short*)w; w += sml;
    float2* Ml = (float2*)w; w += (long)NSPLIT * 32 * NTOK * sizeof(float2);
    unsigned short* Opart = dirs;   // dirs is dead once KV GEMM completes (18.9MB < 37.75MB)

    const unsigned short* vision = cv[0];
    const unsigned short* dirb = cv[1];
    const unsigned short* inW = cv[2];
    const unsigned short* inB = cv[3];
    const unsigned short* outW = cv[4];
    const unsigned short* outB = cv[5];
    const unsigned short* finW = cv[6];
    const unsigned short* finB = cv[7];
    const unsigned short* lng = cv[8];
    const unsigned short* lnbt = cv[9];

    dim3 blk(256, 1, 1);

    // 0. dtype detect
    detect_kernel<<<dim3(1), dim3(64), 0, stream>>>((const unsigned int*)d_in[1], meta);

    // 1. single fused conversion launch (+ transposed dirW)
    ConvJobs J;
    int bacc = 0;
    for (int i = 0; i < 10; ++i) {
        J.src[i] = d_in[cidx[i]];
        J.dst[i] = cv[i];
        J.n4[i] = (int)(csz[i] / 4);
        J.bstart[i] = bacc;
        bacc += (int)((csz[i] / 4 + 1023) / 1024);
    }
    conv_all<<<dim3(bacc), blk, 0, stream>>>(J, meta);
    transpose_conv<<<dim3(1024, KDIR), blk, 0, stream>>>(d_in[1], dWT, meta);

    // 2. merged dirs(z<8)+Q(z==8, pre-scaled) GEMM: A=vision, M=2304
    gemm_glds<6, 8, 128, 128><<<dim3(18 * 8, 9), blk, 0, stream>>>(
        vision, dWT, dirb, dirs, inW, inB, Qh, NB * NTOK, (long)DIM * DIM, DIM);

    // 3. fused K+V GEMM (wk||wv contiguous): K->Kh, V->VTh (phi-permuted)
    gemm_glds<5, 16, 128, 128><<<dim3(144 * 16, 1), blk, 0, stream>>>(
        dirs, inW + DIM * DIM, inB + DIM, Kh, nullptr, nullptr, VTh, NB * KN, 0L, 0L);

    // 4. 3-chunk KV-split flash attention -> Opart (aliases dirs) + Ml
    attn_kernel7<<<dim3(3 * 32 * NSPLIT), blk, 0, stream>>>(Qh, Kh, VTh, Opart, Ml);

    // 5. combine partials -> Ob [b,n,h*128+d]
    attn_reduce<<<dim3(9, 32), blk, 0, stream>>>(Opart, Ml, Ob);

    // 6. fused = Ob @ out_proj^T + b   (64x64 tile: 576 blocks)
    gemm_glds<0, 16, 64, 64><<<dim3(36 * 16, 1), blk, 0, stream>>>(
        Ob, outW, outB, Fu, nullptr, nullptr, nullptr, NB * NTOK, 0L, 0L);

    // 7. y = fused @ fin^T + b
    gemm_glds<0, 16, 64, 64><<<dim3(36 * 16, 1), blk, 0, stream>>>(
        Fu, finW, finB, Y2, nullptr, nullptr, nullptr, NB * NTOK, 0L, 0L);

    // 8. LayerNorm + residual -> d_out
    ln2_kernel<<<dim3(NB * NTOK), blk, 0, stream>>>(Y2, lng, lnbt, vision, d_out, meta);
}